// Round 8
// baseline (771.501 us; speedup 1.0000x reference)
//
#include <hip/hip_runtime.h>
#include <hip/hip_bf16.h>

// SpatialNCA, MI355X. R16: fix k_scan (R15 counters: 96us @ grid=1, occupancy
// 0.18% -- 49 sequential Hillis-Steele chunks with ~980 barriers while 255
// CUs idle). New scan: single pass, 1024 threads, thread-serial chunk sums
// (CH=ceil(N/1024)) -> one 1024-wide LDS scan (20 barriers) -> serial prefix
// write-back (cnti L2-hot on re-read). Everything else identical to R15
// (32-way replicated stats, wave-per-edge k_t1, streaming MFMA k_gm x2,
// CSR-permuted segment sums). Trace: staged expect=4095, rc expect=3327.

#define EMBD 128
#define TE 32
#define KC 32
#define BN_EPS 1e-5f
#define SREP 32
#define SSTRIDE 1280

typedef unsigned int u32;
typedef _Float16 f16;
typedef _Float16 hf8_t __attribute__((ext_vector_type(8)));
typedef float fx4_t __attribute__((ext_vector_type(4)));

__device__ __forceinline__ bool finitef(float f) {
    union { float f; u32 i; } v; v.f = f;
    return ((v.i >> 23) & 0xFFu) != 0xFFu;
}
__device__ __forceinline__ float sane(float f, float lim) {
    if (!finitef(f)) return 0.f;
    return fminf(fmaxf(f, -lim), lim);
}
__device__ __forceinline__ void trace_mark(float* tp, float bit) {
    if (blockIdx.x == 0 && threadIdx.x == 0) atomicAdd(tp, bit);
}

struct f16x4 { f16 a, b, c, d; };
struct alignas(4) f16x2 { f16 x, y; };
__device__ __forceinline__ float4 ld4h(const f16* p) {
    f16x4 t = *(const f16x4*)p;
    return make_float4((float)t.a, (float)t.b, (float)t.c, (float)t.d);
}
__device__ __forceinline__ void st4h(f16* p, float4 v) {
    f16x4 t; t.a = (f16)v.x; t.b = (f16)v.y; t.c = (f16)v.z; t.d = (f16)v.w;
    *(f16x4*)p = t;
}

// ---------------------------------------------------------------- sentinel
__global__ __launch_bounds__(256) void k_fill(float* out, float val, int n) {
    int i = blockIdx.x * 256 + threadIdx.x;
    if (i < n) out[i] = val;
}

// ------------------------------------------------------------ shared macros
#define STAGE_W(WPTR, K0) { \
        const float* wp = (WPTR) + (size_t)((K0) + kw) * EMBD + cw; \
        float4 wa = *(const float4*)wp; \
        float4 wb = *(const float4*)(wp + 4); \
        float4 wc = *(const float4*)(wp + 8); \
        float4 wdv = *(const float4*)(wp + 12); \
        float* wd = &Ws[kw][cw]; \
        *(float4*)(wd + 0) = wa; *(float4*)(wd + 4) = wb; \
        *(float4*)(wd + 8) = wc; *(float4*)(wd + 12) = wdv; }

#define MMA32() { \
        _Pragma("unroll 8") \
        for (int kk = 0; kk < KC; ++kk) { \
            float4 xv4 = *(const float4*)&XsT[kk][e4]; \
            float4 wv4 = *(const float4*)&Ws[kk][c4]; \
            float xv[4] = {xv4.x, xv4.y, xv4.z, xv4.w}; \
            float wv[4] = {wv4.x, wv4.y, wv4.z, wv4.w}; \
            for (int i = 0; i < 4; ++i) \
                for (int j = 0; j < 4; ++j) acc[i][j] = fmaf(xv[i], wv[j], acc[i][j]); } }

// stats write: into replica (blockIdx & (SREP-1))
#define STATS_TO(SOUT) { \
        __syncthreads(); \
        const int rep_ = (blockIdx.x & (SREP - 1)) * SSTRIDE; \
        for (int j = 0; j < 4; ++j) { \
            float s = 0.f, q = 0.f; \
            for (int i = 0; i < 4; ++i) \
                if (e4 + i < valid) { float a = acc[i][j]; s += a; q += a * a; } \
            part_s[grp][c4 + j] = s; part_q[grp][c4 + j] = q; \
        } \
        __syncthreads(); \
        if (tid < EMBD) { \
            float S = 0.f, Q = 0.f; \
            for (int g = 0; g < 8; ++g) { S += part_s[g][tid]; Q += part_q[g][tid]; } \
            atomicAdd(&(SOUT)[rep_ + tid], S); \
            atomicAdd(&(SOUT)[rep_ + EMBD + tid], Q); } }

// stats read: fold SREP replicas (L2-hot)
#define LOAD_AFF(SRC, GG, BB, SS, CC, DEN) { \
        float sm_ = 0.f, sq_ = 0.f; \
        _Pragma("unroll 8") \
        for (int r_ = 0; r_ < SREP; ++r_) { \
            sm_ += (SRC)[r_ * SSTRIDE + tid]; \
            sq_ += (SRC)[r_ * SSTRIDE + EMBD + tid]; } \
        float m_ = sm_ * (DEN); \
        float v_ = fmaxf(sq_ * (DEN) - m_ * m_, 0.f); \
        float s_ = (GG)[tid] * rsqrtf(v_ + BN_EPS); \
        (SS)[tid] = s_; (CC)[tid] = (BB)[tid] - m_ * s_; }

// Rebuild post-BN1 a1 into XsT from UV (fp16) + dist.  (rc fallback only)
#define REBUILD_XST(K0) { \
        int k = (K0) + kl; \
        float4 u4 = ld4h(uv + (size_t)dst_s[e_st] * 256 + k); \
        float4 v4 = ld4h(uv + (size_t)src_s[e_st] * 256 + 128 + k); \
        float4 wd = *(const float4*)(W1 + (size_t)(2 * EMBD) * EMBD + k); \
        float dd_ = dist_s[e_st]; \
        float r0_ = fmaf(dd_, wd.x, u4.x + v4.x); \
        float r1_ = fmaf(dd_, wd.y, u4.y + v4.y); \
        float r2_ = fmaf(dd_, wd.z, u4.z + v4.z); \
        float r3_ = fmaf(dd_, wd.w, u4.w + v4.w); \
        XsT[kl + 0][e_st] = fmaxf(fmaf(r0_, sA_s[k + 0], sA_c[k + 0]), 0.f); \
        XsT[kl + 1][e_st] = fmaxf(fmaf(r1_, sA_s[k + 1], sA_c[k + 1]), 0.f); \
        XsT[kl + 2][e_st] = fmaxf(fmaf(r2_, sA_s[k + 2], sA_c[k + 2]), 0.f); \
        XsT[kl + 3][e_st] = fmaxf(fmaf(r3_, sA_s[k + 3], sA_c[k + 3]), 0.f); }

#define EDGE_META(WITH_SRC) { \
        if (tid < TE) { \
            int e = r0 + tid; if (e >= E) e = E - 1; \
            int dj = srcI[e], di = dstI[e]; \
            if ((u32)dj >= (u32)Nn) dj = 0; \
            if ((u32)di >= (u32)Nn) di = 0; \
            dst_s[tid] = di; \
            if (WITH_SRC) { \
                src_s[tid] = dj; \
                float2 pj = *(const float2*)(pos + (size_t)dj * 2); \
                float2 pi = *(const float2*)(pos + (size_t)di * 2); \
                float dx = pj.x - pi.x, dy = pj.y - pi.y; \
                dist_s[tid] = sqrtf(dx * dx + dy * dy); } } }

// ================================================================== k_uv
// U = h @ W1[0:128] (dst part), V = h @ W1[128:256] (src part), fp16 out.
__global__ __launch_bounds__(256) void k_uv(
    const float* __restrict__ h, const float* __restrict__ W1,
    f16* __restrict__ uv, float* trace, float bit, int Nn)
{
    trace_mark(trace, bit);
    __shared__ float XsT[KC][TE];
    __shared__ float Ws[KC][EMBD];

    const int tid = threadIdx.x;
    const int r0 = blockIdx.x * TE;
    int valid = Nn - r0; if (valid > TE) valid = TE;

    const int e_st = tid >> 3, kl = (tid & 7) << 2;
    const int kw = tid >> 3, cw = (tid & 7) << 4;
    const int e4 = (tid >> 5) << 2, c4 = (tid & 31) << 2;

    for (int pass = 0; pass < 2; ++pass) {
        float acc[4][4];
#pragma unroll
        for (int i = 0; i < 4; ++i)
#pragma unroll
            for (int j = 0; j < 4; ++j) acc[i][j] = 0.f;

        const float* Wp = W1 + (size_t)pass * EMBD * EMBD;
        for (int k0 = 0; k0 < EMBD; k0 += KC) {
            {
                float4 x = make_float4(0.f, 0.f, 0.f, 0.f);
                if (e_st < valid)
                    x = *(const float4*)(h + (size_t)(r0 + e_st) * EMBD + k0 + kl);
                XsT[kl + 0][e_st] = x.x; XsT[kl + 1][e_st] = x.y;
                XsT[kl + 2][e_st] = x.z; XsT[kl + 3][e_st] = x.w;
            }
            STAGE_W(Wp, k0);
            __syncthreads();
            MMA32();
            __syncthreads();
        }
#pragma unroll
        for (int i = 0; i < 4; ++i)
            if (e4 + i < valid)
                st4h(uv + (size_t)(r0 + e4 + i) * 256 + pass * EMBD + c4,
                     make_float4(acc[i][0], acc[i][1], acc[i][2], acc[i][3]));
    }
}

// ================================================================== k_count
__global__ __launch_bounds__(256) void k_count(
    const int* __restrict__ dstI, int* __restrict__ cnti,
    float* trace, float bit, int E, int Nn)
{
    trace_mark(trace, bit);
    int e = blockIdx.x * 256 + threadIdx.x;
    if (e >= E) return;
    int di = dstI[e];
    if ((u32)di >= (u32)Nn) di = 0;
    atomicAdd(&cnti[di], 1);
}

// ================================================================== k_scan
// Single-pass thread-serial scan: 1024 threads, each owns CH=ceil(N/1024)
// contiguous counts. Pass 1: serial chunk totals. One LDS scan (20 barriers).
// Pass 2: serial prefix write-back (cnti L2-hot). Replaces R15's 49-chunk
// sequential Hillis-Steele (96us -> ~10us predicted).
__global__ __launch_bounds__(1024) void k_scan(
    const int* __restrict__ cnti, int* __restrict__ offs,
    int* __restrict__ cursor, float* trace, float bit, int Nn)
{
    trace_mark(trace, bit);
    __shared__ int buf[1024];
    const int tid = threadIdx.x;
    const int CH = (Nn + 1023) >> 10;
    const int base = tid * CH;

    int tot = 0;
    for (int i = 0; i < CH; ++i) {
        int n = base + i;
        if (n < Nn) tot += cnti[n];
    }
    buf[tid] = tot;
    __syncthreads();
    for (int d = 1; d < 1024; d <<= 1) {
        int t = (tid >= d) ? buf[tid - d] : 0;
        __syncthreads();
        buf[tid] += t;
        __syncthreads();
    }
    int run = buf[tid] - tot;          // exclusive prefix at chunk start
    for (int i = 0; i < CH; ++i) {
        int n = base + i;
        if (n < Nn) {
            int v = cnti[n];
            offs[n] = run; cursor[n] = run;
            run += v;
        }
    }
    if (tid == 1023) offs[Nn] = run;   // == grand total
}

// =============================================================== k_scatter
// Permutation: p = cursor[dst]++ ; srcp[p]/dstp[p] = endpoints ; eidx for rc.
__global__ __launch_bounds__(256) void k_scatter(
    const int* __restrict__ srcI, const int* __restrict__ dstI,
    int* __restrict__ cursor, int* __restrict__ eidx,
    int* __restrict__ srcp, int* __restrict__ dstp,
    float* trace, float bit, int E, int Nn)
{
    trace_mark(trace, bit);
    int e = blockIdx.x * 256 + threadIdx.x;
    if (e >= E) return;
    int di = dstI[e], sj = srcI[e];
    if ((u32)di >= (u32)Nn) di = 0;
    if ((u32)sj >= (u32)Nn) sj = 0;
    int p = atomicAdd(&cursor[di], 1);
    eidx[p] = e;
    srcp[p] = sj;
    dstp[p] = di;
}

// ================================================================== k_t1
// WAVE-PER-EDGE gather: t1[k] = U[dstp[k]] + V[srcp[k]] + dist*w1d, stored
// raw fp16 in permuted order; stats1 into replica slot.
#define TB 64
__global__ __launch_bounds__(256) void k_t1(
    const f16* __restrict__ uv, const float* __restrict__ pos,
    const int* __restrict__ srcp, const int* __restrict__ dstp,
    const float* __restrict__ W1, float* stats_out,
    f16* __restrict__ t1out, float* trace, float bit, int E, int Nn)
{
    trace_mark(trace, bit);
    __shared__ int ds[TB], ss[TB];
    __shared__ float dd[TB];
    __shared__ float ps[4][EMBD], pq[4][EMBD];

    const int tid = threadIdx.x;
    const int r0 = blockIdx.x * TB;

    if (tid < TB) {
        int e = r0 + tid; if (e >= E) e = E - 1;
        int dj = srcp[e], di = dstp[e];
        ds[tid] = di; ss[tid] = dj;
        float2 pj = *(const float2*)(pos + (size_t)dj * 2);
        float2 pi = *(const float2*)(pos + (size_t)di * 2);
        float dx = pj.x - pi.x, dy = pj.y - pi.y;
        dd[tid] = sqrtf(dx * dx + dy * dy);
    }
    __syncthreads();

    const int lane = tid & 63, wv = tid >> 6;
    const int c0 = lane * 2;
    const float w0 = W1[(size_t)(2 * EMBD) * EMBD + c0];
    const float w1 = W1[(size_t)(2 * EMBD) * EMBD + c0 + 1];

    float S0 = 0.f, Q0 = 0.f, S1 = 0.f, Q1 = 0.f;
#pragma unroll
    for (int i = 0; i < 16; ++i) {
        const int el = wv * 16 + i;
        const int e = r0 + el;
        f16x2 u2 = *(const f16x2*)(uv + (size_t)ds[el] * 256 + c0);
        f16x2 v2 = *(const f16x2*)(uv + (size_t)ss[el] * 256 + 128 + c0);
        float d = dd[el];
        float t0 = fmaf(d, w0, (float)u2.x + (float)v2.x);
        float t1v = fmaf(d, w1, (float)u2.y + (float)v2.y);
        if (e < E) {
            S0 += t0; Q0 += t0 * t0;
            S1 += t1v; Q1 += t1v * t1v;
            f16x2 o; o.x = (f16)t0; o.y = (f16)t1v;
            *(f16x2*)(t1out + (size_t)e * EMBD + c0) = o;
        }
    }
    ps[wv][c0] = S0; ps[wv][c0 + 1] = S1;
    pq[wv][c0] = Q0; pq[wv][c0 + 1] = Q1;
    __syncthreads();
    const int rep = (blockIdx.x & (SREP - 1)) * SSTRIDE;
    if (tid < EMBD) {
        atomicAdd(&stats_out[rep + tid], ps[0][tid] + ps[1][tid] + ps[2][tid] + ps[3][tid]);
        atomicAdd(&stats_out[rep + EMBD + tid], pq[0][tid] + pq[1][tid] + pq[2][tid] + pq[3][tid]);
    }
}
#undef TB

// =============================================================== k_stats1
// rc fallback only: stats1 over permuted t1 (no staging buffer available).
#define SB 128
__global__ __launch_bounds__(256) void k_stats1(
    const f16* __restrict__ uv, const float* __restrict__ pos,
    const int* __restrict__ srcp, const int* __restrict__ dstp,
    const float* __restrict__ W1, float* stats_out,
    float* trace, float bit, int E, int Nn)
{
    trace_mark(trace, bit);
    __shared__ int ds[SB], ss[SB];
    __shared__ float dd[SB];
    __shared__ float ps[2][EMBD], pq[2][EMBD];

    const int tid = threadIdx.x;
    const int r0 = blockIdx.x * SB;

    if (tid < SB) {
        int e = r0 + tid; if (e >= E) e = E - 1;
        int dj = srcp[e], di = dstp[e];
        ds[tid] = di; ss[tid] = dj;
        float2 pj = *(const float2*)(pos + (size_t)dj * 2);
        float2 pi = *(const float2*)(pos + (size_t)di * 2);
        float dx = pj.x - pi.x, dy = pj.y - pi.y;
        dd[tid] = sqrtf(dx * dx + dy * dy);
    }
    __syncthreads();

    const int c = tid & 127, hh = tid >> 7;
    const float w1d = W1[(size_t)(2 * EMBD) * EMBD + c];
    float S = 0.f, Q = 0.f;
#pragma unroll 4
    for (int i = 0; i < 64; ++i) {
        int el = hh * 64 + i;
        int e = r0 + el;
        if (e < E) {
            float u = (float)uv[(size_t)ds[el] * 256 + c];
            float v = (float)uv[(size_t)ss[el] * 256 + 128 + c];
            float t = fmaf(dd[el], w1d, u + v);
            S += t; Q += t * t;
        }
    }
    ps[hh][c] = S; pq[hh][c] = Q;
    __syncthreads();
    const int rep = (blockIdx.x & (SREP - 1)) * SSTRIDE;
    if (tid < EMBD) {
        atomicAdd(&stats_out[rep + tid], ps[0][tid] + ps[1][tid]);
        atomicAdd(&stats_out[rep + EMBD + tid], pq[0][tid] + pq[1][tid]);
    }
}
#undef SB

// ================================================================== k_prep
// Transpose W2/Wp1 to fp16 MFMA B-frag-slot order.
__global__ __launch_bounds__(256) void k_prep(
    const float* __restrict__ W2, const float* __restrict__ Wp1,
    f16* __restrict__ wtf2, f16* __restrict__ wtf3, float* trace, float bit)
{
    trace_mark(trace, bit);
    int id = blockIdx.x * 256 + threadIdx.x;   // 64 blocks -> 16384
    int k = id >> 7, n = id & 127;
    size_t s = ((size_t)(k >> 3) * 128 + n) * 8 + (k & 7);
    wtf2[s] = (f16)W2[(size_t)k * 128 + n];
    wtf3[s] = (f16)Wp1[(size_t)k * 128 + n];
}

// ================================================================== k_gm
// Streaming MFMA mid GEMM: a = relu(bn(tin_raw)); tout_raw = a @ W; stats
// into replica; IN-PLACE safe.
__global__ __launch_bounds__(256) void k_gm(
    const f16* __restrict__ tin, const f16* __restrict__ wtf,
    const float* g, const float* b,
    const float* __restrict__ stats_in, float* stats_out,
    f16* __restrict__ tout, float* trace, float bit, int E)
{
    trace_mark(trace, bit);
    __shared__ __align__(16) f16 bsh[16384];
    __shared__ float sB_s[EMBD], sB_c[EMBD];
    __shared__ float ps[4][EMBD], pq[4][EMBD];

    const int tid = threadIdx.x;
    const int r0 = blockIdx.x * 64;

    if (tid < EMBD) {
        const float invE = 1.f / (float)E;
        LOAD_AFF(stats_in, g, b, sB_s, sB_c, invE);
    }
    {
        const float4* s4 = (const float4*)wtf;
        float4* d4 = (float4*)bsh;
#pragma unroll
        for (int i = 0; i < 8; ++i) d4[i * 256 + tid] = s4[i * 256 + tid];
    }
    __syncthreads();

    const int wv = tid >> 6, lane = tid & 63;
    const int lm = lane & 15, lg = lane >> 4;
    int grA = r0 + wv * 16 + lm; if (grA >= E) grA = E - 1;

    fx4_t acc[8];
#pragma unroll
    for (int c = 0; c < 8; ++c) acc[c] = (fx4_t){0.f, 0.f, 0.f, 0.f};

#pragma unroll
    for (int ks = 0; ks < 4; ++ks) {
        const int k0 = ks * 32 + lg * 8;
        hf8_t x8 = *(const hf8_t*)(tin + (size_t)grA * 128 + k0);
        hf8_t af;
#pragma unroll
        for (int e = 0; e < 8; ++e) {
            int k = k0 + e;
            af[e] = (f16)fmaxf(fmaf((float)x8[e], sB_s[k], sB_c[k]), 0.f);
        }
        const f16* bb = bsh + (size_t)(ks * 4 + lg) * 128 * 8;
#pragma unroll
        for (int c = 0; c < 8; ++c) {
            hf8_t bf = *(const hf8_t*)(bb + (size_t)(c * 16 + lm) * 8);
            acc[c] = __builtin_amdgcn_mfma_f32_16x16x32_f16(af, bf, acc[c], 0, 0, 0);
        }
    }

    const int rbase = wv * 16 + lg * 4;
#pragma unroll
    for (int c = 0; c < 8; ++c) {
        float s = 0.f, q = 0.f;
#pragma unroll
        for (int r = 0; r < 4; ++r)
            if (r0 + rbase + r < E) { float a = acc[c][r]; s += a; q += a * a; }
        s += __shfl_xor(s, 16, 64); q += __shfl_xor(q, 16, 64);
        s += __shfl_xor(s, 32, 64); q += __shfl_xor(q, 32, 64);
        if (lg == 0) { ps[wv][c * 16 + lm] = s; pq[wv][c * 16 + lm] = q; }
    }
    __syncthreads();
    const int rep = (blockIdx.x & (SREP - 1)) * SSTRIDE;
    if (tid < EMBD) {
        atomicAdd(&stats_out[rep + tid], ps[0][tid] + ps[1][tid] + ps[2][tid] + ps[3][tid]);
        atomicAdd(&stats_out[rep + EMBD + tid], pq[0][tid] + pq[1][tid] + pq[2][tid] + pq[3][tid]);
    }

    f16* otile = bsh;
#pragma unroll
    for (int c = 0; c < 8; ++c) {
        int col = c * 16 + lm;
#pragma unroll
        for (int r = 0; r < 4; ++r)
            otile[(size_t)(rbase + r) * 136 + col] = (f16)acc[c][r];
    }
    __syncthreads();
#pragma unroll
    for (int it = 0; it < 4; ++it) {
        int row = it * 16 + (tid >> 4), ch = tid & 15;
        int gr = r0 + row;
        if (gr < E)
            *(float4*)(tout + (size_t)gr * 128 + ch * 8) =
                *(const float4*)(otile + (size_t)row * 136 + ch * 8);
    }
}

// ================================================================== k_aggr
// Contiguous segment-sum over permuted t2: h_aggr[n] = sum relu(bn2(t2[k])).
__global__ __launch_bounds__(256) void k_aggr(
    const f16* __restrict__ t2, const int* __restrict__ offs,
    const float* g2, const float* b2, const float* __restrict__ stats_in,
    float* __restrict__ h_aggr, float* trace, float bit, int E, int Nn)
{
    trace_mark(trace, bit);
    __shared__ float sB_s[EMBD], sB_c[EMBD];
    const int tid = threadIdx.x;
    if (tid < EMBD) {
        const float invE = 1.f / (float)E;
        LOAD_AFF(stats_in, g2, b2, sB_s, sB_c, invE);
    }
    __syncthreads();

    const int lane = tid & 63;
    const int node = blockIdx.x * 4 + (tid >> 6);
    if (node >= Nn) return;

    const int c0 = lane * 2;
    const float s0 = sB_s[c0], s1 = sB_s[c0 + 1];
    const float cc0 = sB_c[c0], cc1 = sB_c[c0 + 1];
    const int o0 = offs[node], o1 = offs[node + 1];

    float a0 = 0.f, a1 = 0.f;
    for (int k = o0; k < o1; ++k) {
        f16x2 xv = *(const f16x2*)(t2 + (size_t)k * EMBD + c0);
        a0 += fmaxf(fmaf((float)xv.x, s0, cc0), 0.f);
        a1 += fmaxf(fmaf((float)xv.y, s1, cc1), 0.f);
    }
    *(float2*)(h_aggr + (size_t)node * EMBD + c0) = make_float2(a0, a1);
}

// ================================================================== k_dot
__global__ __launch_bounds__(256) void k_dot(
    const f16* __restrict__ t3, const float* __restrict__ Wp2,
    const float* g3, const float* b3,
    const float* __restrict__ stats_in, float* stats_out, float* t4,
    float* trace, float bit, int E)
{
    trace_mark(trace, bit);
    __shared__ float sC_s[EMBD], sC_c[EMBD];
    __shared__ float red[256];
    __shared__ float dotbuf[TE];

    const int tid = threadIdx.x;
    const int r0 = blockIdx.x * TE;
    int valid = E - r0; if (valid > TE) valid = TE;

    if (tid < EMBD) {
        const float invE = 1.f / (float)E;
        LOAD_AFF(stats_in, g3, b3, sC_s, sC_c, invE);
    }
    __syncthreads();

    const int row = tid >> 3, c0 = (tid & 7) << 4;
    int e = r0 + row; if (e >= E) e = E - 1;
    const f16* tp = t3 + (size_t)e * EMBD + c0;

    float part = 0.f;
#pragma unroll
    for (int q = 0; q < 4; ++q) {
        float4 x = ld4h(tp + q * 4);
        float4 w = *(const float4*)(Wp2 + c0 + q * 4);
        int c = c0 + q * 4;
        part = fmaf(fmaxf(fmaf(x.x, sC_s[c + 0], sC_c[c + 0]), 0.f), w.x, part);
        part = fmaf(fmaxf(fmaf(x.y, sC_s[c + 1], sC_c[c + 1]), 0.f), w.y, part);
        part = fmaf(fmaxf(fmaf(x.z, sC_s[c + 2], sC_c[c + 2]), 0.f), w.z, part);
        part = fmaf(fmaxf(fmaf(x.w, sC_s[c + 3], sC_c[c + 3]), 0.f), w.w, part);
    }
    red[tid] = part;
    __syncthreads();
    if ((tid & 7) == 0) {
        float dot = red[tid] + red[tid+1] + red[tid+2] + red[tid+3]
                  + red[tid+4] + red[tid+5] + red[tid+6] + red[tid+7];
        dotbuf[row] = dot;
        if (row < valid) t4[r0 + row] = dot;
    }
    __syncthreads();
    if (tid == 0) {
        float S = 0.f, Q = 0.f;
        for (int r = 0; r < valid; ++r) { float d = dotbuf[r]; S += d; Q += d * d; }
        const int rep = (blockIdx.x & (SREP - 1)) * SSTRIDE;
        atomicAdd(&stats_out[rep + 0], S);
        atomicAdd(&stats_out[rep + EMBD], Q);
    }
}

// ============================================================= k_pos_aggr
// PERM=1: t4/srcp permuted (streaming). PERM=0: rc tier via eidx.
template<int PERM>
__global__ __launch_bounds__(256) void k_pos_aggr(
    const float* __restrict__ t4, const int* __restrict__ offs,
    const int* __restrict__ eidx, const int* __restrict__ srcp,
    const int* __restrict__ srcI,
    const float* __restrict__ pos, const float* __restrict__ stats_base,
    const float* gp2, const float* bbp2,
    float* __restrict__ x_aggr, float* trace, float bit, int E, int Nn)
{
    trace_mark(trace, bit);
    const int tid = threadIdx.x;
    const int lane = tid & 63;
    const int node = blockIdx.x * 4 + (tid >> 6);
    if (node >= Nn) return;

    const float invE = 1.f / (float)E;
    float sm = 0.f, sq = 0.f;
#pragma unroll 8
    for (int r = 0; r < SREP; ++r) {
        sm += stats_base[r * SSTRIDE + 768];
        sq += stats_base[r * SSTRIDE + 768 + EMBD];
    }
    float m = sm * invE;
    float v = fmaxf(sq * invE - m * m, 0.f);
    float s3 = gp2[0] * rsqrtf(v + BN_EPS);
    float c3 = bbp2[0] - m * s3;

    const int o0 = offs[node], o1 = offs[node + 1];
    float2 pi = *(const float2*)(pos + (size_t)node * 2);
    float ax = 0.f, ay = 0.f;
    for (int k = o0 + lane; k < o1; k += 64) {
        float s; int j;
        if (PERM) {
            s = fmaxf(fmaf(t4[k], s3, c3), 0.f);
            j = srcp[k];
        } else {
            int e = eidx[k];
            s = fmaxf(fmaf(t4[e], s3, c3), 0.f);
            j = srcI[e];
            if ((u32)j >= (u32)Nn) j = 0;
        }
        float2 pj = *(const float2*)(pos + (size_t)j * 2);
        ax += (pj.x - pi.x) * s;
        ay += (pj.y - pi.y) * s;
    }
#pragma unroll
    for (int off = 32; off; off >>= 1) {
        ax += __shfl_down(ax, off, 64);
        ay += __shfl_down(ay, off, 64);
    }
    if (lane == 0) {
        float inv = 1.f / fmaxf((float)(o1 - o0), 1.f);
        *(float2*)(x_aggr + (size_t)node * 2) = make_float2(ax * inv, ay * inv);
    }
}

// ============================================================== k_edge_rc
// Recompute tier (small ws) — original edge order.
template<int DEPTH>
__global__ __launch_bounds__(256) void k_edge_rc(
    const f16* __restrict__ uv,
    const int* __restrict__ srcI, const int* __restrict__ dstI,
    const float* __restrict__ pos,
    const float* __restrict__ W1, const float* __restrict__ W2,
    const float* __restrict__ W3, const float* __restrict__ Wp2,
    const float* g1, const float* b1, const float* g2, const float* b2,
    const float* g3, const float* b3,
    const float* __restrict__ stats_base, float* stats_out,
    float* h_aggr, float* t4_out,
    float* trace, float bit, int E, int Nn)
{
    trace_mark(trace, bit);
    __shared__ float XsT[KC][TE];
    __shared__ float Ws[KC][EMBD];
    __shared__ float A[(DEPTH >= 3) ? TE : 1][EMBD + 4];
    __shared__ float part_s[8][EMBD];
    __shared__ float part_q[8][EMBD];
    __shared__ float red[(DEPTH >= 4) ? 256 : 1];
    __shared__ float dotbuf[(DEPTH >= 4) ? TE : 1];
    __shared__ float sA_s[EMBD], sA_c[EMBD];
    __shared__ float sB_s[(DEPTH >= 3) ? EMBD : 1], sB_c[(DEPTH >= 3) ? EMBD : 1];
    __shared__ float sC_s[(DEPTH >= 4) ? EMBD : 1], sC_c[(DEPTH >= 4) ? EMBD : 1];
    __shared__ int dst_s[TE], src_s[TE];
    __shared__ float dist_s[TE];

    const int tid = threadIdx.x;
    const int r0 = blockIdx.x * TE;
    int valid = E - r0; if (valid > TE) valid = TE;

    if (tid < EMBD) {
        const float invE = 1.f / (float)E;
        LOAD_AFF(stats_base, g1, b1, sA_s, sA_c, invE);
        if (DEPTH >= 3) LOAD_AFF(stats_base + 256, g2, b2, sB_s, sB_c, invE);
        if (DEPTH >= 4) LOAD_AFF(stats_base + 512, g3, b3, sC_s, sC_c, invE);
    }
    EDGE_META(1);
    __syncthreads();

    const int e_st = tid >> 3, kl = (tid & 7) << 2;
    const int kw = tid >> 3, cw = (tid & 7) << 4;
    const int e4 = (tid >> 5) << 2, c4 = (tid & 31) << 2;
    const int grp = tid >> 5;

    float acc[4][4];
#pragma unroll
    for (int i = 0; i < 4; ++i)
#pragma unroll
        for (int j = 0; j < 4; ++j) acc[i][j] = 0.f;

    for (int k0 = 0; k0 < EMBD; k0 += KC) {
        REBUILD_XST(k0);
        STAGE_W(W2, k0);
        __syncthreads();
        MMA32();
        __syncthreads();
    }

    if (DEPTH == 2) { STATS_TO(stats_out); return; }

#pragma unroll
    for (int i = 0; i < 4; ++i) {
        float4 o;
#pragma unroll
        for (int j = 0; j < 4; ++j) {
            float v = fmaxf(fmaf(acc[i][j], sB_s[c4 + j], sB_c[c4 + j]), 0.f);
            (&o.x)[j] = v;
            if (DEPTH == 3 && (e4 + i) < valid)
                atomicAdd(&h_aggr[(size_t)dst_s[e4 + i] * EMBD + c4 + j], v);
        }
        *(float4*)&A[e4 + i][c4] = o;
    }
    __syncthreads();

#pragma unroll
    for (int i = 0; i < 4; ++i)
#pragma unroll
        for (int j = 0; j < 4; ++j) acc[i][j] = 0.f;
    for (int k0 = 0; k0 < EMBD; k0 += KC) {
        STAGE_W(W3, k0);
        __syncthreads();
#pragma unroll 8
        for (int kk = 0; kk < KC; ++kk) {
            float4 wv4 = *(const float4*)&Ws[kk][c4];
            float wv[4] = {wv4.x, wv4.y, wv4.z, wv4.w};
            float xv[4];
#pragma unroll
            for (int i = 0; i < 4; ++i) xv[i] = A[e4 + i][k0 + kk];
#pragma unroll
            for (int i = 0; i < 4; ++i)
#pragma unroll
                for (int j = 0; j < 4; ++j) acc[i][j] = fmaf(xv[i], wv[j], acc[i][j]);
        }
        __syncthreads();
    }

    if (DEPTH == 3) { STATS_TO(stats_out); return; }

#pragma unroll
    for (int i = 0; i < 4; ++i) {
        float4 o;
#pragma unroll
        for (int j = 0; j < 4; ++j)
            (&o.x)[j] = fmaxf(fmaf(acc[i][j], sC_s[c4 + j], sC_c[c4 + j]), 0.f);
        *(float4*)&A[e4 + i][c4] = o;
    }
    __syncthreads();

    {
        const int row = tid >> 3, c0 = (tid & 7) << 4;
        float w[16];
        *(float4*)(w + 0)  = *(const float4*)(Wp2 + c0);
        *(float4*)(w + 4)  = *(const float4*)(Wp2 + c0 + 4);
        *(float4*)(w + 8)  = *(const float4*)(Wp2 + c0 + 8);
        *(float4*)(w + 12) = *(const float4*)(Wp2 + c0 + 12);
        float part = 0.f;
#pragma unroll
        for (int c = 0; c < 16; ++c) part = fmaf(A[row][c0 + c], w[c], part);
        red[tid] = part;
        __syncthreads();
        if ((tid & 7) == 0) {
            float dot = red[tid] + red[tid+1] + red[tid+2] + red[tid+3]
                      + red[tid+4] + red[tid+5] + red[tid+6] + red[tid+7];
            dotbuf[row] = dot;
            if (row < valid) t4_out[r0 + row] = dot;
        }
        __syncthreads();
        if (tid == 0) {
            float S = 0.f, Q = 0.f;
            for (int r = 0; r < valid; ++r) { float d = dotbuf[r]; S += d; Q += d * d; }
            const int rep = (blockIdx.x & (SREP - 1)) * SSTRIDE;
            atomicAdd(&stats_out[rep + 0], S);
            atomicAdd(&stats_out[rep + EMBD], Q);
        }
    }
}

// =============================================================== node GEMM
__global__ __launch_bounds__(256) void k_upd(
    const float* h, const float* h_aggr, const float* W,
    float* stats_out, float* t5, float* trace, float bit, int Nn)
{
    trace_mark(trace, bit);
    __shared__ float XsT[KC][TE];
    __shared__ float Ws[KC][EMBD];
    __shared__ float part_s[8][EMBD];
    __shared__ float part_q[8][EMBD];

    const int tid = threadIdx.x;
    const int r0 = blockIdx.x * TE;
    int valid = Nn - r0; if (valid > TE) valid = TE;

    float acc[4][4];
#pragma unroll
    for (int i = 0; i < 4; ++i)
#pragma unroll
        for (int j = 0; j < 4; ++j) acc[i][j] = 0.f;

    const int e_st = tid >> 3, kl = (tid & 7) << 2;
    const int kw = tid >> 3, cw = (tid & 7) << 4;
    const int e4 = (tid >> 5) << 2, c4 = (tid & 31) << 2;
    const int grp = tid >> 5;

    for (int k0 = 0; k0 < 2 * EMBD; k0 += KC) {
        {
            float4 x = make_float4(0.f, 0.f, 0.f, 0.f);
            if (e_st < valid) {
                int k = k0 + kl;
                int row = r0 + e_st;
                const float* base = (k < EMBD)
                    ? h + (size_t)row * EMBD + k
                    : h_aggr + (size_t)row * EMBD + (k - EMBD);
                x = *(const float4*)base;
            }
            XsT[kl + 0][e_st] = x.x; XsT[kl + 1][e_st] = x.y;
            XsT[kl + 2][e_st] = x.z; XsT[kl + 3][e_st] = x.w;
        }
        STAGE_W(W, k0);
        __syncthreads();
        MMA32();
        __syncthreads();
    }

    STATS_TO(stats_out);

#pragma unroll
    for (int i = 0; i < 4; ++i) {
        int row = r0 + e4 + i;
        if (e4 + i < valid)
            *(float4*)(t5 + (size_t)row * EMBD + c4) =
                make_float4(acc[i][0], acc[i][1], acc[i][2], acc[i][3]);
    }
}

// ---------------------------------------------------------------- epilogue
__global__ __launch_bounds__(256) void k_final(
    const float* h, const float* pos, const float* stats5,
    const float* gu1, const float* bbu1,
    const float* x_aggr, const float* trace,
    float* out, int N, float expect)
{
    __shared__ float s4[EMBD], cc4[EMBD];
    int tid = threadIdx.x;
    if (tid < EMBD) {
        const float invN = 1.f / (float)N;
        LOAD_AFF(stats5, gu1, bbu1, s4, cc4, invN);
    }
    __syncthreads();
    int n = blockIdx.x * 2 + (tid >> 7);
    int c = tid & 127;
    if (n >= N) return;
    float hv = h[(size_t)n * EMBD + c];
    float t = out[(size_t)n * EMBD + c];
    float res = sane(hv + fmaxf(fmaf(t, s4[c], cc4[c]), 0.f), 100.f);
    if (n == 0 && c == 1) {
        float tr = trace[0];
        if (fabsf(tr - expect) > 0.5f) res = 1048576.0f + tr * 64.0f;
    }
    out[(size_t)n * EMBD + c] = res;
    if (c < 2) {
        float p = pos[(size_t)n * 2 + c];
        float xa = x_aggr[(size_t)n * 2 + c];
        out[(size_t)N * EMBD + (size_t)n * 2 + c] = sane(p + xa, 100.f);
    }
}

// ================================================================= launch
extern "C" void kernel_launch(void* const* d_in, const int* in_sizes, int n_in,
                              void* d_out, int out_size, void* d_ws, size_t ws_size,
                              hipStream_t stream)
{
    const float* h   = (const float*)d_in[0];
    const float* pos = (const float*)d_in[1];
    const int* ei    = (const int*)d_in[3];
    const float* Wm1 = (const float*)d_in[4];
    const float* gm1 = (const float*)d_in[6];
    const float* bbm1= (const float*)d_in[7];
    const float* Wm2 = (const float*)d_in[8];
    const float* gm2 = (const float*)d_in[10];
    const float* bbm2= (const float*)d_in[11];
    const float* Wp1 = (const float*)d_in[12];
    const float* gp1 = (const float*)d_in[14];
    const float* bbp1= (const float*)d_in[15];
    const float* Wp2 = (const float*)d_in[16];
    const float* gp2 = (const float*)d_in[18];
    const float* bbp2= (const float*)d_in[19];
    const float* Wu1 = (const float*)d_in[20];
    const float* gu1 = (const float*)d_in[22];
    const float* bbu1= (const float*)d_in[23];

    const int N = in_sizes[0] / EMBD;
    const int E = in_sizes[3] / 2;
    const int* srcI = ei;
    const int* dstI = ei + E;

    size_t off = 0;
    auto carve = [&](size_t bytes) -> size_t {
        size_t o = off; off += (bytes + 255) & ~(size_t)255; return o;
    };
    size_t o_stats  = carve((size_t)SREP * SSTRIDE * sizeof(float));  // 164 KB
    size_t o_trace  = carve(256);
    size_t o_cnti   = carve((size_t)N * sizeof(int));
    size_t zero_small = off;
    size_t o_haggr  = carve((size_t)N * EMBD * sizeof(float));
    size_t zero_need = off;                                  // ~26 MB
    size_t o_xaggr  = carve((size_t)N * 2 * sizeof(float));
    size_t o_t4     = carve((size_t)E * sizeof(float));
    size_t o_offs   = carve((size_t)(N + 1) * sizeof(int));
    size_t o_cursor = carve((size_t)N * sizeof(int));
    size_t o_eidx   = carve((size_t)E * sizeof(int));
    size_t o_srcp   = carve((size_t)E * sizeof(int));
    size_t o_dstp   = carve((size_t)E * sizeof(int));
    size_t o_wtf2   = carve(16384 * sizeof(f16));
    size_t o_wtf3   = carve(16384 * sizeof(f16));
    size_t base_need = off;                                  // ~35 MB
    size_t o_ebuf   = carve((size_t)E * EMBD * sizeof(f16)); // +128 MB
    size_t need_staged = off;

    float* out_f = (float*)d_out;

    if (ws_size < base_need) {
        k_fill<<<(out_size + 255) / 256, 256, 0, stream>>>(out_f, 12345678.0f, out_size);
        return;
    }

    char* wsb = (char*)d_ws;
    float* stats  = (float*)(wsb + o_stats);
    float* trace  = (float*)(wsb + o_trace);
    int*   cnti   = (int*)(wsb + o_cnti);
    float* h_aggr = (float*)(wsb + o_haggr);
    float* x_aggr = (float*)(wsb + o_xaggr);
    float* t4     = (float*)(wsb + o_t4);
    int*   offs   = (int*)(wsb + o_offs);
    int*   cursor = (int*)(wsb + o_cursor);
    int*   eidx   = (int*)(wsb + o_eidx);
    int*   srcp   = (int*)(wsb + o_srcp);
    int*   dstp   = (int*)(wsb + o_dstp);
    f16*   wtf2   = (f16*)(wsb + o_wtf2);
    f16*   wtf3   = (f16*)(wsb + o_wtf3);
    f16*   uv     = (f16*)d_out;   // N*256 fp16 = N*512B <= out bytes

    const bool staged = (ws_size >= need_staged);
    hipMemsetAsync(d_ws, 0, staged ? zero_small : zero_need, stream);

    const int gPE  = (E + 255) / 256;
    const int gE   = (E + TE - 1) / TE;
    const int gE64 = (E + 63) / 64;
    const int gN   = (N + TE - 1) / TE;
    const int gS1  = (E + 127) / 128;
    const int gW   = (N + 3) / 4;

    k_uv<<<gN, 256, 0, stream>>>(h, Wm1, uv, trace, 1.0f, N);
    k_count<<<gPE, 256, 0, stream>>>(dstI, cnti, trace, 2.0f, E, N);
    k_scan<<<1, 1024, 0, stream>>>(cnti, offs, cursor, trace, 4.0f, N);
    k_scatter<<<gPE, 256, 0, stream>>>(srcI, dstI, cursor, eidx, srcp, dstp,
                                       trace, 8.0f, E, N);

    if (staged) {
        f16* eb = (f16*)(wsb + o_ebuf);
        k_t1<<<gE64, 256, 0, stream>>>(uv, pos, srcp, dstp, Wm1,
                                       stats, eb, trace, 16.0f, E, N);
        k_prep<<<64, 256, 0, stream>>>(Wm2, Wp1, wtf2, wtf3, trace, 32.0f);
        k_gm<<<gE64, 256, 0, stream>>>(eb, wtf2, gm1, bbm1,
                                       stats, stats + 256,
                                       eb, trace, 64.0f, E);
        k_aggr<<<gW, 256, 0, stream>>>(eb, offs, gm2, bbm2, stats + 256,
                                       h_aggr, trace, 128.0f, E, N);
        k_gm<<<gE64, 256, 0, stream>>>(eb, wtf3, gm2, bbm2,
                                       stats + 256, stats + 512,
                                       eb, trace, 256.0f, E);
        k_dot<<<gE, 256, 0, stream>>>(eb, Wp2, gp1, bbp1,
                                      stats + 512, stats + 768, t4,
                                      trace, 512.0f, E);
        k_pos_aggr<1><<<gW, 256, 0, stream>>>(t4, offs, eidx, srcp, srcI, pos,
                                              stats, gp2, bbp2, x_aggr,
                                              trace, 1024.0f, E, N);
    } else {
        k_stats1<<<gS1, 256, 0, stream>>>(uv, pos, srcp, dstp, Wm1,
                                          stats, trace, 16.0f, E, N);
        k_edge_rc<2><<<gE, 256, 0, stream>>>(uv, srcI, dstI, pos,
                                             Wm1, Wm2, Wp1, Wp2,
                                             gm1, bbm1, gm2, bbm2, gp1, bbp1,
                                             stats, stats + 256, h_aggr, t4,
                                             trace, 32.0f, E, N);
        k_edge_rc<3><<<gE, 256, 0, stream>>>(uv, srcI, dstI, pos,
                                             Wm1, Wm2, Wp1, Wp2,
                                             gm1, bbm1, gm2, bbm2, gp1, bbp1,
                                             stats, stats + 512, h_aggr, t4,
                                             trace, 64.0f, E, N);
        k_edge_rc<4><<<gE, 256, 0, stream>>>(uv, srcI, dstI, pos,
                                             Wm1, Wm2, Wp1, Wp2,
                                             gm1, bbm1, gm2, bbm2, gp1, bbp1,
                                             stats, stats + 768, h_aggr, t4,
                                             trace, 128.0f, E, N);
        k_pos_aggr<0><<<gW, 256, 0, stream>>>(t4, offs, eidx, srcp, srcI, pos,
                                              stats, gp2, bbp2, x_aggr,
                                              trace, 1024.0f, E, N);
    }

    k_upd<<<gN, 256, 0, stream>>>(h, h_aggr, Wu1, stats + 1024, out_f,
                                  trace, 2048.0f, N);
    k_final<<<(N + 1) / 2, 256, 0, stream>>>(h, pos, stats + 1024, gu1, bbu1,
                                             x_aggr, trace, out_f, N,
                                             staged ? 4095.0f : 3327.0f);
}

// Round 9
// 652.253 us; speedup vs baseline: 1.1828x; 1.1828x over previous
//
#include <hip/hip_runtime.h>
#include <hip/hip_bf16.h>

// SpatialNCA, MI355X. R17: parallel hierarchical scan. R16 counters: the
// single-block scan REGRESSED (96->127us, occupancy 0.14%, VALUBusy 0.01%)
// -- one CU latency-bound while 255 idle. Now 3 kernels: k_scan1 (49 blocks,
// per-block LDS scan -> local prefixes + block totals), k_scan2 (1 tiny
// block scans 49 totals), k_scan3 (49 blocks add block prefix). ~15us total.
// Everything else identical to R15/R16 (32-way replicated stats, wave-per-
// edge k_t1, streaming MFMA k_gm x2, CSR-permuted segment sums).
// Trace fail-closed: staged expect=16383, rc expect=4095.

#define EMBD 128
#define TE 32
#define KC 32
#define BN_EPS 1e-5f
#define SREP 32
#define SSTRIDE 1280

typedef unsigned int u32;
typedef _Float16 f16;
typedef _Float16 hf8_t __attribute__((ext_vector_type(8)));
typedef float fx4_t __attribute__((ext_vector_type(4)));

__device__ __forceinline__ bool finitef(float f) {
    union { float f; u32 i; } v; v.f = f;
    return ((v.i >> 23) & 0xFFu) != 0xFFu;
}
__device__ __forceinline__ float sane(float f, float lim) {
    if (!finitef(f)) return 0.f;
    return fminf(fmaxf(f, -lim), lim);
}
__device__ __forceinline__ void trace_mark(float* tp, float bit) {
    if (blockIdx.x == 0 && threadIdx.x == 0) atomicAdd(tp, bit);
}

struct f16x4 { f16 a, b, c, d; };
struct alignas(4) f16x2 { f16 x, y; };
__device__ __forceinline__ float4 ld4h(const f16* p) {
    f16x4 t = *(const f16x4*)p;
    return make_float4((float)t.a, (float)t.b, (float)t.c, (float)t.d);
}
__device__ __forceinline__ void st4h(f16* p, float4 v) {
    f16x4 t; t.a = (f16)v.x; t.b = (f16)v.y; t.c = (f16)v.z; t.d = (f16)v.w;
    *(f16x4*)p = t;
}

// ---------------------------------------------------------------- sentinel
__global__ __launch_bounds__(256) void k_fill(float* out, float val, int n) {
    int i = blockIdx.x * 256 + threadIdx.x;
    if (i < n) out[i] = val;
}

// ------------------------------------------------------------ shared macros
#define STAGE_W(WPTR, K0) { \
        const float* wp = (WPTR) + (size_t)((K0) + kw) * EMBD + cw; \
        float4 wa = *(const float4*)wp; \
        float4 wb = *(const float4*)(wp + 4); \
        float4 wc = *(const float4*)(wp + 8); \
        float4 wdv = *(const float4*)(wp + 12); \
        float* wd = &Ws[kw][cw]; \
        *(float4*)(wd + 0) = wa; *(float4*)(wd + 4) = wb; \
        *(float4*)(wd + 8) = wc; *(float4*)(wd + 12) = wdv; }

#define MMA32() { \
        _Pragma("unroll 8") \
        for (int kk = 0; kk < KC; ++kk) { \
            float4 xv4 = *(const float4*)&XsT[kk][e4]; \
            float4 wv4 = *(const float4*)&Ws[kk][c4]; \
            float xv[4] = {xv4.x, xv4.y, xv4.z, xv4.w}; \
            float wv[4] = {wv4.x, wv4.y, wv4.z, wv4.w}; \
            for (int i = 0; i < 4; ++i) \
                for (int j = 0; j < 4; ++j) acc[i][j] = fmaf(xv[i], wv[j], acc[i][j]); } }

// stats write: into replica (blockIdx & (SREP-1))
#define STATS_TO(SOUT) { \
        __syncthreads(); \
        const int rep_ = (blockIdx.x & (SREP - 1)) * SSTRIDE; \
        for (int j = 0; j < 4; ++j) { \
            float s = 0.f, q = 0.f; \
            for (int i = 0; i < 4; ++i) \
                if (e4 + i < valid) { float a = acc[i][j]; s += a; q += a * a; } \
            part_s[grp][c4 + j] = s; part_q[grp][c4 + j] = q; \
        } \
        __syncthreads(); \
        if (tid < EMBD) { \
            float S = 0.f, Q = 0.f; \
            for (int g = 0; g < 8; ++g) { S += part_s[g][tid]; Q += part_q[g][tid]; } \
            atomicAdd(&(SOUT)[rep_ + tid], S); \
            atomicAdd(&(SOUT)[rep_ + EMBD + tid], Q); } }

// stats read: fold SREP replicas (L2-hot)
#define LOAD_AFF(SRC, GG, BB, SS, CC, DEN) { \
        float sm_ = 0.f, sq_ = 0.f; \
        _Pragma("unroll 8") \
        for (int r_ = 0; r_ < SREP; ++r_) { \
            sm_ += (SRC)[r_ * SSTRIDE + tid]; \
            sq_ += (SRC)[r_ * SSTRIDE + EMBD + tid]; } \
        float m_ = sm_ * (DEN); \
        float v_ = fmaxf(sq_ * (DEN) - m_ * m_, 0.f); \
        float s_ = (GG)[tid] * rsqrtf(v_ + BN_EPS); \
        (SS)[tid] = s_; (CC)[tid] = (BB)[tid] - m_ * s_; }

// Rebuild post-BN1 a1 into XsT from UV (fp16) + dist.  (rc fallback only)
#define REBUILD_XST(K0) { \
        int k = (K0) + kl; \
        float4 u4 = ld4h(uv + (size_t)dst_s[e_st] * 256 + k); \
        float4 v4 = ld4h(uv + (size_t)src_s[e_st] * 256 + 128 + k); \
        float4 wd = *(const float4*)(W1 + (size_t)(2 * EMBD) * EMBD + k); \
        float dd_ = dist_s[e_st]; \
        float r0_ = fmaf(dd_, wd.x, u4.x + v4.x); \
        float r1_ = fmaf(dd_, wd.y, u4.y + v4.y); \
        float r2_ = fmaf(dd_, wd.z, u4.z + v4.z); \
        float r3_ = fmaf(dd_, wd.w, u4.w + v4.w); \
        XsT[kl + 0][e_st] = fmaxf(fmaf(r0_, sA_s[k + 0], sA_c[k + 0]), 0.f); \
        XsT[kl + 1][e_st] = fmaxf(fmaf(r1_, sA_s[k + 1], sA_c[k + 1]), 0.f); \
        XsT[kl + 2][e_st] = fmaxf(fmaf(r2_, sA_s[k + 2], sA_c[k + 2]), 0.f); \
        XsT[kl + 3][e_st] = fmaxf(fmaf(r3_, sA_s[k + 3], sA_c[k + 3]), 0.f); }

#define EDGE_META(WITH_SRC) { \
        if (tid < TE) { \
            int e = r0 + tid; if (e >= E) e = E - 1; \
            int dj = srcI[e], di = dstI[e]; \
            if ((u32)dj >= (u32)Nn) dj = 0; \
            if ((u32)di >= (u32)Nn) di = 0; \
            dst_s[tid] = di; \
            if (WITH_SRC) { \
                src_s[tid] = dj; \
                float2 pj = *(const float2*)(pos + (size_t)dj * 2); \
                float2 pi = *(const float2*)(pos + (size_t)di * 2); \
                float dx = pj.x - pi.x, dy = pj.y - pi.y; \
                dist_s[tid] = sqrtf(dx * dx + dy * dy); } } }

// ================================================================== k_uv
// U = h @ W1[0:128] (dst part), V = h @ W1[128:256] (src part), fp16 out.
__global__ __launch_bounds__(256) void k_uv(
    const float* __restrict__ h, const float* __restrict__ W1,
    f16* __restrict__ uv, float* trace, float bit, int Nn)
{
    trace_mark(trace, bit);
    __shared__ float XsT[KC][TE];
    __shared__ float Ws[KC][EMBD];

    const int tid = threadIdx.x;
    const int r0 = blockIdx.x * TE;
    int valid = Nn - r0; if (valid > TE) valid = TE;

    const int e_st = tid >> 3, kl = (tid & 7) << 2;
    const int kw = tid >> 3, cw = (tid & 7) << 4;
    const int e4 = (tid >> 5) << 2, c4 = (tid & 31) << 2;

    for (int pass = 0; pass < 2; ++pass) {
        float acc[4][4];
#pragma unroll
        for (int i = 0; i < 4; ++i)
#pragma unroll
            for (int j = 0; j < 4; ++j) acc[i][j] = 0.f;

        const float* Wp = W1 + (size_t)pass * EMBD * EMBD;
        for (int k0 = 0; k0 < EMBD; k0 += KC) {
            {
                float4 x = make_float4(0.f, 0.f, 0.f, 0.f);
                if (e_st < valid)
                    x = *(const float4*)(h + (size_t)(r0 + e_st) * EMBD + k0 + kl);
                XsT[kl + 0][e_st] = x.x; XsT[kl + 1][e_st] = x.y;
                XsT[kl + 2][e_st] = x.z; XsT[kl + 3][e_st] = x.w;
            }
            STAGE_W(Wp, k0);
            __syncthreads();
            MMA32();
            __syncthreads();
        }
#pragma unroll
        for (int i = 0; i < 4; ++i)
            if (e4 + i < valid)
                st4h(uv + (size_t)(r0 + e4 + i) * 256 + pass * EMBD + c4,
                     make_float4(acc[i][0], acc[i][1], acc[i][2], acc[i][3]));
    }
}

// ================================================================== k_count
__global__ __launch_bounds__(256) void k_count(
    const int* __restrict__ dstI, int* __restrict__ cnti,
    float* trace, float bit, int E, int Nn)
{
    trace_mark(trace, bit);
    int e = blockIdx.x * 256 + threadIdx.x;
    if (e >= E) return;
    int di = dstI[e];
    if ((u32)di >= (u32)Nn) di = 0;
    atomicAdd(&cnti[di], 1);
}

// ================================================================= k_scan1
// Per-block LDS scan of 1024 counts: local exclusive prefix -> offs, block
// total -> bsum.  49 blocks in parallel (vs R16's single-block serial).
__global__ __launch_bounds__(1024) void k_scan1(
    const int* __restrict__ cnti, int* __restrict__ offs,
    int* __restrict__ bsum, float* trace, float bit, int Nn)
{
    trace_mark(trace, bit);
    __shared__ int buf[1024];
    const int tid = threadIdx.x;
    const int gid = blockIdx.x * 1024 + tid;
    int v = (gid < Nn) ? cnti[gid] : 0;
    buf[tid] = v;
    __syncthreads();
    for (int d = 1; d < 1024; d <<= 1) {
        int t = (tid >= d) ? buf[tid - d] : 0;
        __syncthreads();
        buf[tid] += t;
        __syncthreads();
    }
    if (gid < Nn) offs[gid] = buf[tid] - v;      // block-local exclusive
    if (tid == 1023) bsum[blockIdx.x] = buf[1023];
}

// ================================================================= k_scan2
// Exclusive scan of block totals (nb <= 1024). 1 tiny block.
__global__ __launch_bounds__(1024) void k_scan2(
    int* __restrict__ bsum, int* __restrict__ offs,
    float* trace, float bit, int nb, int Nn)
{
    trace_mark(trace, bit);
    __shared__ int buf[1024];
    const int tid = threadIdx.x;
    int v = (tid < nb) ? bsum[tid] : 0;
    buf[tid] = v;
    __syncthreads();
    for (int d = 1; d < 1024; d <<= 1) {
        int t = (tid >= d) ? buf[tid - d] : 0;
        __syncthreads();
        buf[tid] += t;
        __syncthreads();
    }
    if (tid < nb) bsum[tid] = buf[tid] - v;      // exclusive
    if (tid == 1023) offs[Nn] = buf[1023];       // grand total (== E)
}

// ================================================================= k_scan3
// offs[gid] += bsum[block]; cursor mirror.
__global__ __launch_bounds__(1024) void k_scan3(
    int* __restrict__ offs, int* __restrict__ cursor,
    const int* __restrict__ bsum, float* trace, float bit, int Nn)
{
    trace_mark(trace, bit);
    const int gid = blockIdx.x * 1024 + threadIdx.x;
    if (gid >= Nn) return;
    int o = offs[gid] + bsum[blockIdx.x];
    offs[gid] = o;
    cursor[gid] = o;
}

// =============================================================== k_scatter
// Permutation: p = cursor[dst]++ ; srcp[p]/dstp[p] = endpoints ; eidx for rc.
__global__ __launch_bounds__(256) void k_scatter(
    const int* __restrict__ srcI, const int* __restrict__ dstI,
    int* __restrict__ cursor, int* __restrict__ eidx,
    int* __restrict__ srcp, int* __restrict__ dstp,
    float* trace, float bit, int E, int Nn)
{
    trace_mark(trace, bit);
    int e = blockIdx.x * 256 + threadIdx.x;
    if (e >= E) return;
    int di = dstI[e], sj = srcI[e];
    if ((u32)di >= (u32)Nn) di = 0;
    if ((u32)sj >= (u32)Nn) sj = 0;
    int p = atomicAdd(&cursor[di], 1);
    eidx[p] = e;
    srcp[p] = sj;
    dstp[p] = di;
}

// ================================================================== k_t1
// WAVE-PER-EDGE gather: t1[k] = U[dstp[k]] + V[srcp[k]] + dist*w1d, stored
// raw fp16 in permuted order; stats1 into replica slot.
#define TB 64
__global__ __launch_bounds__(256) void k_t1(
    const f16* __restrict__ uv, const float* __restrict__ pos,
    const int* __restrict__ srcp, const int* __restrict__ dstp,
    const float* __restrict__ W1, float* stats_out,
    f16* __restrict__ t1out, float* trace, float bit, int E, int Nn)
{
    trace_mark(trace, bit);
    __shared__ int ds[TB], ss[TB];
    __shared__ float dd[TB];
    __shared__ float ps[4][EMBD], pq[4][EMBD];

    const int tid = threadIdx.x;
    const int r0 = blockIdx.x * TB;

    if (tid < TB) {
        int e = r0 + tid; if (e >= E) e = E - 1;
        int dj = srcp[e], di = dstp[e];
        ds[tid] = di; ss[tid] = dj;
        float2 pj = *(const float2*)(pos + (size_t)dj * 2);
        float2 pi = *(const float2*)(pos + (size_t)di * 2);
        float dx = pj.x - pi.x, dy = pj.y - pi.y;
        dd[tid] = sqrtf(dx * dx + dy * dy);
    }
    __syncthreads();

    const int lane = tid & 63, wv = tid >> 6;
    const int c0 = lane * 2;
    const float w0 = W1[(size_t)(2 * EMBD) * EMBD + c0];
    const float w1 = W1[(size_t)(2 * EMBD) * EMBD + c0 + 1];

    float S0 = 0.f, Q0 = 0.f, S1 = 0.f, Q1 = 0.f;
#pragma unroll
    for (int i = 0; i < 16; ++i) {
        const int el = wv * 16 + i;
        const int e = r0 + el;
        f16x2 u2 = *(const f16x2*)(uv + (size_t)ds[el] * 256 + c0);
        f16x2 v2 = *(const f16x2*)(uv + (size_t)ss[el] * 256 + 128 + c0);
        float d = dd[el];
        float t0 = fmaf(d, w0, (float)u2.x + (float)v2.x);
        float t1v = fmaf(d, w1, (float)u2.y + (float)v2.y);
        if (e < E) {
            S0 += t0; Q0 += t0 * t0;
            S1 += t1v; Q1 += t1v * t1v;
            f16x2 o; o.x = (f16)t0; o.y = (f16)t1v;
            *(f16x2*)(t1out + (size_t)e * EMBD + c0) = o;
        }
    }
    ps[wv][c0] = S0; ps[wv][c0 + 1] = S1;
    pq[wv][c0] = Q0; pq[wv][c0 + 1] = Q1;
    __syncthreads();
    const int rep = (blockIdx.x & (SREP - 1)) * SSTRIDE;
    if (tid < EMBD) {
        atomicAdd(&stats_out[rep + tid], ps[0][tid] + ps[1][tid] + ps[2][tid] + ps[3][tid]);
        atomicAdd(&stats_out[rep + EMBD + tid], pq[0][tid] + pq[1][tid] + pq[2][tid] + pq[3][tid]);
    }
}
#undef TB

// =============================================================== k_stats1
// rc fallback only: stats1 over permuted t1 (no staging buffer available).
#define SB 128
__global__ __launch_bounds__(256) void k_stats1(
    const f16* __restrict__ uv, const float* __restrict__ pos,
    const int* __restrict__ srcp, const int* __restrict__ dstp,
    const float* __restrict__ W1, float* stats_out,
    float* trace, float bit, int E, int Nn)
{
    trace_mark(trace, bit);
    __shared__ int ds[SB], ss[SB];
    __shared__ float dd[SB];
    __shared__ float ps[2][EMBD], pq[2][EMBD];

    const int tid = threadIdx.x;
    const int r0 = blockIdx.x * SB;

    if (tid < SB) {
        int e = r0 + tid; if (e >= E) e = E - 1;
        int dj = srcp[e], di = dstp[e];
        ds[tid] = di; ss[tid] = dj;
        float2 pj = *(const float2*)(pos + (size_t)dj * 2);
        float2 pi = *(const float2*)(pos + (size_t)di * 2);
        float dx = pj.x - pi.x, dy = pj.y - pi.y;
        dd[tid] = sqrtf(dx * dx + dy * dy);
    }
    __syncthreads();

    const int c = tid & 127, hh = tid >> 7;
    const float w1d = W1[(size_t)(2 * EMBD) * EMBD + c];
    float S = 0.f, Q = 0.f;
#pragma unroll 4
    for (int i = 0; i < 64; ++i) {
        int el = hh * 64 + i;
        int e = r0 + el;
        if (e < E) {
            float u = (float)uv[(size_t)ds[el] * 256 + c];
            float v = (float)uv[(size_t)ss[el] * 256 + 128 + c];
            float t = fmaf(dd[el], w1d, u + v);
            S += t; Q += t * t;
        }
    }
    ps[hh][c] = S; pq[hh][c] = Q;
    __syncthreads();
    const int rep = (blockIdx.x & (SREP - 1)) * SSTRIDE;
    if (tid < EMBD) {
        atomicAdd(&stats_out[rep + tid], ps[0][tid] + ps[1][tid]);
        atomicAdd(&stats_out[rep + EMBD + tid], pq[0][tid] + pq[1][tid]);
    }
}
#undef SB

// ================================================================== k_prep
// Transpose W2/Wp1 to fp16 MFMA B-frag-slot order.
__global__ __launch_bounds__(256) void k_prep(
    const float* __restrict__ W2, const float* __restrict__ Wp1,
    f16* __restrict__ wtf2, f16* __restrict__ wtf3, float* trace, float bit)
{
    trace_mark(trace, bit);
    int id = blockIdx.x * 256 + threadIdx.x;   // 64 blocks -> 16384
    int k = id >> 7, n = id & 127;
    size_t s = ((size_t)(k >> 3) * 128 + n) * 8 + (k & 7);
    wtf2[s] = (f16)W2[(size_t)k * 128 + n];
    wtf3[s] = (f16)Wp1[(size_t)k * 128 + n];
}

// ================================================================== k_gm
// Streaming MFMA mid GEMM: a = relu(bn(tin_raw)); tout_raw = a @ W; stats
// into replica; IN-PLACE safe.
__global__ __launch_bounds__(256) void k_gm(
    const f16* __restrict__ tin, const f16* __restrict__ wtf,
    const float* g, const float* b,
    const float* __restrict__ stats_in, float* stats_out,
    f16* __restrict__ tout, float* trace, float bit, int E)
{
    trace_mark(trace, bit);
    __shared__ __align__(16) f16 bsh[16384];
    __shared__ float sB_s[EMBD], sB_c[EMBD];
    __shared__ float ps[4][EMBD], pq[4][EMBD];

    const int tid = threadIdx.x;
    const int r0 = blockIdx.x * 64;

    if (tid < EMBD) {
        const float invE = 1.f / (float)E;
        LOAD_AFF(stats_in, g, b, sB_s, sB_c, invE);
    }
    {
        const float4* s4 = (const float4*)wtf;
        float4* d4 = (float4*)bsh;
#pragma unroll
        for (int i = 0; i < 8; ++i) d4[i * 256 + tid] = s4[i * 256 + tid];
    }
    __syncthreads();

    const int wv = tid >> 6, lane = tid & 63;
    const int lm = lane & 15, lg = lane >> 4;
    int grA = r0 + wv * 16 + lm; if (grA >= E) grA = E - 1;

    fx4_t acc[8];
#pragma unroll
    for (int c = 0; c < 8; ++c) acc[c] = (fx4_t){0.f, 0.f, 0.f, 0.f};

#pragma unroll
    for (int ks = 0; ks < 4; ++ks) {
        const int k0 = ks * 32 + lg * 8;
        hf8_t x8 = *(const hf8_t*)(tin + (size_t)grA * 128 + k0);
        hf8_t af;
#pragma unroll
        for (int e = 0; e < 8; ++e) {
            int k = k0 + e;
            af[e] = (f16)fmaxf(fmaf((float)x8[e], sB_s[k], sB_c[k]), 0.f);
        }
        const f16* bb = bsh + (size_t)(ks * 4 + lg) * 128 * 8;
#pragma unroll
        for (int c = 0; c < 8; ++c) {
            hf8_t bf = *(const hf8_t*)(bb + (size_t)(c * 16 + lm) * 8);
            acc[c] = __builtin_amdgcn_mfma_f32_16x16x32_f16(af, bf, acc[c], 0, 0, 0);
        }
    }

    const int rbase = wv * 16 + lg * 4;
#pragma unroll
    for (int c = 0; c < 8; ++c) {
        float s = 0.f, q = 0.f;
#pragma unroll
        for (int r = 0; r < 4; ++r)
            if (r0 + rbase + r < E) { float a = acc[c][r]; s += a; q += a * a; }
        s += __shfl_xor(s, 16, 64); q += __shfl_xor(q, 16, 64);
        s += __shfl_xor(s, 32, 64); q += __shfl_xor(q, 32, 64);
        if (lg == 0) { ps[wv][c * 16 + lm] = s; pq[wv][c * 16 + lm] = q; }
    }
    __syncthreads();
    const int rep = (blockIdx.x & (SREP - 1)) * SSTRIDE;
    if (tid < EMBD) {
        atomicAdd(&stats_out[rep + tid], ps[0][tid] + ps[1][tid] + ps[2][tid] + ps[3][tid]);
        atomicAdd(&stats_out[rep + EMBD + tid], pq[0][tid] + pq[1][tid] + pq[2][tid] + pq[3][tid]);
    }

    f16* otile = bsh;
#pragma unroll
    for (int c = 0; c < 8; ++c) {
        int col = c * 16 + lm;
#pragma unroll
        for (int r = 0; r < 4; ++r)
            otile[(size_t)(rbase + r) * 136 + col] = (f16)acc[c][r];
    }
    __syncthreads();
#pragma unroll
    for (int it = 0; it < 4; ++it) {
        int row = it * 16 + (tid >> 4), ch = tid & 15;
        int gr = r0 + row;
        if (gr < E)
            *(float4*)(tout + (size_t)gr * 128 + ch * 8) =
                *(const float4*)(otile + (size_t)row * 136 + ch * 8);
    }
}

// ================================================================== k_aggr
// Contiguous segment-sum over permuted t2: h_aggr[n] = sum relu(bn2(t2[k])).
__global__ __launch_bounds__(256) void k_aggr(
    const f16* __restrict__ t2, const int* __restrict__ offs,
    const float* g2, const float* b2, const float* __restrict__ stats_in,
    float* __restrict__ h_aggr, float* trace, float bit, int E, int Nn)
{
    trace_mark(trace, bit);
    __shared__ float sB_s[EMBD], sB_c[EMBD];
    const int tid = threadIdx.x;
    if (tid < EMBD) {
        const float invE = 1.f / (float)E;
        LOAD_AFF(stats_in, g2, b2, sB_s, sB_c, invE);
    }
    __syncthreads();

    const int lane = tid & 63;
    const int node = blockIdx.x * 4 + (tid >> 6);
    if (node >= Nn) return;

    const int c0 = lane * 2;
    const float s0 = sB_s[c0], s1 = sB_s[c0 + 1];
    const float cc0 = sB_c[c0], cc1 = sB_c[c0 + 1];
    const int o0 = offs[node], o1 = offs[node + 1];

    float a0 = 0.f, a1 = 0.f;
    for (int k = o0; k < o1; ++k) {
        f16x2 xv = *(const f16x2*)(t2 + (size_t)k * EMBD + c0);
        a0 += fmaxf(fmaf((float)xv.x, s0, cc0), 0.f);
        a1 += fmaxf(fmaf((float)xv.y, s1, cc1), 0.f);
    }
    *(float2*)(h_aggr + (size_t)node * EMBD + c0) = make_float2(a0, a1);
}

// ================================================================== k_dot
__global__ __launch_bounds__(256) void k_dot(
    const f16* __restrict__ t3, const float* __restrict__ Wp2,
    const float* g3, const float* b3,
    const float* __restrict__ stats_in, float* stats_out, float* t4,
    float* trace, float bit, int E)
{
    trace_mark(trace, bit);
    __shared__ float sC_s[EMBD], sC_c[EMBD];
    __shared__ float red[256];
    __shared__ float dotbuf[TE];

    const int tid = threadIdx.x;
    const int r0 = blockIdx.x * TE;
    int valid = E - r0; if (valid > TE) valid = TE;

    if (tid < EMBD) {
        const float invE = 1.f / (float)E;
        LOAD_AFF(stats_in, g3, b3, sC_s, sC_c, invE);
    }
    __syncthreads();

    const int row = tid >> 3, c0 = (tid & 7) << 4;
    int e = r0 + row; if (e >= E) e = E - 1;
    const f16* tp = t3 + (size_t)e * EMBD + c0;

    float part = 0.f;
#pragma unroll
    for (int q = 0; q < 4; ++q) {
        float4 x = ld4h(tp + q * 4);
        float4 w = *(const float4*)(Wp2 + c0 + q * 4);
        int c = c0 + q * 4;
        part = fmaf(fmaxf(fmaf(x.x, sC_s[c + 0], sC_c[c + 0]), 0.f), w.x, part);
        part = fmaf(fmaxf(fmaf(x.y, sC_s[c + 1], sC_c[c + 1]), 0.f), w.y, part);
        part = fmaf(fmaxf(fmaf(x.z, sC_s[c + 2], sC_c[c + 2]), 0.f), w.z, part);
        part = fmaf(fmaxf(fmaf(x.w, sC_s[c + 3], sC_c[c + 3]), 0.f), w.w, part);
    }
    red[tid] = part;
    __syncthreads();
    if ((tid & 7) == 0) {
        float dot = red[tid] + red[tid+1] + red[tid+2] + red[tid+3]
                  + red[tid+4] + red[tid+5] + red[tid+6] + red[tid+7];
        dotbuf[row] = dot;
        if (row < valid) t4[r0 + row] = dot;
    }
    __syncthreads();
    if (tid == 0) {
        float S = 0.f, Q = 0.f;
        for (int r = 0; r < valid; ++r) { float d = dotbuf[r]; S += d; Q += d * d; }
        const int rep = (blockIdx.x & (SREP - 1)) * SSTRIDE;
        atomicAdd(&stats_out[rep + 0], S);
        atomicAdd(&stats_out[rep + EMBD], Q);
    }
}

// ============================================================= k_pos_aggr
// PERM=1: t4/srcp permuted (streaming). PERM=0: rc tier via eidx.
template<int PERM>
__global__ __launch_bounds__(256) void k_pos_aggr(
    const float* __restrict__ t4, const int* __restrict__ offs,
    const int* __restrict__ eidx, const int* __restrict__ srcp,
    const int* __restrict__ srcI,
    const float* __restrict__ pos, const float* __restrict__ stats_base,
    const float* gp2, const float* bbp2,
    float* __restrict__ x_aggr, float* trace, float bit, int E, int Nn)
{
    trace_mark(trace, bit);
    const int tid = threadIdx.x;
    const int lane = tid & 63;
    const int node = blockIdx.x * 4 + (tid >> 6);
    if (node >= Nn) return;

    const float invE = 1.f / (float)E;
    float sm = 0.f, sq = 0.f;
#pragma unroll 8
    for (int r = 0; r < SREP; ++r) {
        sm += stats_base[r * SSTRIDE + 768];
        sq += stats_base[r * SSTRIDE + 768 + EMBD];
    }
    float m = sm * invE;
    float v = fmaxf(sq * invE - m * m, 0.f);
    float s3 = gp2[0] * rsqrtf(v + BN_EPS);
    float c3 = bbp2[0] - m * s3;

    const int o0 = offs[node], o1 = offs[node + 1];
    float2 pi = *(const float2*)(pos + (size_t)node * 2);
    float ax = 0.f, ay = 0.f;
    for (int k = o0 + lane; k < o1; k += 64) {
        float s; int j;
        if (PERM) {
            s = fmaxf(fmaf(t4[k], s3, c3), 0.f);
            j = srcp[k];
        } else {
            int e = eidx[k];
            s = fmaxf(fmaf(t4[e], s3, c3), 0.f);
            j = srcI[e];
            if ((u32)j >= (u32)Nn) j = 0;
        }
        float2 pj = *(const float2*)(pos + (size_t)j * 2);
        ax += (pj.x - pi.x) * s;
        ay += (pj.y - pi.y) * s;
    }
#pragma unroll
    for (int off = 32; off; off >>= 1) {
        ax += __shfl_down(ax, off, 64);
        ay += __shfl_down(ay, off, 64);
    }
    if (lane == 0) {
        float inv = 1.f / fmaxf((float)(o1 - o0), 1.f);
        *(float2*)(x_aggr + (size_t)node * 2) = make_float2(ax * inv, ay * inv);
    }
}

// ============================================================== k_edge_rc
// Recompute tier (small ws) — original edge order.
template<int DEPTH>
__global__ __launch_bounds__(256) void k_edge_rc(
    const f16* __restrict__ uv,
    const int* __restrict__ srcI, const int* __restrict__ dstI,
    const float* __restrict__ pos,
    const float* __restrict__ W1, const float* __restrict__ W2,
    const float* __restrict__ W3, const float* __restrict__ Wp2,
    const float* g1, const float* b1, const float* g2, const float* b2,
    const float* g3, const float* b3,
    const float* __restrict__ stats_base, float* stats_out,
    float* h_aggr, float* t4_out,
    float* trace, float bit, int E, int Nn)
{
    trace_mark(trace, bit);
    __shared__ float XsT[KC][TE];
    __shared__ float Ws[KC][EMBD];
    __shared__ float A[(DEPTH >= 3) ? TE : 1][EMBD + 4];
    __shared__ float part_s[8][EMBD];
    __shared__ float part_q[8][EMBD];
    __shared__ float red[(DEPTH >= 4) ? 256 : 1];
    __shared__ float dotbuf[(DEPTH >= 4) ? TE : 1];
    __shared__ float sA_s[EMBD], sA_c[EMBD];
    __shared__ float sB_s[(DEPTH >= 3) ? EMBD : 1], sB_c[(DEPTH >= 3) ? EMBD : 1];
    __shared__ float sC_s[(DEPTH >= 4) ? EMBD : 1], sC_c[(DEPTH >= 4) ? EMBD : 1];
    __shared__ int dst_s[TE], src_s[TE];
    __shared__ float dist_s[TE];

    const int tid = threadIdx.x;
    const int r0 = blockIdx.x * TE;
    int valid = E - r0; if (valid > TE) valid = TE;

    if (tid < EMBD) {
        const float invE = 1.f / (float)E;
        LOAD_AFF(stats_base, g1, b1, sA_s, sA_c, invE);
        if (DEPTH >= 3) LOAD_AFF(stats_base + 256, g2, b2, sB_s, sB_c, invE);
        if (DEPTH >= 4) LOAD_AFF(stats_base + 512, g3, b3, sC_s, sC_c, invE);
    }
    EDGE_META(1);
    __syncthreads();

    const int e_st = tid >> 3, kl = (tid & 7) << 2;
    const int kw = tid >> 3, cw = (tid & 7) << 4;
    const int e4 = (tid >> 5) << 2, c4 = (tid & 31) << 2;
    const int grp = tid >> 5;

    float acc[4][4];
#pragma unroll
    for (int i = 0; i < 4; ++i)
#pragma unroll
        for (int j = 0; j < 4; ++j) acc[i][j] = 0.f;

    for (int k0 = 0; k0 < EMBD; k0 += KC) {
        REBUILD_XST(k0);
        STAGE_W(W2, k0);
        __syncthreads();
        MMA32();
        __syncthreads();
    }

    if (DEPTH == 2) { STATS_TO(stats_out); return; }

#pragma unroll
    for (int i = 0; i < 4; ++i) {
        float4 o;
#pragma unroll
        for (int j = 0; j < 4; ++j) {
            float v = fmaxf(fmaf(acc[i][j], sB_s[c4 + j], sB_c[c4 + j]), 0.f);
            (&o.x)[j] = v;
            if (DEPTH == 3 && (e4 + i) < valid)
                atomicAdd(&h_aggr[(size_t)dst_s[e4 + i] * EMBD + c4 + j], v);
        }
        *(float4*)&A[e4 + i][c4] = o;
    }
    __syncthreads();

#pragma unroll
    for (int i = 0; i < 4; ++i)
#pragma unroll
        for (int j = 0; j < 4; ++j) acc[i][j] = 0.f;
    for (int k0 = 0; k0 < EMBD; k0 += KC) {
        STAGE_W(W3, k0);
        __syncthreads();
#pragma unroll 8
        for (int kk = 0; kk < KC; ++kk) {
            float4 wv4 = *(const float4*)&Ws[kk][c4];
            float wv[4] = {wv4.x, wv4.y, wv4.z, wv4.w};
            float xv[4];
#pragma unroll
            for (int i = 0; i < 4; ++i) xv[i] = A[e4 + i][k0 + kk];
#pragma unroll
            for (int i = 0; i < 4; ++i)
#pragma unroll
                for (int j = 0; j < 4; ++j) acc[i][j] = fmaf(xv[i], wv[j], acc[i][j]);
        }
        __syncthreads();
    }

    if (DEPTH == 3) { STATS_TO(stats_out); return; }

#pragma unroll
    for (int i = 0; i < 4; ++i) {
        float4 o;
#pragma unroll
        for (int j = 0; j < 4; ++j)
            (&o.x)[j] = fmaxf(fmaf(acc[i][j], sC_s[c4 + j], sC_c[c4 + j]), 0.f);
        *(float4*)&A[e4 + i][c4] = o;
    }
    __syncthreads();

    {
        const int row = tid >> 3, c0 = (tid & 7) << 4;
        float w[16];
        *(float4*)(w + 0)  = *(const float4*)(Wp2 + c0);
        *(float4*)(w + 4)  = *(const float4*)(Wp2 + c0 + 4);
        *(float4*)(w + 8)  = *(const float4*)(Wp2 + c0 + 8);
        *(float4*)(w + 12) = *(const float4*)(Wp2 + c0 + 12);
        float part = 0.f;
#pragma unroll
        for (int c = 0; c < 16; ++c) part = fmaf(A[row][c0 + c], w[c], part);
        red[tid] = part;
        __syncthreads();
        if ((tid & 7) == 0) {
            float dot = red[tid] + red[tid+1] + red[tid+2] + red[tid+3]
                      + red[tid+4] + red[tid+5] + red[tid+6] + red[tid+7];
            dotbuf[row] = dot;
            if (row < valid) t4_out[r0 + row] = dot;
        }
        __syncthreads();
        if (tid == 0) {
            float S = 0.f, Q = 0.f;
            for (int r = 0; r < valid; ++r) { float d = dotbuf[r]; S += d; Q += d * d; }
            const int rep = (blockIdx.x & (SREP - 1)) * SSTRIDE;
            atomicAdd(&stats_out[rep + 0], S);
            atomicAdd(&stats_out[rep + EMBD], Q);
        }
    }
}

// =============================================================== node GEMM
__global__ __launch_bounds__(256) void k_upd(
    const float* h, const float* h_aggr, const float* W,
    float* stats_out, float* t5, float* trace, float bit, int Nn)
{
    trace_mark(trace, bit);
    __shared__ float XsT[KC][TE];
    __shared__ float Ws[KC][EMBD];
    __shared__ float part_s[8][EMBD];
    __shared__ float part_q[8][EMBD];

    const int tid = threadIdx.x;
    const int r0 = blockIdx.x * TE;
    int valid = Nn - r0; if (valid > TE) valid = TE;

    float acc[4][4];
#pragma unroll
    for (int i = 0; i < 4; ++i)
#pragma unroll
        for (int j = 0; j < 4; ++j) acc[i][j] = 0.f;

    const int e_st = tid >> 3, kl = (tid & 7) << 2;
    const int kw = tid >> 3, cw = (tid & 7) << 4;
    const int e4 = (tid >> 5) << 2, c4 = (tid & 31) << 2;
    const int grp = tid >> 5;

    for (int k0 = 0; k0 < 2 * EMBD; k0 += KC) {
        {
            float4 x = make_float4(0.f, 0.f, 0.f, 0.f);
            if (e_st < valid) {
                int k = k0 + kl;
                int row = r0 + e_st;
                const float* base = (k < EMBD)
                    ? h + (size_t)row * EMBD + k
                    : h_aggr + (size_t)row * EMBD + (k - EMBD);
                x = *(const float4*)base;
            }
            XsT[kl + 0][e_st] = x.x; XsT[kl + 1][e_st] = x.y;
            XsT[kl + 2][e_st] = x.z; XsT[kl + 3][e_st] = x.w;
        }
        STAGE_W(W, k0);
        __syncthreads();
        MMA32();
        __syncthreads();
    }

    STATS_TO(stats_out);

#pragma unroll
    for (int i = 0; i < 4; ++i) {
        int row = r0 + e4 + i;
        if (e4 + i < valid)
            *(float4*)(t5 + (size_t)row * EMBD + c4) =
                make_float4(acc[i][0], acc[i][1], acc[i][2], acc[i][3]);
    }
}

// ---------------------------------------------------------------- epilogue
__global__ __launch_bounds__(256) void k_final(
    const float* h, const float* pos, const float* stats5,
    const float* gu1, const float* bbu1,
    const float* x_aggr, const float* trace,
    float* out, int N, float expect)
{
    __shared__ float s4[EMBD], cc4[EMBD];
    int tid = threadIdx.x;
    if (tid < EMBD) {
        const float invN = 1.f / (float)N;
        LOAD_AFF(stats5, gu1, bbu1, s4, cc4, invN);
    }
    __syncthreads();
    int n = blockIdx.x * 2 + (tid >> 7);
    int c = tid & 127;
    if (n >= N) return;
    float hv = h[(size_t)n * EMBD + c];
    float t = out[(size_t)n * EMBD + c];
    float res = sane(hv + fmaxf(fmaf(t, s4[c], cc4[c]), 0.f), 100.f);
    if (n == 0 && c == 1) {
        float tr = trace[0];
        if (fabsf(tr - expect) > 0.5f) res = 1048576.0f + tr * 64.0f;
    }
    out[(size_t)n * EMBD + c] = res;
    if (c < 2) {
        float p = pos[(size_t)n * 2 + c];
        float xa = x_aggr[(size_t)n * 2 + c];
        out[(size_t)N * EMBD + (size_t)n * 2 + c] = sane(p + xa, 100.f);
    }
}

// ================================================================= launch
extern "C" void kernel_launch(void* const* d_in, const int* in_sizes, int n_in,
                              void* d_out, int out_size, void* d_ws, size_t ws_size,
                              hipStream_t stream)
{
    const float* h   = (const float*)d_in[0];
    const float* pos = (const float*)d_in[1];
    const int* ei    = (const int*)d_in[3];
    const float* Wm1 = (const float*)d_in[4];
    const float* gm1 = (const float*)d_in[6];
    const float* bbm1= (const float*)d_in[7];
    const float* Wm2 = (const float*)d_in[8];
    const float* gm2 = (const float*)d_in[10];
    const float* bbm2= (const float*)d_in[11];
    const float* Wp1 = (const float*)d_in[12];
    const float* gp1 = (const float*)d_in[14];
    const float* bbp1= (const float*)d_in[15];
    const float* Wp2 = (const float*)d_in[16];
    const float* gp2 = (const float*)d_in[18];
    const float* bbp2= (const float*)d_in[19];
    const float* Wu1 = (const float*)d_in[20];
    const float* gu1 = (const float*)d_in[22];
    const float* bbu1= (const float*)d_in[23];

    const int N = in_sizes[0] / EMBD;
    const int E = in_sizes[3] / 2;
    const int* srcI = ei;
    const int* dstI = ei + E;

    size_t off = 0;
    auto carve = [&](size_t bytes) -> size_t {
        size_t o = off; off += (bytes + 255) & ~(size_t)255; return o;
    };
    size_t o_stats  = carve((size_t)SREP * SSTRIDE * sizeof(float));  // 164 KB
    size_t o_trace  = carve(256);
    size_t o_cnti   = carve((size_t)N * sizeof(int));
    size_t zero_small = off;
    size_t o_haggr  = carve((size_t)N * EMBD * sizeof(float));
    size_t zero_need = off;                                  // ~26 MB
    size_t o_xaggr  = carve((size_t)N * 2 * sizeof(float));
    size_t o_t4     = carve((size_t)E * sizeof(float));
    size_t o_offs   = carve((size_t)(N + 1) * sizeof(int));
    size_t o_cursor = carve((size_t)N * sizeof(int));
    size_t o_bsum   = carve(1024 * sizeof(int));
    size_t o_eidx   = carve((size_t)E * sizeof(int));
    size_t o_srcp   = carve((size_t)E * sizeof(int));
    size_t o_dstp   = carve((size_t)E * sizeof(int));
    size_t o_wtf2   = carve(16384 * sizeof(f16));
    size_t o_wtf3   = carve(16384 * sizeof(f16));
    size_t base_need = off;                                  // ~35 MB
    size_t o_ebuf   = carve((size_t)E * EMBD * sizeof(f16)); // +128 MB
    size_t need_staged = off;

    float* out_f = (float*)d_out;

    if (ws_size < base_need) {
        k_fill<<<(out_size + 255) / 256, 256, 0, stream>>>(out_f, 12345678.0f, out_size);
        return;
    }

    char* wsb = (char*)d_ws;
    float* stats  = (float*)(wsb + o_stats);
    float* trace  = (float*)(wsb + o_trace);
    int*   cnti   = (int*)(wsb + o_cnti);
    float* h_aggr = (float*)(wsb + o_haggr);
    float* x_aggr = (float*)(wsb + o_xaggr);
    float* t4     = (float*)(wsb + o_t4);
    int*   offs   = (int*)(wsb + o_offs);
    int*   cursor = (int*)(wsb + o_cursor);
    int*   bsum   = (int*)(wsb + o_bsum);
    int*   eidx   = (int*)(wsb + o_eidx);
    int*   srcp   = (int*)(wsb + o_srcp);
    int*   dstp   = (int*)(wsb + o_dstp);
    f16*   wtf2   = (f16*)(wsb + o_wtf2);
    f16*   wtf3   = (f16*)(wsb + o_wtf3);
    f16*   uv     = (f16*)d_out;   // N*256 fp16 = N*512B <= out bytes

    const bool staged = (ws_size >= need_staged);
    hipMemsetAsync(d_ws, 0, staged ? zero_small : zero_need, stream);

    const int gPE  = (E + 255) / 256;
    const int gE   = (E + TE - 1) / TE;
    const int gE64 = (E + 63) / 64;
    const int gN   = (N + TE - 1) / TE;
    const int gS1  = (E + 127) / 128;
    const int gW   = (N + 3) / 4;
    const int gSC  = (N + 1023) / 1024;

    k_uv<<<gN, 256, 0, stream>>>(h, Wm1, uv, trace, 1.0f, N);
    k_count<<<gPE, 256, 0, stream>>>(dstI, cnti, trace, 2.0f, E, N);
    k_scan1<<<gSC, 1024, 0, stream>>>(cnti, offs, bsum, trace, 4.0f, N);
    k_scan2<<<1, 1024, 0, stream>>>(bsum, offs, trace, 8.0f, gSC, N);
    k_scan3<<<gSC, 1024, 0, stream>>>(offs, cursor, bsum, trace, 16.0f, N);
    k_scatter<<<gPE, 256, 0, stream>>>(srcI, dstI, cursor, eidx, srcp, dstp,
                                       trace, 32.0f, E, N);

    if (staged) {
        f16* eb = (f16*)(wsb + o_ebuf);
        k_t1<<<gE64, 256, 0, stream>>>(uv, pos, srcp, dstp, Wm1,
                                       stats, eb, trace, 64.0f, E, N);
        k_prep<<<64, 256, 0, stream>>>(Wm2, Wp1, wtf2, wtf3, trace, 128.0f);
        k_gm<<<gE64, 256, 0, stream>>>(eb, wtf2, gm1, bbm1,
                                       stats, stats + 256,
                                       eb, trace, 256.0f, E);
        k_aggr<<<gW, 256, 0, stream>>>(eb, offs, gm2, bbm2, stats + 256,
                                       h_aggr, trace, 512.0f, E, N);
        k_gm<<<gE64, 256, 0, stream>>>(eb, wtf3, gm2, bbm2,
                                       stats + 256, stats + 512,
                                       eb, trace, 1024.0f, E);
        k_dot<<<gE, 256, 0, stream>>>(eb, Wp2, gp1, bbp1,
                                      stats + 512, stats + 768, t4,
                                      trace, 2048.0f, E);
        k_pos_aggr<1><<<gW, 256, 0, stream>>>(t4, offs, eidx, srcp, srcI, pos,
                                              stats, gp2, bbp2, x_aggr,
                                              trace, 4096.0f, E, N);
    } else {
        k_stats1<<<gS1, 256, 0, stream>>>(uv, pos, srcp, dstp, Wm1,
                                          stats, trace, 64.0f, E, N);
        k_edge_rc<2><<<gE, 256, 0, stream>>>(uv, srcI, dstI, pos,
                                             Wm1, Wm2, Wp1, Wp2,
                                             gm1, bbm1, gm2, bbm2, gp1, bbp1,
                                             stats, stats + 256, h_aggr, t4,
                                             trace, 128.0f, E, N);
        k_edge_rc<3><<<gE, 256, 0, stream>>>(uv, srcI, dstI, pos,
                                             Wm1, Wm2, Wp1, Wp2,
                                             gm1, bbm1, gm2, bbm2, gp1, bbp1,
                                             stats, stats + 512, h_aggr, t4,
                                             trace, 256.0f, E, N);
        k_edge_rc<4><<<gE, 256, 0, stream>>>(uv, srcI, dstI, pos,
                                             Wm1, Wm2, Wp1, Wp2,
                                             gm1, bbm1, gm2, bbm2, gp1, bbp1,
                                             stats, stats + 768, h_aggr, t4,
                                             trace, 512.0f, E, N);
        k_pos_aggr<0><<<gW, 256, 0, stream>>>(t4, offs, eidx, srcp, srcI, pos,
                                              stats, gp2, bbp2, x_aggr,
                                              trace, 1024.0f, E, N);
    }

    k_upd<<<gN, 256, 0, stream>>>(h, h_aggr, Wu1, stats + 1024, out_f,
                                  trace, staged ? 8192.0f : 2048.0f, N);
    k_final<<<(N + 1) / 2, 256, 0, stream>>>(h, pos, stats + 1024, gu1, bbu1,
                                             x_aggr, trace, out_f, N,
                                             staged ? 16383.0f : 4095.0f);
}

// Round 10
// 609.356 us; speedup vs baseline: 1.2661x; 1.0704x over previous
//
#include <hip/hip_runtime.h>
#include <hip/hip_bf16.h>

// SpatialNCA, MI355X. R18: k_gm row-tiling + packed-f16 BN affine. R17
// counters: k_gm x2 = top dispatches, 81us @ HBM 31%/VALU 32%/Mfma 8% --
// per-block 32KB weight re-staging (7813 blocks) + scalar-f32 A-build VALU.
// Now 256 rows/block (weights staged ONCE, stats in regs across 4 sub-tiles,
// 32-row LDS repack chunk, ~47KB LDS = 3 blocks/CU unchanged) and the BN1/2
// affine computed in packed f16 (v_pk_fma/max, no converts). Rest identical
// to R17. Trace fail-closed: staged expect=16383, rc expect=4095.

#define EMBD 128
#define TE 32
#define KC 32
#define BN_EPS 1e-5f
#define SREP 32
#define SSTRIDE 1280
#define ROWT 4

typedef unsigned int u32;
typedef _Float16 f16;
typedef _Float16 hf8_t __attribute__((ext_vector_type(8)));
typedef float fx4_t __attribute__((ext_vector_type(4)));

__device__ __forceinline__ bool finitef(float f) {
    union { float f; u32 i; } v; v.f = f;
    return ((v.i >> 23) & 0xFFu) != 0xFFu;
}
__device__ __forceinline__ float sane(float f, float lim) {
    if (!finitef(f)) return 0.f;
    return fminf(fmaxf(f, -lim), lim);
}
__device__ __forceinline__ void trace_mark(float* tp, float bit) {
    if (blockIdx.x == 0 && threadIdx.x == 0) atomicAdd(tp, bit);
}

struct f16x4 { f16 a, b, c, d; };
struct alignas(4) f16x2 { f16 x, y; };
__device__ __forceinline__ float4 ld4h(const f16* p) {
    f16x4 t = *(const f16x4*)p;
    return make_float4((float)t.a, (float)t.b, (float)t.c, (float)t.d);
}
__device__ __forceinline__ void st4h(f16* p, float4 v) {
    f16x4 t; t.a = (f16)v.x; t.b = (f16)v.y; t.c = (f16)v.z; t.d = (f16)v.w;
    *(f16x4*)p = t;
}

// ---------------------------------------------------------------- sentinel
__global__ __launch_bounds__(256) void k_fill(float* out, float val, int n) {
    int i = blockIdx.x * 256 + threadIdx.x;
    if (i < n) out[i] = val;
}

// ------------------------------------------------------------ shared macros
#define STAGE_W(WPTR, K0) { \
        const float* wp = (WPTR) + (size_t)((K0) + kw) * EMBD + cw; \
        float4 wa = *(const float4*)wp; \
        float4 wb = *(const float4*)(wp + 4); \
        float4 wc = *(const float4*)(wp + 8); \
        float4 wdv = *(const float4*)(wp + 12); \
        float* wd = &Ws[kw][cw]; \
        *(float4*)(wd + 0) = wa; *(float4*)(wd + 4) = wb; \
        *(float4*)(wd + 8) = wc; *(float4*)(wd + 12) = wdv; }

#define MMA32() { \
        _Pragma("unroll 8") \
        for (int kk = 0; kk < KC; ++kk) { \
            float4 xv4 = *(const float4*)&XsT[kk][e4]; \
            float4 wv4 = *(const float4*)&Ws[kk][c4]; \
            float xv[4] = {xv4.x, xv4.y, xv4.z, xv4.w}; \
            float wv[4] = {wv4.x, wv4.y, wv4.z, wv4.w}; \
            for (int i = 0; i < 4; ++i) \
                for (int j = 0; j < 4; ++j) acc[i][j] = fmaf(xv[i], wv[j], acc[i][j]); } }

// stats write: into replica (blockIdx & (SREP-1))
#define STATS_TO(SOUT) { \
        __syncthreads(); \
        const int rep_ = (blockIdx.x & (SREP - 1)) * SSTRIDE; \
        for (int j = 0; j < 4; ++j) { \
            float s = 0.f, q = 0.f; \
            for (int i = 0; i < 4; ++i) \
                if (e4 + i < valid) { float a = acc[i][j]; s += a; q += a * a; } \
            part_s[grp][c4 + j] = s; part_q[grp][c4 + j] = q; \
        } \
        __syncthreads(); \
        if (tid < EMBD) { \
            float S = 0.f, Q = 0.f; \
            for (int g = 0; g < 8; ++g) { S += part_s[g][tid]; Q += part_q[g][tid]; } \
            atomicAdd(&(SOUT)[rep_ + tid], S); \
            atomicAdd(&(SOUT)[rep_ + EMBD + tid], Q); } }

// stats read: fold SREP replicas (L2-hot)
#define LOAD_AFF(SRC, GG, BB, SS, CC, DEN) { \
        float sm_ = 0.f, sq_ = 0.f; \
        _Pragma("unroll 8") \
        for (int r_ = 0; r_ < SREP; ++r_) { \
            sm_ += (SRC)[r_ * SSTRIDE + tid]; \
            sq_ += (SRC)[r_ * SSTRIDE + EMBD + tid]; } \
        float m_ = sm_ * (DEN); \
        float v_ = fmaxf(sq_ * (DEN) - m_ * m_, 0.f); \
        float s_ = (GG)[tid] * rsqrtf(v_ + BN_EPS); \
        (SS)[tid] = s_; (CC)[tid] = (BB)[tid] - m_ * s_; }

// Rebuild post-BN1 a1 into XsT from UV (fp16) + dist.  (rc fallback only)
#define REBUILD_XST(K0) { \
        int k = (K0) + kl; \
        float4 u4 = ld4h(uv + (size_t)dst_s[e_st] * 256 + k); \
        float4 v4 = ld4h(uv + (size_t)src_s[e_st] * 256 + 128 + k); \
        float4 wd = *(const float4*)(W1 + (size_t)(2 * EMBD) * EMBD + k); \
        float dd_ = dist_s[e_st]; \
        float r0_ = fmaf(dd_, wd.x, u4.x + v4.x); \
        float r1_ = fmaf(dd_, wd.y, u4.y + v4.y); \
        float r2_ = fmaf(dd_, wd.z, u4.z + v4.z); \
        float r3_ = fmaf(dd_, wd.w, u4.w + v4.w); \
        XsT[kl + 0][e_st] = fmaxf(fmaf(r0_, sA_s[k + 0], sA_c[k + 0]), 0.f); \
        XsT[kl + 1][e_st] = fmaxf(fmaf(r1_, sA_s[k + 1], sA_c[k + 1]), 0.f); \
        XsT[kl + 2][e_st] = fmaxf(fmaf(r2_, sA_s[k + 2], sA_c[k + 2]), 0.f); \
        XsT[kl + 3][e_st] = fmaxf(fmaf(r3_, sA_s[k + 3], sA_c[k + 3]), 0.f); }

#define EDGE_META(WITH_SRC) { \
        if (tid < TE) { \
            int e = r0 + tid; if (e >= E) e = E - 1; \
            int dj = srcI[e], di = dstI[e]; \
            if ((u32)dj >= (u32)Nn) dj = 0; \
            if ((u32)di >= (u32)Nn) di = 0; \
            dst_s[tid] = di; \
            if (WITH_SRC) { \
                src_s[tid] = dj; \
                float2 pj = *(const float2*)(pos + (size_t)dj * 2); \
                float2 pi = *(const float2*)(pos + (size_t)di * 2); \
                float dx = pj.x - pi.x, dy = pj.y - pi.y; \
                dist_s[tid] = sqrtf(dx * dx + dy * dy); } } }

// ================================================================== k_uv
// U = h @ W1[0:128] (dst part), V = h @ W1[128:256] (src part), fp16 out.
__global__ __launch_bounds__(256) void k_uv(
    const float* __restrict__ h, const float* __restrict__ W1,
    f16* __restrict__ uv, float* trace, float bit, int Nn)
{
    trace_mark(trace, bit);
    __shared__ float XsT[KC][TE];
    __shared__ float Ws[KC][EMBD];

    const int tid = threadIdx.x;
    const int r0 = blockIdx.x * TE;
    int valid = Nn - r0; if (valid > TE) valid = TE;

    const int e_st = tid >> 3, kl = (tid & 7) << 2;
    const int kw = tid >> 3, cw = (tid & 7) << 4;
    const int e4 = (tid >> 5) << 2, c4 = (tid & 31) << 2;

    for (int pass = 0; pass < 2; ++pass) {
        float acc[4][4];
#pragma unroll
        for (int i = 0; i < 4; ++i)
#pragma unroll
            for (int j = 0; j < 4; ++j) acc[i][j] = 0.f;

        const float* Wp = W1 + (size_t)pass * EMBD * EMBD;
        for (int k0 = 0; k0 < EMBD; k0 += KC) {
            {
                float4 x = make_float4(0.f, 0.f, 0.f, 0.f);
                if (e_st < valid)
                    x = *(const float4*)(h + (size_t)(r0 + e_st) * EMBD + k0 + kl);
                XsT[kl + 0][e_st] = x.x; XsT[kl + 1][e_st] = x.y;
                XsT[kl + 2][e_st] = x.z; XsT[kl + 3][e_st] = x.w;
            }
            STAGE_W(Wp, k0);
            __syncthreads();
            MMA32();
            __syncthreads();
        }
#pragma unroll
        for (int i = 0; i < 4; ++i)
            if (e4 + i < valid)
                st4h(uv + (size_t)(r0 + e4 + i) * 256 + pass * EMBD + c4,
                     make_float4(acc[i][0], acc[i][1], acc[i][2], acc[i][3]));
    }
}

// ================================================================== k_count
__global__ __launch_bounds__(256) void k_count(
    const int* __restrict__ dstI, int* __restrict__ cnti,
    float* trace, float bit, int E, int Nn)
{
    trace_mark(trace, bit);
    int e = blockIdx.x * 256 + threadIdx.x;
    if (e >= E) return;
    int di = dstI[e];
    if ((u32)di >= (u32)Nn) di = 0;
    atomicAdd(&cnti[di], 1);
}

// ================================================================= k_scan1
__global__ __launch_bounds__(1024) void k_scan1(
    const int* __restrict__ cnti, int* __restrict__ offs,
    int* __restrict__ bsum, float* trace, float bit, int Nn)
{
    trace_mark(trace, bit);
    __shared__ int buf[1024];
    const int tid = threadIdx.x;
    const int gid = blockIdx.x * 1024 + tid;
    int v = (gid < Nn) ? cnti[gid] : 0;
    buf[tid] = v;
    __syncthreads();
    for (int d = 1; d < 1024; d <<= 1) {
        int t = (tid >= d) ? buf[tid - d] : 0;
        __syncthreads();
        buf[tid] += t;
        __syncthreads();
    }
    if (gid < Nn) offs[gid] = buf[tid] - v;      // block-local exclusive
    if (tid == 1023) bsum[blockIdx.x] = buf[1023];
}

// ================================================================= k_scan2
__global__ __launch_bounds__(1024) void k_scan2(
    int* __restrict__ bsum, int* __restrict__ offs,
    float* trace, float bit, int nb, int Nn)
{
    trace_mark(trace, bit);
    __shared__ int buf[1024];
    const int tid = threadIdx.x;
    int v = (tid < nb) ? bsum[tid] : 0;
    buf[tid] = v;
    __syncthreads();
    for (int d = 1; d < 1024; d <<= 1) {
        int t = (tid >= d) ? buf[tid - d] : 0;
        __syncthreads();
        buf[tid] += t;
        __syncthreads();
    }
    if (tid < nb) bsum[tid] = buf[tid] - v;      // exclusive
    if (tid == 1023) offs[Nn] = buf[1023];       // grand total (== E)
}

// ================================================================= k_scan3
__global__ __launch_bounds__(1024) void k_scan3(
    int* __restrict__ offs, int* __restrict__ cursor,
    const int* __restrict__ bsum, float* trace, float bit, int Nn)
{
    trace_mark(trace, bit);
    const int gid = blockIdx.x * 1024 + threadIdx.x;
    if (gid >= Nn) return;
    int o = offs[gid] + bsum[blockIdx.x];
    offs[gid] = o;
    cursor[gid] = o;
}

// =============================================================== k_scatter
__global__ __launch_bounds__(256) void k_scatter(
    const int* __restrict__ srcI, const int* __restrict__ dstI,
    int* __restrict__ cursor, int* __restrict__ eidx,
    int* __restrict__ srcp, int* __restrict__ dstp,
    float* trace, float bit, int E, int Nn)
{
    trace_mark(trace, bit);
    int e = blockIdx.x * 256 + threadIdx.x;
    if (e >= E) return;
    int di = dstI[e], sj = srcI[e];
    if ((u32)di >= (u32)Nn) di = 0;
    if ((u32)sj >= (u32)Nn) sj = 0;
    int p = atomicAdd(&cursor[di], 1);
    eidx[p] = e;
    srcp[p] = sj;
    dstp[p] = di;
}

// ================================================================== k_t1
// WAVE-PER-EDGE gather: t1[k] = U[dstp[k]] + V[srcp[k]] + dist*w1d, stored
// raw fp16 in permuted order; stats1 into replica slot.
#define TB 64
__global__ __launch_bounds__(256) void k_t1(
    const f16* __restrict__ uv, const float* __restrict__ pos,
    const int* __restrict__ srcp, const int* __restrict__ dstp,
    const float* __restrict__ W1, float* stats_out,
    f16* __restrict__ t1out, float* trace, float bit, int E, int Nn)
{
    trace_mark(trace, bit);
    __shared__ int ds[TB], ss[TB];
    __shared__ float dd[TB];
    __shared__ float ps[4][EMBD], pq[4][EMBD];

    const int tid = threadIdx.x;
    const int r0 = blockIdx.x * TB;

    if (tid < TB) {
        int e = r0 + tid; if (e >= E) e = E - 1;
        int dj = srcp[e], di = dstp[e];
        ds[tid] = di; ss[tid] = dj;
        float2 pj = *(const float2*)(pos + (size_t)dj * 2);
        float2 pi = *(const float2*)(pos + (size_t)di * 2);
        float dx = pj.x - pi.x, dy = pj.y - pi.y;
        dd[tid] = sqrtf(dx * dx + dy * dy);
    }
    __syncthreads();

    const int lane = tid & 63, wv = tid >> 6;
    const int c0 = lane * 2;
    const float w0 = W1[(size_t)(2 * EMBD) * EMBD + c0];
    const float w1 = W1[(size_t)(2 * EMBD) * EMBD + c0 + 1];

    float S0 = 0.f, Q0 = 0.f, S1 = 0.f, Q1 = 0.f;
#pragma unroll
    for (int i = 0; i < 16; ++i) {
        const int el = wv * 16 + i;
        const int e = r0 + el;
        f16x2 u2 = *(const f16x2*)(uv + (size_t)ds[el] * 256 + c0);
        f16x2 v2 = *(const f16x2*)(uv + (size_t)ss[el] * 256 + 128 + c0);
        float d = dd[el];
        float t0 = fmaf(d, w0, (float)u2.x + (float)v2.x);
        float t1v = fmaf(d, w1, (float)u2.y + (float)v2.y);
        if (e < E) {
            S0 += t0; Q0 += t0 * t0;
            S1 += t1v; Q1 += t1v * t1v;
            f16x2 o; o.x = (f16)t0; o.y = (f16)t1v;
            *(f16x2*)(t1out + (size_t)e * EMBD + c0) = o;
        }
    }
    ps[wv][c0] = S0; ps[wv][c0 + 1] = S1;
    pq[wv][c0] = Q0; pq[wv][c0 + 1] = Q1;
    __syncthreads();
    const int rep = (blockIdx.x & (SREP - 1)) * SSTRIDE;
    if (tid < EMBD) {
        atomicAdd(&stats_out[rep + tid], ps[0][tid] + ps[1][tid] + ps[2][tid] + ps[3][tid]);
        atomicAdd(&stats_out[rep + EMBD + tid], pq[0][tid] + pq[1][tid] + pq[2][tid] + pq[3][tid]);
    }
}
#undef TB

// =============================================================== k_stats1
// rc fallback only: stats1 over permuted t1 (no staging buffer available).
#define SB 128
__global__ __launch_bounds__(256) void k_stats1(
    const f16* __restrict__ uv, const float* __restrict__ pos,
    const int* __restrict__ srcp, const int* __restrict__ dstp,
    const float* __restrict__ W1, float* stats_out,
    float* trace, float bit, int E, int Nn)
{
    trace_mark(trace, bit);
    __shared__ int ds[SB], ss[SB];
    __shared__ float dd[SB];
    __shared__ float ps[2][EMBD], pq[2][EMBD];

    const int tid = threadIdx.x;
    const int r0 = blockIdx.x * SB;

    if (tid < SB) {
        int e = r0 + tid; if (e >= E) e = E - 1;
        int dj = srcp[e], di = dstp[e];
        ds[tid] = di; ss[tid] = dj;
        float2 pj = *(const float2*)(pos + (size_t)dj * 2);
        float2 pi = *(const float2*)(pos + (size_t)di * 2);
        float dx = pj.x - pi.x, dy = pj.y - pi.y;
        dd[tid] = sqrtf(dx * dx + dy * dy);
    }
    __syncthreads();

    const int c = tid & 127, hh = tid >> 7;
    const float w1d = W1[(size_t)(2 * EMBD) * EMBD + c];
    float S = 0.f, Q = 0.f;
#pragma unroll 4
    for (int i = 0; i < 64; ++i) {
        int el = hh * 64 + i;
        int e = r0 + el;
        if (e < E) {
            float u = (float)uv[(size_t)ds[el] * 256 + c];
            float v = (float)uv[(size_t)ss[el] * 256 + 128 + c];
            float t = fmaf(dd[el], w1d, u + v);
            S += t; Q += t * t;
        }
    }
    ps[hh][c] = S; pq[hh][c] = Q;
    __syncthreads();
    const int rep = (blockIdx.x & (SREP - 1)) * SSTRIDE;
    if (tid < EMBD) {
        atomicAdd(&stats_out[rep + tid], ps[0][tid] + ps[1][tid]);
        atomicAdd(&stats_out[rep + EMBD + tid], pq[0][tid] + pq[1][tid]);
    }
}
#undef SB

// ================================================================== k_prep
// Transpose W2/Wp1 to fp16 MFMA B-frag-slot order.
__global__ __launch_bounds__(256) void k_prep(
    const float* __restrict__ W2, const float* __restrict__ Wp1,
    f16* __restrict__ wtf2, f16* __restrict__ wtf3, float* trace, float bit)
{
    trace_mark(trace, bit);
    int id = blockIdx.x * 256 + threadIdx.x;   // 64 blocks -> 16384
    int k = id >> 7, n = id & 127;
    size_t s = ((size_t)(k >> 3) * 128 + n) * 8 + (k & 7);
    wtf2[s] = (f16)W2[(size_t)k * 128 + n];
    wtf3[s] = (f16)Wp1[(size_t)k * 128 + n];
}

// ================================================================== k_gm
// Streaming MFMA mid GEMM, R18: 256 rows/block (4 sub-tiles of 64), weights
// staged ONCE, packed-f16 BN affine, stats in regs across tiles, 32-row LDS
// repack chunk. IN-PLACE safe (block reads each sub-tile's rows fully before
// writing them; tiles are disjoint).
__global__ __launch_bounds__(256) void k_gm(
    const f16* __restrict__ tin, const f16* __restrict__ wtf,
    const float* g, const float* b,
    const float* __restrict__ stats_in, float* stats_out,
    f16* __restrict__ tout, float* trace, float bit, int E)
{
    trace_mark(trace, bit);
    __shared__ __align__(16) f16 bsh[16384];      // 32 KB weights (resident)
    __shared__ __align__(16) f16 otile[32][136];  // 8.5 KB repack chunk
    __shared__ float sB_s[EMBD], sB_c[EMBD];
    __shared__ f16 sB_h[EMBD], cB_h[EMBD];
    __shared__ float ps[4][EMBD], pq[4][EMBD];

    const int tid = threadIdx.x;
    const int base = blockIdx.x * (64 * ROWT);

    if (tid < EMBD) {
        const float invE = 1.f / (float)E;
        LOAD_AFF(stats_in, g, b, sB_s, sB_c, invE);
        sB_h[tid] = (f16)sB_s[tid];
        cB_h[tid] = (f16)sB_c[tid];
    }
    {   // stage frag-ordered weights once, 32 KB linear
        const float4* s4 = (const float4*)wtf;
        float4* d4 = (float4*)bsh;
#pragma unroll
        for (int i = 0; i < 8; ++i) d4[i * 256 + tid] = s4[i * 256 + tid];
    }
    __syncthreads();

    const int wv = tid >> 6, lane = tid & 63;
    const int lm = lane & 15, lg = lane >> 4;
    const int rbl = wv * 16 + lg * 4;             // local row base of C-frags

    float sAcc[8], qAcc[8];
#pragma unroll
    for (int c = 0; c < 8; ++c) { sAcc[c] = 0.f; qAcc[c] = 0.f; }

    for (int t = 0; t < ROWT; ++t) {
        const int r0 = base + t * 64;
        if (r0 >= E) break;
        int grA = r0 + wv * 16 + lm; if (grA >= E) grA = E - 1;

        fx4_t acc[8];
#pragma unroll
        for (int c = 0; c < 8; ++c) acc[c] = (fx4_t){0.f, 0.f, 0.f, 0.f};

#pragma unroll
        for (int ks = 0; ks < 4; ++ks) {
            const int k0 = ks * 32 + lg * 8;
            hf8_t x8 = *(const hf8_t*)(tin + (size_t)grA * 128 + k0);
            hf8_t s8 = *(const hf8_t*)&sB_h[k0];
            hf8_t c8 = *(const hf8_t*)&cB_h[k0];
            hf8_t af = x8 * s8 + c8;              // v_pk_fma_f16
#pragma unroll
            for (int e = 0; e < 8; ++e)
                af[e] = (af[e] > (f16)0.f) ? af[e] : (f16)0.f;  // v_pk_max_f16
            const f16* bb = bsh + (size_t)(ks * 4 + lg) * 128 * 8;
#pragma unroll
            for (int c = 0; c < 8; ++c) {
                hf8_t bf = *(const hf8_t*)(bb + (size_t)(c * 16 + lm) * 8);
                acc[c] = __builtin_amdgcn_mfma_f32_16x16x32_f16(af, bf, acc[c], 0, 0, 0);
            }
        }

        // accumulate stats in registers
#pragma unroll
        for (int c = 0; c < 8; ++c) {
#pragma unroll
            for (int r = 0; r < 4; ++r)
                if (r0 + rbl + r < E) {
                    float a = acc[c][r];
                    sAcc[c] += a; qAcc[c] += a * a;
                }
        }

        // repack + coalesced store, two 32-row halves through otile
#pragma unroll
        for (int half = 0; half < 2; ++half) {
            __syncthreads();                       // otile free
            if ((rbl >> 5) == half) {
                const int rloc = rbl & 31;
#pragma unroll
                for (int c = 0; c < 8; ++c) {
                    int col = c * 16 + lm;
#pragma unroll
                    for (int r = 0; r < 4; ++r)
                        otile[rloc + r][col] = (f16)acc[c][r];
                }
            }
            __syncthreads();
#pragma unroll
            for (int it = 0; it < 2; ++it) {
                int rloc = it * 16 + (tid >> 4), ch = tid & 15;
                int gr = r0 + half * 32 + rloc;
                if (gr < E)
                    *(float4*)(tout + (size_t)gr * 128 + ch * 8) =
                        *(const float4*)(&otile[rloc][ch * 8]);
            }
        }
    }

    // final stats reduce + replica atomic
#pragma unroll
    for (int c = 0; c < 8; ++c) {
        float s = sAcc[c], q = qAcc[c];
        s += __shfl_xor(s, 16, 64); q += __shfl_xor(q, 16, 64);
        s += __shfl_xor(s, 32, 64); q += __shfl_xor(q, 32, 64);
        if (lg == 0) { ps[wv][c * 16 + lm] = s; pq[wv][c * 16 + lm] = q; }
    }
    __syncthreads();
    const int rep = (blockIdx.x & (SREP - 1)) * SSTRIDE;
    if (tid < EMBD) {
        atomicAdd(&stats_out[rep + tid], ps[0][tid] + ps[1][tid] + ps[2][tid] + ps[3][tid]);
        atomicAdd(&stats_out[rep + EMBD + tid], pq[0][tid] + pq[1][tid] + pq[2][tid] + pq[3][tid]);
    }
}

// ================================================================== k_aggr
// Contiguous segment-sum over permuted t2: h_aggr[n] = sum relu(bn2(t2[k])).
__global__ __launch_bounds__(256) void k_aggr(
    const f16* __restrict__ t2, const int* __restrict__ offs,
    const float* g2, const float* b2, const float* __restrict__ stats_in,
    float* __restrict__ h_aggr, float* trace, float bit, int E, int Nn)
{
    trace_mark(trace, bit);
    __shared__ float sB_s[EMBD], sB_c[EMBD];
    const int tid = threadIdx.x;
    if (tid < EMBD) {
        const float invE = 1.f / (float)E;
        LOAD_AFF(stats_in, g2, b2, sB_s, sB_c, invE);
    }
    __syncthreads();

    const int lane = tid & 63;
    const int node = blockIdx.x * 4 + (tid >> 6);
    if (node >= Nn) return;

    const int c0 = lane * 2;
    const float s0 = sB_s[c0], s1 = sB_s[c0 + 1];
    const float cc0 = sB_c[c0], cc1 = sB_c[c0 + 1];
    const int o0 = offs[node], o1 = offs[node + 1];

    float a0 = 0.f, a1 = 0.f;
    for (int k = o0; k < o1; ++k) {
        f16x2 xv = *(const f16x2*)(t2 + (size_t)k * EMBD + c0);
        a0 += fmaxf(fmaf((float)xv.x, s0, cc0), 0.f);
        a1 += fmaxf(fmaf((float)xv.y, s1, cc1), 0.f);
    }
    *(float2*)(h_aggr + (size_t)node * EMBD + c0) = make_float2(a0, a1);
}

// ================================================================== k_dot
__global__ __launch_bounds__(256) void k_dot(
    const f16* __restrict__ t3, const float* __restrict__ Wp2,
    const float* g3, const float* b3,
    const float* __restrict__ stats_in, float* stats_out, float* t4,
    float* trace, float bit, int E)
{
    trace_mark(trace, bit);
    __shared__ float sC_s[EMBD], sC_c[EMBD];
    __shared__ float red[256];
    __shared__ float dotbuf[TE];

    const int tid = threadIdx.x;
    const int r0 = blockIdx.x * TE;
    int valid = E - r0; if (valid > TE) valid = TE;

    if (tid < EMBD) {
        const float invE = 1.f / (float)E;
        LOAD_AFF(stats_in, g3, b3, sC_s, sC_c, invE);
    }
    __syncthreads();

    const int row = tid >> 3, c0 = (tid & 7) << 4;
    int e = r0 + row; if (e >= E) e = E - 1;
    const f16* tp = t3 + (size_t)e * EMBD + c0;

    float part = 0.f;
#pragma unroll
    for (int q = 0; q < 4; ++q) {
        float4 x = ld4h(tp + q * 4);
        float4 w = *(const float4*)(Wp2 + c0 + q * 4);
        int c = c0 + q * 4;
        part = fmaf(fmaxf(fmaf(x.x, sC_s[c + 0], sC_c[c + 0]), 0.f), w.x, part);
        part = fmaf(fmaxf(fmaf(x.y, sC_s[c + 1], sC_c[c + 1]), 0.f), w.y, part);
        part = fmaf(fmaxf(fmaf(x.z, sC_s[c + 2], sC_c[c + 2]), 0.f), w.z, part);
        part = fmaf(fmaxf(fmaf(x.w, sC_s[c + 3], sC_c[c + 3]), 0.f), w.w, part);
    }
    red[tid] = part;
    __syncthreads();
    if ((tid & 7) == 0) {
        float dot = red[tid] + red[tid+1] + red[tid+2] + red[tid+3]
                  + red[tid+4] + red[tid+5] + red[tid+6] + red[tid+7];
        dotbuf[row] = dot;
        if (row < valid) t4[r0 + row] = dot;
    }
    __syncthreads();
    if (tid == 0) {
        float S = 0.f, Q = 0.f;
        for (int r = 0; r < valid; ++r) { float d = dotbuf[r]; S += d; Q += d * d; }
        const int rep = (blockIdx.x & (SREP - 1)) * SSTRIDE;
        atomicAdd(&stats_out[rep + 0], S);
        atomicAdd(&stats_out[rep + EMBD], Q);
    }
}

// ============================================================= k_pos_aggr
// PERM=1: t4/srcp permuted (streaming). PERM=0: rc tier via eidx.
template<int PERM>
__global__ __launch_bounds__(256) void k_pos_aggr(
    const float* __restrict__ t4, const int* __restrict__ offs,
    const int* __restrict__ eidx, const int* __restrict__ srcp,
    const int* __restrict__ srcI,
    const float* __restrict__ pos, const float* __restrict__ stats_base,
    const float* gp2, const float* bbp2,
    float* __restrict__ x_aggr, float* trace, float bit, int E, int Nn)
{
    trace_mark(trace, bit);
    const int tid = threadIdx.x;
    const int lane = tid & 63;
    const int node = blockIdx.x * 4 + (tid >> 6);
    if (node >= Nn) return;

    const float invE = 1.f / (float)E;
    float sm = 0.f, sq = 0.f;
#pragma unroll 8
    for (int r = 0; r < SREP; ++r) {
        sm += stats_base[r * SSTRIDE + 768];
        sq += stats_base[r * SSTRIDE + 768 + EMBD];
    }
    float m = sm * invE;
    float v = fmaxf(sq * invE - m * m, 0.f);
    float s3 = gp2[0] * rsqrtf(v + BN_EPS);
    float c3 = bbp2[0] - m * s3;

    const int o0 = offs[node], o1 = offs[node + 1];
    float2 pi = *(const float2*)(pos + (size_t)node * 2);
    float ax = 0.f, ay = 0.f;
    for (int k = o0 + lane; k < o1; k += 64) {
        float s; int j;
        if (PERM) {
            s = fmaxf(fmaf(t4[k], s3, c3), 0.f);
            j = srcp[k];
        } else {
            int e = eidx[k];
            s = fmaxf(fmaf(t4[e], s3, c3), 0.f);
            j = srcI[e];
            if ((u32)j >= (u32)Nn) j = 0;
        }
        float2 pj = *(const float2*)(pos + (size_t)j * 2);
        ax += (pj.x - pi.x) * s;
        ay += (pj.y - pi.y) * s;
    }
#pragma unroll
    for (int off = 32; off; off >>= 1) {
        ax += __shfl_down(ax, off, 64);
        ay += __shfl_down(ay, off, 64);
    }
    if (lane == 0) {
        float inv = 1.f / fmaxf((float)(o1 - o0), 1.f);
        *(float2*)(x_aggr + (size_t)node * 2) = make_float2(ax * inv, ay * inv);
    }
}

// ============================================================== k_edge_rc
// Recompute tier (small ws) — original edge order.
template<int DEPTH>
__global__ __launch_bounds__(256) void k_edge_rc(
    const f16* __restrict__ uv,
    const int* __restrict__ srcI, const int* __restrict__ dstI,
    const float* __restrict__ pos,
    const float* __restrict__ W1, const float* __restrict__ W2,
    const float* __restrict__ W3, const float* __restrict__ Wp2,
    const float* g1, const float* b1, const float* g2, const float* b2,
    const float* g3, const float* b3,
    const float* __restrict__ stats_base, float* stats_out,
    float* h_aggr, float* t4_out,
    float* trace, float bit, int E, int Nn)
{
    trace_mark(trace, bit);
    __shared__ float XsT[KC][TE];
    __shared__ float Ws[KC][EMBD];
    __shared__ float A[(DEPTH >= 3) ? TE : 1][EMBD + 4];
    __shared__ float part_s[8][EMBD];
    __shared__ float part_q[8][EMBD];
    __shared__ float red[(DEPTH >= 4) ? 256 : 1];
    __shared__ float dotbuf[(DEPTH >= 4) ? TE : 1];
    __shared__ float sA_s[EMBD], sA_c[EMBD];
    __shared__ float sB_s[(DEPTH >= 3) ? EMBD : 1], sB_c[(DEPTH >= 3) ? EMBD : 1];
    __shared__ float sC_s[(DEPTH >= 4) ? EMBD : 1], sC_c[(DEPTH >= 4) ? EMBD : 1];
    __shared__ int dst_s[TE], src_s[TE];
    __shared__ float dist_s[TE];

    const int tid = threadIdx.x;
    const int r0 = blockIdx.x * TE;
    int valid = E - r0; if (valid > TE) valid = TE;

    if (tid < EMBD) {
        const float invE = 1.f / (float)E;
        LOAD_AFF(stats_base, g1, b1, sA_s, sA_c, invE);
        if (DEPTH >= 3) LOAD_AFF(stats_base + 256, g2, b2, sB_s, sB_c, invE);
        if (DEPTH >= 4) LOAD_AFF(stats_base + 512, g3, b3, sC_s, sC_c, invE);
    }
    EDGE_META(1);
    __syncthreads();

    const int e_st = tid >> 3, kl = (tid & 7) << 2;
    const int kw = tid >> 3, cw = (tid & 7) << 4;
    const int e4 = (tid >> 5) << 2, c4 = (tid & 31) << 2;
    const int grp = tid >> 5;

    float acc[4][4];
#pragma unroll
    for (int i = 0; i < 4; ++i)
#pragma unroll
        for (int j = 0; j < 4; ++j) acc[i][j] = 0.f;

    for (int k0 = 0; k0 < EMBD; k0 += KC) {
        REBUILD_XST(k0);
        STAGE_W(W2, k0);
        __syncthreads();
        MMA32();
        __syncthreads();
    }

    if (DEPTH == 2) { STATS_TO(stats_out); return; }

#pragma unroll
    for (int i = 0; i < 4; ++i) {
        float4 o;
#pragma unroll
        for (int j = 0; j < 4; ++j) {
            float v = fmaxf(fmaf(acc[i][j], sB_s[c4 + j], sB_c[c4 + j]), 0.f);
            (&o.x)[j] = v;
            if (DEPTH == 3 && (e4 + i) < valid)
                atomicAdd(&h_aggr[(size_t)dst_s[e4 + i] * EMBD + c4 + j], v);
        }
        *(float4*)&A[e4 + i][c4] = o;
    }
    __syncthreads();

#pragma unroll
    for (int i = 0; i < 4; ++i)
#pragma unroll
        for (int j = 0; j < 4; ++j) acc[i][j] = 0.f;
    for (int k0 = 0; k0 < EMBD; k0 += KC) {
        STAGE_W(W3, k0);
        __syncthreads();
#pragma unroll 8
        for (int kk = 0; kk < KC; ++kk) {
            float4 wv4 = *(const float4*)&Ws[kk][c4];
            float wv[4] = {wv4.x, wv4.y, wv4.z, wv4.w};
            float xv[4];
#pragma unroll
            for (int i = 0; i < 4; ++i) xv[i] = A[e4 + i][k0 + kk];
#pragma unroll
            for (int i = 0; i < 4; ++i)
#pragma unroll
                for (int j = 0; j < 4; ++j) acc[i][j] = fmaf(xv[i], wv[j], acc[i][j]);
        }
        __syncthreads();
    }

    if (DEPTH == 3) { STATS_TO(stats_out); return; }

#pragma unroll
    for (int i = 0; i < 4; ++i) {
        float4 o;
#pragma unroll
        for (int j = 0; j < 4; ++j)
            (&o.x)[j] = fmaxf(fmaf(acc[i][j], sC_s[c4 + j], sC_c[c4 + j]), 0.f);
        *(float4*)&A[e4 + i][c4] = o;
    }
    __syncthreads();

    {
        const int row = tid >> 3, c0 = (tid & 7) << 4;
        float w[16];
        *(float4*)(w + 0)  = *(const float4*)(Wp2 + c0);
        *(float4*)(w + 4)  = *(const float4*)(Wp2 + c0 + 4);
        *(float4*)(w + 8)  = *(const float4*)(Wp2 + c0 + 8);
        *(float4*)(w + 12) = *(const float4*)(Wp2 + c0 + 12);
        float part = 0.f;
#pragma unroll
        for (int c = 0; c < 16; ++c) part = fmaf(A[row][c0 + c], w[c], part);
        red[tid] = part;
        __syncthreads();
        if ((tid & 7) == 0) {
            float dot = red[tid] + red[tid+1] + red[tid+2] + red[tid+3]
                      + red[tid+4] + red[tid+5] + red[tid+6] + red[tid+7];
            dotbuf[row] = dot;
            if (row < valid) t4_out[r0 + row] = dot;
        }
        __syncthreads();
        if (tid == 0) {
            float S = 0.f, Q = 0.f;
            for (int r = 0; r < valid; ++r) { float d = dotbuf[r]; S += d; Q += d * d; }
            const int rep = (blockIdx.x & (SREP - 1)) * SSTRIDE;
            atomicAdd(&stats_out[rep + 0], S);
            atomicAdd(&stats_out[rep + EMBD], Q);
        }
    }
}

// =============================================================== node GEMM
__global__ __launch_bounds__(256) void k_upd(
    const float* h, const float* h_aggr, const float* W,
    float* stats_out, float* t5, float* trace, float bit, int Nn)
{
    trace_mark(trace, bit);
    __shared__ float XsT[KC][TE];
    __shared__ float Ws[KC][EMBD];
    __shared__ float part_s[8][EMBD];
    __shared__ float part_q[8][EMBD];

    const int tid = threadIdx.x;
    const int r0 = blockIdx.x * TE;
    int valid = Nn - r0; if (valid > TE) valid = TE;

    float acc[4][4];
#pragma unroll
    for (int i = 0; i < 4; ++i)
#pragma unroll
        for (int j = 0; j < 4; ++j) acc[i][j] = 0.f;

    const int e_st = tid >> 3, kl = (tid & 7) << 2;
    const int kw = tid >> 3, cw = (tid & 7) << 4;
    const int e4 = (tid >> 5) << 2, c4 = (tid & 31) << 2;
    const int grp = tid >> 5;

    for (int k0 = 0; k0 < 2 * EMBD; k0 += KC) {
        {
            float4 x = make_float4(0.f, 0.f, 0.f, 0.f);
            if (e_st < valid) {
                int k = k0 + kl;
                int row = r0 + e_st;
                const float* base = (k < EMBD)
                    ? h + (size_t)row * EMBD + k
                    : h_aggr + (size_t)row * EMBD + (k - EMBD);
                x = *(const float4*)base;
            }
            XsT[kl + 0][e_st] = x.x; XsT[kl + 1][e_st] = x.y;
            XsT[kl + 2][e_st] = x.z; XsT[kl + 3][e_st] = x.w;
        }
        STAGE_W(W, k0);
        __syncthreads();
        MMA32();
        __syncthreads();
    }

    STATS_TO(stats_out);

#pragma unroll
    for (int i = 0; i < 4; ++i) {
        int row = r0 + e4 + i;
        if (e4 + i < valid)
            *(float4*)(t5 + (size_t)row * EMBD + c4) =
                make_float4(acc[i][0], acc[i][1], acc[i][2], acc[i][3]);
    }
}

// ---------------------------------------------------------------- epilogue
__global__ __launch_bounds__(256) void k_final(
    const float* h, const float* pos, const float* stats5,
    const float* gu1, const float* bbu1,
    const float* x_aggr, const float* trace,
    float* out, int N, float expect)
{
    __shared__ float s4[EMBD], cc4[EMBD];
    int tid = threadIdx.x;
    if (tid < EMBD) {
        const float invN = 1.f / (float)N;
        LOAD_AFF(stats5, gu1, bbu1, s4, cc4, invN);
    }
    __syncthreads();
    int n = blockIdx.x * 2 + (tid >> 7);
    int c = tid & 127;
    if (n >= N) return;
    float hv = h[(size_t)n * EMBD + c];
    float t = out[(size_t)n * EMBD + c];
    float res = sane(hv + fmaxf(fmaf(t, s4[c], cc4[c]), 0.f), 100.f);
    if (n == 0 && c == 1) {
        float tr = trace[0];
        if (fabsf(tr - expect) > 0.5f) res = 1048576.0f + tr * 64.0f;
    }
    out[(size_t)n * EMBD + c] = res;
    if (c < 2) {
        float p = pos[(size_t)n * 2 + c];
        float xa = x_aggr[(size_t)n * 2 + c];
        out[(size_t)N * EMBD + (size_t)n * 2 + c] = sane(p + xa, 100.f);
    }
}

// ================================================================= launch
extern "C" void kernel_launch(void* const* d_in, const int* in_sizes, int n_in,
                              void* d_out, int out_size, void* d_ws, size_t ws_size,
                              hipStream_t stream)
{
    const float* h   = (const float*)d_in[0];
    const float* pos = (const float*)d_in[1];
    const int* ei    = (const int*)d_in[3];
    const float* Wm1 = (const float*)d_in[4];
    const float* gm1 = (const float*)d_in[6];
    const float* bbm1= (const float*)d_in[7];
    const float* Wm2 = (const float*)d_in[8];
    const float* gm2 = (const float*)d_in[10];
    const float* bbm2= (const float*)d_in[11];
    const float* Wp1 = (const float*)d_in[12];
    const float* gp1 = (const float*)d_in[14];
    const float* bbp1= (const float*)d_in[15];
    const float* Wp2 = (const float*)d_in[16];
    const float* gp2 = (const float*)d_in[18];
    const float* bbp2= (const float*)d_in[19];
    const float* Wu1 = (const float*)d_in[20];
    const float* gu1 = (const float*)d_in[22];
    const float* bbu1= (const float*)d_in[23];

    const int N = in_sizes[0] / EMBD;
    const int E = in_sizes[3] / 2;
    const int* srcI = ei;
    const int* dstI = ei + E;

    size_t off = 0;
    auto carve = [&](size_t bytes) -> size_t {
        size_t o = off; off += (bytes + 255) & ~(size_t)255; return o;
    };
    size_t o_stats  = carve((size_t)SREP * SSTRIDE * sizeof(float));  // 164 KB
    size_t o_trace  = carve(256);
    size_t o_cnti   = carve((size_t)N * sizeof(int));
    size_t zero_small = off;
    size_t o_haggr  = carve((size_t)N * EMBD * sizeof(float));
    size_t zero_need = off;                                  // ~26 MB
    size_t o_xaggr  = carve((size_t)N * 2 * sizeof(float));
    size_t o_t4     = carve((size_t)E * sizeof(float));
    size_t o_offs   = carve((size_t)(N + 1) * sizeof(int));
    size_t o_cursor = carve((size_t)N * sizeof(int));
    size_t o_bsum   = carve(1024 * sizeof(int));
    size_t o_eidx   = carve((size_t)E * sizeof(int));
    size_t o_srcp   = carve((size_t)E * sizeof(int));
    size_t o_dstp   = carve((size_t)E * sizeof(int));
    size_t o_wtf2   = carve(16384 * sizeof(f16));
    size_t o_wtf3   = carve(16384 * sizeof(f16));
    size_t base_need = off;                                  // ~35 MB
    size_t o_ebuf   = carve((size_t)E * EMBD * sizeof(f16)); // +128 MB
    size_t need_staged = off;

    float* out_f = (float*)d_out;

    if (ws_size < base_need) {
        k_fill<<<(out_size + 255) / 256, 256, 0, stream>>>(out_f, 12345678.0f, out_size);
        return;
    }

    char* wsb = (char*)d_ws;
    float* stats  = (float*)(wsb + o_stats);
    float* trace  = (float*)(wsb + o_trace);
    int*   cnti   = (int*)(wsb + o_cnti);
    float* h_aggr = (float*)(wsb + o_haggr);
    float* x_aggr = (float*)(wsb + o_xaggr);
    float* t4     = (float*)(wsb + o_t4);
    int*   offs   = (int*)(wsb + o_offs);
    int*   cursor = (int*)(wsb + o_cursor);
    int*   bsum   = (int*)(wsb + o_bsum);
    int*   eidx   = (int*)(wsb + o_eidx);
    int*   srcp   = (int*)(wsb + o_srcp);
    int*   dstp   = (int*)(wsb + o_dstp);
    f16*   wtf2   = (f16*)(wsb + o_wtf2);
    f16*   wtf3   = (f16*)(wsb + o_wtf3);
    f16*   uv     = (f16*)d_out;   // N*256 fp16 = N*512B <= out bytes

    const bool staged = (ws_size >= need_staged);
    hipMemsetAsync(d_ws, 0, staged ? zero_small : zero_need, stream);

    const int gPE  = (E + 255) / 256;
    const int gE   = (E + TE - 1) / TE;
    const int gGM  = (E + 64 * ROWT - 1) / (64 * ROWT);
    const int gE64 = (E + 63) / 64;
    const int gN   = (N + TE - 1) / TE;
    const int gS1  = (E + 127) / 128;
    const int gW   = (N + 3) / 4;
    const int gSC  = (N + 1023) / 1024;

    k_uv<<<gN, 256, 0, stream>>>(h, Wm1, uv, trace, 1.0f, N);
    k_count<<<gPE, 256, 0, stream>>>(dstI, cnti, trace, 2.0f, E, N);
    k_scan1<<<gSC, 1024, 0, stream>>>(cnti, offs, bsum, trace, 4.0f, N);
    k_scan2<<<1, 1024, 0, stream>>>(bsum, offs, trace, 8.0f, gSC, N);
    k_scan3<<<gSC, 1024, 0, stream>>>(offs, cursor, bsum, trace, 16.0f, N);
    k_scatter<<<gPE, 256, 0, stream>>>(srcI, dstI, cursor, eidx, srcp, dstp,
                                       trace, 32.0f, E, N);

    if (staged) {
        f16* eb = (f16*)(wsb + o_ebuf);
        k_t1<<<gE64, 256, 0, stream>>>(uv, pos, srcp, dstp, Wm1,
                                       stats, eb, trace, 64.0f, E, N);
        k_prep<<<64, 256, 0, stream>>>(Wm2, Wp1, wtf2, wtf3, trace, 128.0f);
        k_gm<<<gGM, 256, 0, stream>>>(eb, wtf2, gm1, bbm1,
                                      stats, stats + 256,
                                      eb, trace, 256.0f, E);
        k_aggr<<<gW, 256, 0, stream>>>(eb, offs, gm2, bbm2, stats + 256,
                                       h_aggr, trace, 512.0f, E, N);
        k_gm<<<gGM, 256, 0, stream>>>(eb, wtf3, gm2, bbm2,
                                      stats + 256, stats + 512,
                                      eb, trace, 1024.0f, E);
        k_dot<<<gE, 256, 0, stream>>>(eb, Wp2, gp1, bbp1,
                                      stats + 512, stats + 768, t4,
                                      trace, 2048.0f, E);
        k_pos_aggr<1><<<gW, 256, 0, stream>>>(t4, offs, eidx, srcp, srcI, pos,
                                              stats, gp2, bbp2, x_aggr,
                                              trace, 4096.0f, E, N);
    } else {
        k_stats1<<<gS1, 256, 0, stream>>>(uv, pos, srcp, dstp, Wm1,
                                          stats, trace, 64.0f, E, N);
        k_edge_rc<2><<<gE, 256, 0, stream>>>(uv, srcI, dstI, pos,
                                             Wm1, Wm2, Wp1, Wp2,
                                             gm1, bbm1, gm2, bbm2, gp1, bbp1,
                                             stats, stats + 256, h_aggr, t4,
                                             trace, 128.0f, E, N);
        k_edge_rc<3><<<gE, 256, 0, stream>>>(uv, srcI, dstI, pos,
                                             Wm1, Wm2, Wp1, Wp2,
                                             gm1, bbm1, gm2, bbm2, gp1, bbp1,
                                             stats, stats + 512, h_aggr, t4,
                                             trace, 256.0f, E, N);
        k_edge_rc<4><<<gE, 256, 0, stream>>>(uv, srcI, dstI, pos,
                                             Wm1, Wm2, Wp1, Wp2,
                                             gm1, bbm1, gm2, bbm2, gp1, bbp1,
                                             stats, stats + 768, h_aggr, t4,
                                             trace, 512.0f, E, N);
        k_pos_aggr<0><<<gW, 256, 0, stream>>>(t4, offs, eidx, srcp, srcI, pos,
                                              stats, gp2, bbp2, x_aggr,
                                              trace, 1024.0f, E, N);
    }

    k_upd<<<gN, 256, 0, stream>>>(h, h_aggr, Wu1, stats + 1024, out_f,
                                  trace, staged ? 8192.0f : 2048.0f, N);
    k_final<<<(N + 1) / 2, 256, 0, stream>>>(h, pos, stats + 1024, gu1, bbu1,
                                             x_aggr, trace, out_f, N,
                                             staged ? 16383.0f : 4095.0f);
}

// Round 11
// 547.216 us; speedup vs baseline: 1.4099x; 1.1136x over previous
//
#include <hip/hip_runtime.h>
#include <hip/hip_bf16.h>

// SpatialNCA, MI355X. R19: MFMA node GEMMs. R18 counters: k_uv/k_upd are the
// last f32-VALU GEMMs (68us each @ Mfma 0, VALU 38%, 7.6M bank conflicts,
// 24 TF effective). k_prep6 pre-transposes all six 128x128 weight blocks to
// frag-order f16; k_uvm (U,V per pass, 256 rows/block, one 32KB stage/pass)
// and k_updm (K=256, both Wu1 halves resident, f32 repack, replica stats)
// reuse the proven k_gm MFMA template. Rest identical to R18.
// Trace fail-closed: staged expect=16383, rc expect=8191.

#define EMBD 128
#define TE 32
#define KC 32
#define BN_EPS 1e-5f
#define SREP 32
#define SSTRIDE 1280
#define ROWT 4

typedef unsigned int u32;
typedef _Float16 f16;
typedef _Float16 hf8_t __attribute__((ext_vector_type(8)));
typedef float fx4_t __attribute__((ext_vector_type(4)));

__device__ __forceinline__ bool finitef(float f) {
    union { float f; u32 i; } v; v.f = f;
    return ((v.i >> 23) & 0xFFu) != 0xFFu;
}
__device__ __forceinline__ float sane(float f, float lim) {
    if (!finitef(f)) return 0.f;
    return fminf(fmaxf(f, -lim), lim);
}
__device__ __forceinline__ void trace_mark(float* tp, float bit) {
    if (blockIdx.x == 0 && threadIdx.x == 0) atomicAdd(tp, bit);
}

struct f16x4 { f16 a, b, c, d; };
struct alignas(4) f16x2 { f16 x, y; };
__device__ __forceinline__ float4 ld4h(const f16* p) {
    f16x4 t = *(const f16x4*)p;
    return make_float4((float)t.a, (float)t.b, (float)t.c, (float)t.d);
}

// ---------------------------------------------------------------- sentinel
__global__ __launch_bounds__(256) void k_fill(float* out, float val, int n) {
    int i = blockIdx.x * 256 + threadIdx.x;
    if (i < n) out[i] = val;
}

// ------------------------------------------------------------ shared macros
#define STAGE_W(WPTR, K0) { \
        const float* wp = (WPTR) + (size_t)((K0) + kw) * EMBD + cw; \
        float4 wa = *(const float4*)wp; \
        float4 wb = *(const float4*)(wp + 4); \
        float4 wc = *(const float4*)(wp + 8); \
        float4 wdv = *(const float4*)(wp + 12); \
        float* wd = &Ws[kw][cw]; \
        *(float4*)(wd + 0) = wa; *(float4*)(wd + 4) = wb; \
        *(float4*)(wd + 8) = wc; *(float4*)(wd + 12) = wdv; }

#define MMA32() { \
        _Pragma("unroll 8") \
        for (int kk = 0; kk < KC; ++kk) { \
            float4 xv4 = *(const float4*)&XsT[kk][e4]; \
            float4 wv4 = *(const float4*)&Ws[kk][c4]; \
            float xv[4] = {xv4.x, xv4.y, xv4.z, xv4.w}; \
            float wv[4] = {wv4.x, wv4.y, wv4.z, wv4.w}; \
            for (int i = 0; i < 4; ++i) \
                for (int j = 0; j < 4; ++j) acc[i][j] = fmaf(xv[i], wv[j], acc[i][j]); } }

#define STATS_TO(SOUT) { \
        __syncthreads(); \
        const int rep_ = (blockIdx.x & (SREP - 1)) * SSTRIDE; \
        for (int j = 0; j < 4; ++j) { \
            float s = 0.f, q = 0.f; \
            for (int i = 0; i < 4; ++i) \
                if (e4 + i < valid) { float a = acc[i][j]; s += a; q += a * a; } \
            part_s[grp][c4 + j] = s; part_q[grp][c4 + j] = q; \
        } \
        __syncthreads(); \
        if (tid < EMBD) { \
            float S = 0.f, Q = 0.f; \
            for (int g = 0; g < 8; ++g) { S += part_s[g][tid]; Q += part_q[g][tid]; } \
            atomicAdd(&(SOUT)[rep_ + tid], S); \
            atomicAdd(&(SOUT)[rep_ + EMBD + tid], Q); } }

#define LOAD_AFF(SRC, GG, BB, SS, CC, DEN) { \
        float sm_ = 0.f, sq_ = 0.f; \
        _Pragma("unroll 8") \
        for (int r_ = 0; r_ < SREP; ++r_) { \
            sm_ += (SRC)[r_ * SSTRIDE + tid]; \
            sq_ += (SRC)[r_ * SSTRIDE + EMBD + tid]; } \
        float m_ = sm_ * (DEN); \
        float v_ = fmaxf(sq_ * (DEN) - m_ * m_, 0.f); \
        float s_ = (GG)[tid] * rsqrtf(v_ + BN_EPS); \
        (SS)[tid] = s_; (CC)[tid] = (BB)[tid] - m_ * s_; }

// Rebuild post-BN1 a1 into XsT from UV (fp16) + dist.  (rc fallback only)
#define REBUILD_XST(K0) { \
        int k = (K0) + kl; \
        float4 u4 = ld4h(uv + (size_t)dst_s[e_st] * 256 + k); \
        float4 v4 = ld4h(uv + (size_t)src_s[e_st] * 256 + 128 + k); \
        float4 wd = *(const float4*)(W1 + (size_t)(2 * EMBD) * EMBD + k); \
        float dd_ = dist_s[e_st]; \
        float r0_ = fmaf(dd_, wd.x, u4.x + v4.x); \
        float r1_ = fmaf(dd_, wd.y, u4.y + v4.y); \
        float r2_ = fmaf(dd_, wd.z, u4.z + v4.z); \
        float r3_ = fmaf(dd_, wd.w, u4.w + v4.w); \
        XsT[kl + 0][e_st] = fmaxf(fmaf(r0_, sA_s[k + 0], sA_c[k + 0]), 0.f); \
        XsT[kl + 1][e_st] = fmaxf(fmaf(r1_, sA_s[k + 1], sA_c[k + 1]), 0.f); \
        XsT[kl + 2][e_st] = fmaxf(fmaf(r2_, sA_s[k + 2], sA_c[k + 2]), 0.f); \
        XsT[kl + 3][e_st] = fmaxf(fmaf(r3_, sA_s[k + 3], sA_c[k + 3]), 0.f); }

#define EDGE_META(WITH_SRC) { \
        if (tid < TE) { \
            int e = r0 + tid; if (e >= E) e = E - 1; \
            int dj = srcI[e], di = dstI[e]; \
            if ((u32)dj >= (u32)Nn) dj = 0; \
            if ((u32)di >= (u32)Nn) di = 0; \
            dst_s[tid] = di; \
            if (WITH_SRC) { \
                src_s[tid] = dj; \
                float2 pj = *(const float2*)(pos + (size_t)dj * 2); \
                float2 pi = *(const float2*)(pos + (size_t)di * 2); \
                float dx = pj.x - pi.x, dy = pj.y - pi.y; \
                dist_s[tid] = sqrtf(dx * dx + dy * dy); } } }

// ================================================================= k_prep6
// Transpose six 128x128 f32 weight blocks into fp16 MFMA B-frag-slot order:
//   wtf[((k>>3)*128 + n)*8 + (k&7)] = (f16)W[k][n]
// 0:W2  1:Wp1  2:W1[0:128]  3:W1[128:256]  4:Wu1[0:128]  5:Wu1[128:256]
__global__ __launch_bounds__(256) void k_prep6(
    const float* __restrict__ W2, const float* __restrict__ Wp1,
    const float* __restrict__ W1, const float* __restrict__ Wu1,
    f16* __restrict__ wtf2, f16* __restrict__ wtf3,
    f16* __restrict__ wtfU, f16* __restrict__ wtfV,
    f16* __restrict__ wtfHa, f16* __restrict__ wtfHb,
    float* trace, float bit)
{
    trace_mark(trace, bit);
    const int which = blockIdx.x >> 6;                 // 0..5
    const int idx = (blockIdx.x & 63) * 256 + threadIdx.x;  // 0..16383
    const int k = idx >> 7, n = idx & 127;
    const size_t s = ((size_t)(k >> 3) * 128 + n) * 8 + (k & 7);
    switch (which) {
        case 0: wtf2[s]  = (f16)W2[(size_t)k * 128 + n]; break;
        case 1: wtf3[s]  = (f16)Wp1[(size_t)k * 128 + n]; break;
        case 2: wtfU[s]  = (f16)W1[(size_t)k * 128 + n]; break;
        case 3: wtfV[s]  = (f16)W1[(size_t)(128 + k) * 128 + n]; break;
        case 4: wtfHa[s] = (f16)Wu1[(size_t)k * 128 + n]; break;
        case 5: wtfHb[s] = (f16)Wu1[(size_t)(128 + k) * 128 + n]; break;
    }
}

// ================================================================== k_uvm
// MFMA node GEMM: U = h @ W1[0:128], V = h @ W1[128:256], fp16 out (uv row
// stride 256). 256 rows/block, weights staged once per pass.
__global__ __launch_bounds__(256) void k_uvm(
    const float* __restrict__ h, const f16* __restrict__ wtfU,
    const f16* __restrict__ wtfV, f16* __restrict__ uv,
    float* trace, float bit, int Nn)
{
    trace_mark(trace, bit);
    __shared__ __align__(16) f16 bsh[16384];
    __shared__ __align__(16) f16 otile[32][136];

    const int tid = threadIdx.x;
    const int base = blockIdx.x * (64 * ROWT);
    const int wv = tid >> 6, lane = tid & 63;
    const int lm = lane & 15, lg = lane >> 4;
    const int rbl = wv * 16 + lg * 4;

    for (int pass = 0; pass < 2; ++pass) {
        const f16* wsrc = pass ? wtfV : wtfU;
        __syncthreads();
        {
            const float4* s4 = (const float4*)wsrc;
            float4* d4 = (float4*)bsh;
#pragma unroll
            for (int i = 0; i < 8; ++i) d4[i * 256 + tid] = s4[i * 256 + tid];
        }
        __syncthreads();

        for (int t = 0; t < ROWT; ++t) {
            const int r0 = base + t * 64;
            if (r0 >= Nn) break;
            int grA = r0 + wv * 16 + lm; if (grA >= Nn) grA = Nn - 1;

            fx4_t acc[8];
#pragma unroll
            for (int c = 0; c < 8; ++c) acc[c] = (fx4_t){0.f, 0.f, 0.f, 0.f};

#pragma unroll
            for (int ks = 0; ks < 4; ++ks) {
                const int k0 = ks * 32 + lg * 8;
                float4 xa = *(const float4*)(h + (size_t)grA * 128 + k0);
                float4 xb = *(const float4*)(h + (size_t)grA * 128 + k0 + 4);
                hf8_t af;
                af[0] = (f16)xa.x; af[1] = (f16)xa.y; af[2] = (f16)xa.z; af[3] = (f16)xa.w;
                af[4] = (f16)xb.x; af[5] = (f16)xb.y; af[6] = (f16)xb.z; af[7] = (f16)xb.w;
                const f16* bb = bsh + (size_t)(ks * 4 + lg) * 128 * 8;
#pragma unroll
                for (int c = 0; c < 8; ++c) {
                    hf8_t bf = *(const hf8_t*)(bb + (size_t)(c * 16 + lm) * 8);
                    acc[c] = __builtin_amdgcn_mfma_f32_16x16x32_f16(af, bf, acc[c], 0, 0, 0);
                }
            }

#pragma unroll
            for (int half = 0; half < 2; ++half) {
                __syncthreads();
                if ((rbl >> 5) == half) {
                    const int rloc = rbl & 31;
#pragma unroll
                    for (int c = 0; c < 8; ++c) {
                        int col = c * 16 + lm;
#pragma unroll
                        for (int r = 0; r < 4; ++r)
                            otile[rloc + r][col] = (f16)acc[c][r];
                    }
                }
                __syncthreads();
#pragma unroll
                for (int it = 0; it < 2; ++it) {
                    int rloc = it * 16 + (tid >> 4), ch = tid & 15;
                    int gr = r0 + half * 32 + rloc;
                    if (gr < Nn)
                        *(float4*)(uv + (size_t)gr * 256 + pass * 128 + ch * 8) =
                            *(const float4*)(&otile[rloc][ch * 8]);
                }
            }
        }
    }
}

// ================================================================== k_updm
// MFMA node GEMM K=256: t5 = [h, h_aggr] @ Wu1 (f32 out), replica stats.
// Both Wu1 halves resident in LDS (64 KB) -> 1 block/CU, 196 blocks.
__global__ __launch_bounds__(256) void k_updm(
    const float* __restrict__ h, const float* __restrict__ h_aggr,
    const f16* __restrict__ wtfHa, const f16* __restrict__ wtfHb,
    float* stats_out, float* __restrict__ t5,
    float* trace, float bit, int Nn)
{
    trace_mark(trace, bit);
    __shared__ __align__(16) f16 bshA[16384];
    __shared__ __align__(16) f16 bshB[16384];
    __shared__ float otile[32][132];
    __shared__ float ps[4][EMBD], pq[4][EMBD];

    const int tid = threadIdx.x;
    const int base = blockIdx.x * (64 * ROWT);
    const int wv = tid >> 6, lane = tid & 63;
    const int lm = lane & 15, lg = lane >> 4;
    const int rbl = wv * 16 + lg * 4;

    {
        const float4* sa = (const float4*)wtfHa;
        const float4* sb = (const float4*)wtfHb;
        float4* da = (float4*)bshA;
        float4* db = (float4*)bshB;
#pragma unroll
        for (int i = 0; i < 8; ++i) {
            da[i * 256 + tid] = sa[i * 256 + tid];
            db[i * 256 + tid] = sb[i * 256 + tid];
        }
    }
    __syncthreads();

    float sAcc[8], qAcc[8];
#pragma unroll
    for (int c = 0; c < 8; ++c) { sAcc[c] = 0.f; qAcc[c] = 0.f; }

    for (int t = 0; t < ROWT; ++t) {
        const int r0 = base + t * 64;
        if (r0 >= Nn) break;
        int grA = r0 + wv * 16 + lm; if (grA >= Nn) grA = Nn - 1;

        fx4_t acc[8];
#pragma unroll
        for (int c = 0; c < 8; ++c) acc[c] = (fx4_t){0.f, 0.f, 0.f, 0.f};

#pragma unroll
        for (int ks = 0; ks < 8; ++ks) {
            const int k0 = (ks & 3) * 32 + lg * 8;
            const float* src = (ks < 4) ? (h + (size_t)grA * 128 + k0)
                                        : (h_aggr + (size_t)grA * 128 + k0);
            float4 xa = *(const float4*)src;
            float4 xb = *(const float4*)(src + 4);
            hf8_t af;
            af[0] = (f16)xa.x; af[1] = (f16)xa.y; af[2] = (f16)xa.z; af[3] = (f16)xa.w;
            af[4] = (f16)xb.x; af[5] = (f16)xb.y; af[6] = (f16)xb.z; af[7] = (f16)xb.w;
            const f16* bb = ((ks < 4) ? bshA : bshB) + (size_t)((ks & 3) * 4 + lg) * 128 * 8;
#pragma unroll
            for (int c = 0; c < 8; ++c) {
                hf8_t bf = *(const hf8_t*)(bb + (size_t)(c * 16 + lm) * 8);
                acc[c] = __builtin_amdgcn_mfma_f32_16x16x32_f16(af, bf, acc[c], 0, 0, 0);
            }
        }

#pragma unroll
        for (int c = 0; c < 8; ++c) {
#pragma unroll
            for (int r = 0; r < 4; ++r)
                if (r0 + rbl + r < Nn) {
                    float a = acc[c][r];
                    sAcc[c] += a; qAcc[c] += a * a;
                }
        }

#pragma unroll
        for (int half = 0; half < 2; ++half) {
            __syncthreads();
            if ((rbl >> 5) == half) {
                const int rloc = rbl & 31;
#pragma unroll
                for (int c = 0; c < 8; ++c) {
                    int col = c * 16 + lm;
#pragma unroll
                    for (int r = 0; r < 4; ++r)
                        otile[rloc + r][col] = acc[c][r];
                }
            }
            __syncthreads();
#pragma unroll
            for (int it = 0; it < 4; ++it) {
                int rloc = it * 8 + (tid >> 5), ch = tid & 31;
                int gr = r0 + half * 32 + rloc;
                if (gr < Nn)
                    *(float4*)(t5 + (size_t)gr * 128 + ch * 4) =
                        *(const float4*)(&otile[rloc][ch * 4]);
            }
        }
    }

#pragma unroll
    for (int c = 0; c < 8; ++c) {
        float s = sAcc[c], q = qAcc[c];
        s += __shfl_xor(s, 16, 64); q += __shfl_xor(q, 16, 64);
        s += __shfl_xor(s, 32, 64); q += __shfl_xor(q, 32, 64);
        if (lg == 0) { ps[wv][c * 16 + lm] = s; pq[wv][c * 16 + lm] = q; }
    }
    __syncthreads();
    const int rep = (blockIdx.x & (SREP - 1)) * SSTRIDE;
    if (tid < EMBD) {
        atomicAdd(&stats_out[rep + tid], ps[0][tid] + ps[1][tid] + ps[2][tid] + ps[3][tid]);
        atomicAdd(&stats_out[rep + EMBD + tid], pq[0][tid] + pq[1][tid] + pq[2][tid] + pq[3][tid]);
    }
}

// ================================================================== k_count
__global__ __launch_bounds__(256) void k_count(
    const int* __restrict__ dstI, int* __restrict__ cnti,
    float* trace, float bit, int E, int Nn)
{
    trace_mark(trace, bit);
    int e = blockIdx.x * 256 + threadIdx.x;
    if (e >= E) return;
    int di = dstI[e];
    if ((u32)di >= (u32)Nn) di = 0;
    atomicAdd(&cnti[di], 1);
}

// ================================================================= k_scan1
__global__ __launch_bounds__(1024) void k_scan1(
    const int* __restrict__ cnti, int* __restrict__ offs,
    int* __restrict__ bsum, float* trace, float bit, int Nn)
{
    trace_mark(trace, bit);
    __shared__ int buf[1024];
    const int tid = threadIdx.x;
    const int gid = blockIdx.x * 1024 + tid;
    int v = (gid < Nn) ? cnti[gid] : 0;
    buf[tid] = v;
    __syncthreads();
    for (int d = 1; d < 1024; d <<= 1) {
        int t = (tid >= d) ? buf[tid - d] : 0;
        __syncthreads();
        buf[tid] += t;
        __syncthreads();
    }
    if (gid < Nn) offs[gid] = buf[tid] - v;
    if (tid == 1023) bsum[blockIdx.x] = buf[1023];
}

// ================================================================= k_scan2
__global__ __launch_bounds__(1024) void k_scan2(
    int* __restrict__ bsum, int* __restrict__ offs,
    float* trace, float bit, int nb, int Nn)
{
    trace_mark(trace, bit);
    __shared__ int buf[1024];
    const int tid = threadIdx.x;
    int v = (tid < nb) ? bsum[tid] : 0;
    buf[tid] = v;
    __syncthreads();
    for (int d = 1; d < 1024; d <<= 1) {
        int t = (tid >= d) ? buf[tid - d] : 0;
        __syncthreads();
        buf[tid] += t;
        __syncthreads();
    }
    if (tid < nb) bsum[tid] = buf[tid] - v;
    if (tid == 1023) offs[Nn] = buf[1023];
}

// ================================================================= k_scan3
__global__ __launch_bounds__(1024) void k_scan3(
    int* __restrict__ offs, int* __restrict__ cursor,
    const int* __restrict__ bsum, float* trace, float bit, int Nn)
{
    trace_mark(trace, bit);
    const int gid = blockIdx.x * 1024 + threadIdx.x;
    if (gid >= Nn) return;
    int o = offs[gid] + bsum[blockIdx.x];
    offs[gid] = o;
    cursor[gid] = o;
}

// =============================================================== k_scatter
__global__ __launch_bounds__(256) void k_scatter(
    const int* __restrict__ srcI, const int* __restrict__ dstI,
    int* __restrict__ cursor, int* __restrict__ eidx,
    int* __restrict__ srcp, int* __restrict__ dstp,
    float* trace, float bit, int E, int Nn)
{
    trace_mark(trace, bit);
    int e = blockIdx.x * 256 + threadIdx.x;
    if (e >= E) return;
    int di = dstI[e], sj = srcI[e];
    if ((u32)di >= (u32)Nn) di = 0;
    if ((u32)sj >= (u32)Nn) sj = 0;
    int p = atomicAdd(&cursor[di], 1);
    eidx[p] = e;
    srcp[p] = sj;
    dstp[p] = di;
}

// ================================================================== k_t1
#define TB 64
__global__ __launch_bounds__(256) void k_t1(
    const f16* __restrict__ uv, const float* __restrict__ pos,
    const int* __restrict__ srcp, const int* __restrict__ dstp,
    const float* __restrict__ W1, float* stats_out,
    f16* __restrict__ t1out, float* trace, float bit, int E, int Nn)
{
    trace_mark(trace, bit);
    __shared__ int ds[TB], ss[TB];
    __shared__ float dd[TB];
    __shared__ float ps[4][EMBD], pq[4][EMBD];

    const int tid = threadIdx.x;
    const int r0 = blockIdx.x * TB;

    if (tid < TB) {
        int e = r0 + tid; if (e >= E) e = E - 1;
        int dj = srcp[e], di = dstp[e];
        ds[tid] = di; ss[tid] = dj;
        float2 pj = *(const float2*)(pos + (size_t)dj * 2);
        float2 pi = *(const float2*)(pos + (size_t)di * 2);
        float dx = pj.x - pi.x, dy = pj.y - pi.y;
        dd[tid] = sqrtf(dx * dx + dy * dy);
    }
    __syncthreads();

    const int lane = tid & 63, wv = tid >> 6;
    const int c0 = lane * 2;
    const float w0 = W1[(size_t)(2 * EMBD) * EMBD + c0];
    const float w1 = W1[(size_t)(2 * EMBD) * EMBD + c0 + 1];

    float S0 = 0.f, Q0 = 0.f, S1 = 0.f, Q1 = 0.f;
#pragma unroll
    for (int i = 0; i < 16; ++i) {
        const int el = wv * 16 + i;
        const int e = r0 + el;
        f16x2 u2 = *(const f16x2*)(uv + (size_t)ds[el] * 256 + c0);
        f16x2 v2 = *(const f16x2*)(uv + (size_t)ss[el] * 256 + 128 + c0);
        float d = dd[el];
        float t0 = fmaf(d, w0, (float)u2.x + (float)v2.x);
        float t1v = fmaf(d, w1, (float)u2.y + (float)v2.y);
        if (e < E) {
            S0 += t0; Q0 += t0 * t0;
            S1 += t1v; Q1 += t1v * t1v;
            f16x2 o; o.x = (f16)t0; o.y = (f16)t1v;
            *(f16x2*)(t1out + (size_t)e * EMBD + c0) = o;
        }
    }
    ps[wv][c0] = S0; ps[wv][c0 + 1] = S1;
    pq[wv][c0] = Q0; pq[wv][c0 + 1] = Q1;
    __syncthreads();
    const int rep = (blockIdx.x & (SREP - 1)) * SSTRIDE;
    if (tid < EMBD) {
        atomicAdd(&stats_out[rep + tid], ps[0][tid] + ps[1][tid] + ps[2][tid] + ps[3][tid]);
        atomicAdd(&stats_out[rep + EMBD + tid], pq[0][tid] + pq[1][tid] + pq[2][tid] + pq[3][tid]);
    }
}
#undef TB

// =============================================================== k_stats1
// rc fallback only.
#define SB 128
__global__ __launch_bounds__(256) void k_stats1(
    const f16* __restrict__ uv, const float* __restrict__ pos,
    const int* __restrict__ srcp, const int* __restrict__ dstp,
    const float* __restrict__ W1, float* stats_out,
    float* trace, float bit, int E, int Nn)
{
    trace_mark(trace, bit);
    __shared__ int ds[SB], ss[SB];
    __shared__ float dd[SB];
    __shared__ float ps[2][EMBD], pq[2][EMBD];

    const int tid = threadIdx.x;
    const int r0 = blockIdx.x * SB;

    if (tid < SB) {
        int e = r0 + tid; if (e >= E) e = E - 1;
        int dj = srcp[e], di = dstp[e];
        ds[tid] = di; ss[tid] = dj;
        float2 pj = *(const float2*)(pos + (size_t)dj * 2);
        float2 pi = *(const float2*)(pos + (size_t)di * 2);
        float dx = pj.x - pi.x, dy = pj.y - pi.y;
        dd[tid] = sqrtf(dx * dx + dy * dy);
    }
    __syncthreads();

    const int c = tid & 127, hh = tid >> 7;
    const float w1d = W1[(size_t)(2 * EMBD) * EMBD + c];
    float S = 0.f, Q = 0.f;
#pragma unroll 4
    for (int i = 0; i < 64; ++i) {
        int el = hh * 64 + i;
        int e = r0 + el;
        if (e < E) {
            float u = (float)uv[(size_t)ds[el] * 256 + c];
            float v = (float)uv[(size_t)ss[el] * 256 + 128 + c];
            float t = fmaf(dd[el], w1d, u + v);
            S += t; Q += t * t;
        }
    }
    ps[hh][c] = S; pq[hh][c] = Q;
    __syncthreads();
    const int rep = (blockIdx.x & (SREP - 1)) * SSTRIDE;
    if (tid < EMBD) {
        atomicAdd(&stats_out[rep + tid], ps[0][tid] + ps[1][tid]);
        atomicAdd(&stats_out[rep + EMBD + tid], pq[0][tid] + pq[1][tid]);
    }
}
#undef SB

// ================================================================== k_gm
// Streaming MFMA mid GEMM (R18 structure, unchanged).
__global__ __launch_bounds__(256) void k_gm(
    const f16* __restrict__ tin, const f16* __restrict__ wtf,
    const float* g, const float* b,
    const float* __restrict__ stats_in, float* stats_out,
    f16* __restrict__ tout, float* trace, float bit, int E)
{
    trace_mark(trace, bit);
    __shared__ __align__(16) f16 bsh[16384];
    __shared__ __align__(16) f16 otile[32][136];
    __shared__ float sB_s[EMBD], sB_c[EMBD];
    __shared__ f16 sB_h[EMBD], cB_h[EMBD];
    __shared__ float ps[4][EMBD], pq[4][EMBD];

    const int tid = threadIdx.x;
    const int base = blockIdx.x * (64 * ROWT);

    if (tid < EMBD) {
        const float invE = 1.f / (float)E;
        LOAD_AFF(stats_in, g, b, sB_s, sB_c, invE);
        sB_h[tid] = (f16)sB_s[tid];
        cB_h[tid] = (f16)sB_c[tid];
    }
    {
        const float4* s4 = (const float4*)wtf;
        float4* d4 = (float4*)bsh;
#pragma unroll
        for (int i = 0; i < 8; ++i) d4[i * 256 + tid] = s4[i * 256 + tid];
    }
    __syncthreads();

    const int wv = tid >> 6, lane = tid & 63;
    const int lm = lane & 15, lg = lane >> 4;
    const int rbl = wv * 16 + lg * 4;

    float sAcc[8], qAcc[8];
#pragma unroll
    for (int c = 0; c < 8; ++c) { sAcc[c] = 0.f; qAcc[c] = 0.f; }

    for (int t = 0; t < ROWT; ++t) {
        const int r0 = base + t * 64;
        if (r0 >= E) break;
        int grA = r0 + wv * 16 + lm; if (grA >= E) grA = E - 1;

        fx4_t acc[8];
#pragma unroll
        for (int c = 0; c < 8; ++c) acc[c] = (fx4_t){0.f, 0.f, 0.f, 0.f};

#pragma unroll
        for (int ks = 0; ks < 4; ++ks) {
            const int k0 = ks * 32 + lg * 8;
            hf8_t x8 = *(const hf8_t*)(tin + (size_t)grA * 128 + k0);
            hf8_t s8 = *(const hf8_t*)&sB_h[k0];
            hf8_t c8 = *(const hf8_t*)&cB_h[k0];
            hf8_t af = x8 * s8 + c8;
#pragma unroll
            for (int e = 0; e < 8; ++e)
                af[e] = (af[e] > (f16)0.f) ? af[e] : (f16)0.f;
            const f16* bb = bsh + (size_t)(ks * 4 + lg) * 128 * 8;
#pragma unroll
            for (int c = 0; c < 8; ++c) {
                hf8_t bf = *(const hf8_t*)(bb + (size_t)(c * 16 + lm) * 8);
                acc[c] = __builtin_amdgcn_mfma_f32_16x16x32_f16(af, bf, acc[c], 0, 0, 0);
            }
        }

#pragma unroll
        for (int c = 0; c < 8; ++c) {
#pragma unroll
            for (int r = 0; r < 4; ++r)
                if (r0 + rbl + r < E) {
                    float a = acc[c][r];
                    sAcc[c] += a; qAcc[c] += a * a;
                }
        }

#pragma unroll
        for (int half = 0; half < 2; ++half) {
            __syncthreads();
            if ((rbl >> 5) == half) {
                const int rloc = rbl & 31;
#pragma unroll
                for (int c = 0; c < 8; ++c) {
                    int col = c * 16 + lm;
#pragma unroll
                    for (int r = 0; r < 4; ++r)
                        otile[rloc + r][col] = (f16)acc[c][r];
                }
            }
            __syncthreads();
#pragma unroll
            for (int it = 0; it < 2; ++it) {
                int rloc = it * 16 + (tid >> 4), ch = tid & 15;
                int gr = r0 + half * 32 + rloc;
                if (gr < E)
                    *(float4*)(tout + (size_t)gr * 128 + ch * 8) =
                        *(const float4*)(&otile[rloc][ch * 8]);
            }
        }
    }

#pragma unroll
    for (int c = 0; c < 8; ++c) {
        float s = sAcc[c], q = qAcc[c];
        s += __shfl_xor(s, 16, 64); q += __shfl_xor(q, 16, 64);
        s += __shfl_xor(s, 32, 64); q += __shfl_xor(q, 32, 64);
        if (lg == 0) { ps[wv][c * 16 + lm] = s; pq[wv][c * 16 + lm] = q; }
    }
    __syncthreads();
    const int rep = (blockIdx.x & (SREP - 1)) * SSTRIDE;
    if (tid < EMBD) {
        atomicAdd(&stats_out[rep + tid], ps[0][tid] + ps[1][tid] + ps[2][tid] + ps[3][tid]);
        atomicAdd(&stats_out[rep + EMBD + tid], pq[0][tid] + pq[1][tid] + pq[2][tid] + pq[3][tid]);
    }
}

// ================================================================== k_aggr
__global__ __launch_bounds__(256) void k_aggr(
    const f16* __restrict__ t2, const int* __restrict__ offs,
    const float* g2, const float* b2, const float* __restrict__ stats_in,
    float* __restrict__ h_aggr, float* trace, float bit, int E, int Nn)
{
    trace_mark(trace, bit);
    __shared__ float sB_s[EMBD], sB_c[EMBD];
    const int tid = threadIdx.x;
    if (tid < EMBD) {
        const float invE = 1.f / (float)E;
        LOAD_AFF(stats_in, g2, b2, sB_s, sB_c, invE);
    }
    __syncthreads();

    const int lane = tid & 63;
    const int node = blockIdx.x * 4 + (tid >> 6);
    if (node >= Nn) return;

    const int c0 = lane * 2;
    const float s0 = sB_s[c0], s1 = sB_s[c0 + 1];
    const float cc0 = sB_c[c0], cc1 = sB_c[c0 + 1];
    const int o0 = offs[node], o1 = offs[node + 1];

    float a0 = 0.f, a1 = 0.f;
    for (int k = o0; k < o1; ++k) {
        f16x2 xv = *(const f16x2*)(t2 + (size_t)k * EMBD + c0);
        a0 += fmaxf(fmaf((float)xv.x, s0, cc0), 0.f);
        a1 += fmaxf(fmaf((float)xv.y, s1, cc1), 0.f);
    }
    *(float2*)(h_aggr + (size_t)node * EMBD + c0) = make_float2(a0, a1);
}

// ================================================================== k_dot
__global__ __launch_bounds__(256) void k_dot(
    const f16* __restrict__ t3, const float* __restrict__ Wp2,
    const float* g3, const float* b3,
    const float* __restrict__ stats_in, float* stats_out, float* t4,
    float* trace, float bit, int E)
{
    trace_mark(trace, bit);
    __shared__ float sC_s[EMBD], sC_c[EMBD];
    __shared__ float red[256];
    __shared__ float dotbuf[TE];

    const int tid = threadIdx.x;
    const int r0 = blockIdx.x * TE;
    int valid = E - r0; if (valid > TE) valid = TE;

    if (tid < EMBD) {
        const float invE = 1.f / (float)E;
        LOAD_AFF(stats_in, g3, b3, sC_s, sC_c, invE);
    }
    __syncthreads();

    const int row = tid >> 3, c0 = (tid & 7) << 4;
    int e = r0 + row; if (e >= E) e = E - 1;
    const f16* tp = t3 + (size_t)e * EMBD + c0;

    float part = 0.f;
#pragma unroll
    for (int q = 0; q < 4; ++q) {
        float4 x = ld4h(tp + q * 4);
        float4 w = *(const float4*)(Wp2 + c0 + q * 4);
        int c = c0 + q * 4;
        part = fmaf(fmaxf(fmaf(x.x, sC_s[c + 0], sC_c[c + 0]), 0.f), w.x, part);
        part = fmaf(fmaxf(fmaf(x.y, sC_s[c + 1], sC_c[c + 1]), 0.f), w.y, part);
        part = fmaf(fmaxf(fmaf(x.z, sC_s[c + 2], sC_c[c + 2]), 0.f), w.z, part);
        part = fmaf(fmaxf(fmaf(x.w, sC_s[c + 3], sC_c[c + 3]), 0.f), w.w, part);
    }
    red[tid] = part;
    __syncthreads();
    if ((tid & 7) == 0) {
        float dot = red[tid] + red[tid+1] + red[tid+2] + red[tid+3]
                  + red[tid+4] + red[tid+5] + red[tid+6] + red[tid+7];
        dotbuf[row] = dot;
        if (row < valid) t4[r0 + row] = dot;
    }
    __syncthreads();
    if (tid == 0) {
        float S = 0.f, Q = 0.f;
        for (int r = 0; r < valid; ++r) { float d = dotbuf[r]; S += d; Q += d * d; }
        const int rep = (blockIdx.x & (SREP - 1)) * SSTRIDE;
        atomicAdd(&stats_out[rep + 0], S);
        atomicAdd(&stats_out[rep + EMBD], Q);
    }
}

// ============================================================= k_pos_aggr
template<int PERM>
__global__ __launch_bounds__(256) void k_pos_aggr(
    const float* __restrict__ t4, const int* __restrict__ offs,
    const int* __restrict__ eidx, const int* __restrict__ srcp,
    const int* __restrict__ srcI,
    const float* __restrict__ pos, const float* __restrict__ stats_base,
    const float* gp2, const float* bbp2,
    float* __restrict__ x_aggr, float* trace, float bit, int E, int Nn)
{
    trace_mark(trace, bit);
    const int tid = threadIdx.x;
    const int lane = tid & 63;
    const int node = blockIdx.x * 4 + (tid >> 6);
    if (node >= Nn) return;

    const float invE = 1.f / (float)E;
    float sm = 0.f, sq = 0.f;
#pragma unroll 8
    for (int r = 0; r < SREP; ++r) {
        sm += stats_base[r * SSTRIDE + 768];
        sq += stats_base[r * SSTRIDE + 768 + EMBD];
    }
    float m = sm * invE;
    float v = fmaxf(sq * invE - m * m, 0.f);
    float s3 = gp2[0] * rsqrtf(v + BN_EPS);
    float c3 = bbp2[0] - m * s3;

    const int o0 = offs[node], o1 = offs[node + 1];
    float2 pi = *(const float2*)(pos + (size_t)node * 2);
    float ax = 0.f, ay = 0.f;
    for (int k = o0 + lane; k < o1; k += 64) {
        float s; int j;
        if (PERM) {
            s = fmaxf(fmaf(t4[k], s3, c3), 0.f);
            j = srcp[k];
        } else {
            int e = eidx[k];
            s = fmaxf(fmaf(t4[e], s3, c3), 0.f);
            j = srcI[e];
            if ((u32)j >= (u32)Nn) j = 0;
        }
        float2 pj = *(const float2*)(pos + (size_t)j * 2);
        ax += (pj.x - pi.x) * s;
        ay += (pj.y - pi.y) * s;
    }
#pragma unroll
    for (int off = 32; off; off >>= 1) {
        ax += __shfl_down(ax, off, 64);
        ay += __shfl_down(ay, off, 64);
    }
    if (lane == 0) {
        float inv = 1.f / fmaxf((float)(o1 - o0), 1.f);
        *(float2*)(x_aggr + (size_t)node * 2) = make_float2(ax * inv, ay * inv);
    }
}

// ============================================================== k_edge_rc
template<int DEPTH>
__global__ __launch_bounds__(256) void k_edge_rc(
    const f16* __restrict__ uv,
    const int* __restrict__ srcI, const int* __restrict__ dstI,
    const float* __restrict__ pos,
    const float* __restrict__ W1, const float* __restrict__ W2,
    const float* __restrict__ W3, const float* __restrict__ Wp2,
    const float* g1, const float* b1, const float* g2, const float* b2,
    const float* g3, const float* b3,
    const float* __restrict__ stats_base, float* stats_out,
    float* h_aggr, float* t4_out,
    float* trace, float bit, int E, int Nn)
{
    trace_mark(trace, bit);
    __shared__ float XsT[KC][TE];
    __shared__ float Ws[KC][EMBD];
    __shared__ float A[(DEPTH >= 3) ? TE : 1][EMBD + 4];
    __shared__ float part_s[8][EMBD];
    __shared__ float part_q[8][EMBD];
    __shared__ float red[(DEPTH >= 4) ? 256 : 1];
    __shared__ float dotbuf[(DEPTH >= 4) ? TE : 1];
    __shared__ float sA_s[EMBD], sA_c[EMBD];
    __shared__ float sB_s[(DEPTH >= 3) ? EMBD : 1], sB_c[(DEPTH >= 3) ? EMBD : 1];
    __shared__ float sC_s[(DEPTH >= 4) ? EMBD : 1], sC_c[(DEPTH >= 4) ? EMBD : 1];
    __shared__ int dst_s[TE], src_s[TE];
    __shared__ float dist_s[TE];

    const int tid = threadIdx.x;
    const int r0 = blockIdx.x * TE;
    int valid = E - r0; if (valid > TE) valid = TE;

    if (tid < EMBD) {
        const float invE = 1.f / (float)E;
        LOAD_AFF(stats_base, g1, b1, sA_s, sA_c, invE);
        if (DEPTH >= 3) LOAD_AFF(stats_base + 256, g2, b2, sB_s, sB_c, invE);
        if (DEPTH >= 4) LOAD_AFF(stats_base + 512, g3, b3, sC_s, sC_c, invE);
    }
    EDGE_META(1);
    __syncthreads();

    const int e_st = tid >> 3, kl = (tid & 7) << 2;
    const int kw = tid >> 3, cw = (tid & 7) << 4;
    const int e4 = (tid >> 5) << 2, c4 = (tid & 31) << 2;
    const int grp = tid >> 5;

    float acc[4][4];
#pragma unroll
    for (int i = 0; i < 4; ++i)
#pragma unroll
        for (int j = 0; j < 4; ++j) acc[i][j] = 0.f;

    for (int k0 = 0; k0 < EMBD; k0 += KC) {
        REBUILD_XST(k0);
        STAGE_W(W2, k0);
        __syncthreads();
        MMA32();
        __syncthreads();
    }

    if (DEPTH == 2) { STATS_TO(stats_out); return; }

#pragma unroll
    for (int i = 0; i < 4; ++i) {
        float4 o;
#pragma unroll
        for (int j = 0; j < 4; ++j) {
            float v = fmaxf(fmaf(acc[i][j], sB_s[c4 + j], sB_c[c4 + j]), 0.f);
            (&o.x)[j] = v;
            if (DEPTH == 3 && (e4 + i) < valid)
                atomicAdd(&h_aggr[(size_t)dst_s[e4 + i] * EMBD + c4 + j], v);
        }
        *(float4*)&A[e4 + i][c4] = o;
    }
    __syncthreads();

#pragma unroll
    for (int i = 0; i < 4; ++i)
#pragma unroll
        for (int j = 0; j < 4; ++j) acc[i][j] = 0.f;
    for (int k0 = 0; k0 < EMBD; k0 += KC) {
        STAGE_W(W3, k0);
        __syncthreads();
#pragma unroll 8
        for (int kk = 0; kk < KC; ++kk) {
            float4 wv4 = *(const float4*)&Ws[kk][c4];
            float wv[4] = {wv4.x, wv4.y, wv4.z, wv4.w};
            float xv[4];
#pragma unroll
            for (int i = 0; i < 4; ++i) xv[i] = A[e4 + i][k0 + kk];
#pragma unroll
            for (int i = 0; i < 4; ++i)
#pragma unroll
                for (int j = 0; j < 4; ++j) acc[i][j] = fmaf(xv[i], wv[j], acc[i][j]);
        }
        __syncthreads();
    }

    if (DEPTH == 3) { STATS_TO(stats_out); return; }

#pragma unroll
    for (int i = 0; i < 4; ++i) {
        float4 o;
#pragma unroll
        for (int j = 0; j < 4; ++j)
            (&o.x)[j] = fmaxf(fmaf(acc[i][j], sC_s[c4 + j], sC_c[c4 + j]), 0.f);
        *(float4*)&A[e4 + i][c4] = o;
    }
    __syncthreads();

    {
        const int row = tid >> 3, c0 = (tid & 7) << 4;
        float w[16];
        *(float4*)(w + 0)  = *(const float4*)(Wp2 + c0);
        *(float4*)(w + 4)  = *(const float4*)(Wp2 + c0 + 4);
        *(float4*)(w + 8)  = *(const float4*)(Wp2 + c0 + 8);
        *(float4*)(w + 12) = *(const float4*)(Wp2 + c0 + 12);
        float part = 0.f;
#pragma unroll
        for (int c = 0; c < 16; ++c) part = fmaf(A[row][c0 + c], w[c], part);
        red[tid] = part;
        __syncthreads();
        if ((tid & 7) == 0) {
            float dot = red[tid] + red[tid+1] + red[tid+2] + red[tid+3]
                      + red[tid+4] + red[tid+5] + red[tid+6] + red[tid+7];
            dotbuf[row] = dot;
            if (row < valid) t4_out[r0 + row] = dot;
        }
        __syncthreads();
        if (tid == 0) {
            float S = 0.f, Q = 0.f;
            for (int r = 0; r < valid; ++r) { float d = dotbuf[r]; S += d; Q += d * d; }
            const int rep = (blockIdx.x & (SREP - 1)) * SSTRIDE;
            atomicAdd(&stats_out[rep + 0], S);
            atomicAdd(&stats_out[rep + EMBD], Q);
        }
    }
}

// ---------------------------------------------------------------- epilogue
__global__ __launch_bounds__(256) void k_final(
    const float* h, const float* pos, const float* stats5,
    const float* gu1, const float* bbu1,
    const float* x_aggr, const float* trace,
    float* out, int N, float expect)
{
    __shared__ float s4[EMBD], cc4[EMBD];
    int tid = threadIdx.x;
    if (tid < EMBD) {
        const float invN = 1.f / (float)N;
        LOAD_AFF(stats5, gu1, bbu1, s4, cc4, invN);
    }
    __syncthreads();
    int n = blockIdx.x * 2 + (tid >> 7);
    int c = tid & 127;
    if (n >= N) return;
    float hv = h[(size_t)n * EMBD + c];
    float t = out[(size_t)n * EMBD + c];
    float res = sane(hv + fmaxf(fmaf(t, s4[c], cc4[c]), 0.f), 100.f);
    if (n == 0 && c == 1) {
        float tr = trace[0];
        if (fabsf(tr - expect) > 0.5f) res = 1048576.0f + tr * 64.0f;
    }
    out[(size_t)n * EMBD + c] = res;
    if (c < 2) {
        float p = pos[(size_t)n * 2 + c];
        float xa = x_aggr[(size_t)n * 2 + c];
        out[(size_t)N * EMBD + (size_t)n * 2 + c] = sane(p + xa, 100.f);
    }
}

// ================================================================= launch
extern "C" void kernel_launch(void* const* d_in, const int* in_sizes, int n_in,
                              void* d_out, int out_size, void* d_ws, size_t ws_size,
                              hipStream_t stream)
{
    const float* h   = (const float*)d_in[0];
    const float* pos = (const float*)d_in[1];
    const int* ei    = (const int*)d_in[3];
    const float* Wm1 = (const float*)d_in[4];
    const float* gm1 = (const float*)d_in[6];
    const float* bbm1= (const float*)d_in[7];
    const float* Wm2 = (const float*)d_in[8];
    const float* gm2 = (const float*)d_in[10];
    const float* bbm2= (const float*)d_in[11];
    const float* Wp1 = (const float*)d_in[12];
    const float* gp1 = (const float*)d_in[14];
    const float* bbp1= (const float*)d_in[15];
    const float* Wp2 = (const float*)d_in[16];
    const float* gp2 = (const float*)d_in[18];
    const float* bbp2= (const float*)d_in[19];
    const float* Wu1 = (const float*)d_in[20];
    const float* gu1 = (const float*)d_in[22];
    const float* bbu1= (const float*)d_in[23];

    const int N = in_sizes[0] / EMBD;
    const int E = in_sizes[3] / 2;
    const int* srcI = ei;
    const int* dstI = ei + E;

    size_t off = 0;
    auto carve = [&](size_t bytes) -> size_t {
        size_t o = off; off += (bytes + 255) & ~(size_t)255; return o;
    };
    size_t o_stats  = carve((size_t)SREP * SSTRIDE * sizeof(float));  // 164 KB
    size_t o_trace  = carve(256);
    size_t o_cnti   = carve((size_t)N * sizeof(int));
    size_t zero_small = off;
    size_t o_haggr  = carve((size_t)N * EMBD * sizeof(float));
    size_t zero_need = off;                                  // ~26 MB
    size_t o_xaggr  = carve((size_t)N * 2 * sizeof(float));
    size_t o_t4     = carve((size_t)E * sizeof(float));
    size_t o_offs   = carve((size_t)(N + 1) * sizeof(int));
    size_t o_cursor = carve((size_t)N * sizeof(int));
    size_t o_bsum   = carve(1024 * sizeof(int));
    size_t o_eidx   = carve((size_t)E * sizeof(int));
    size_t o_srcp   = carve((size_t)E * sizeof(int));
    size_t o_dstp   = carve((size_t)E * sizeof(int));
    size_t o_wtf2   = carve(16384 * sizeof(f16));
    size_t o_wtf3   = carve(16384 * sizeof(f16));
    size_t o_wtfU   = carve(16384 * sizeof(f16));
    size_t o_wtfV   = carve(16384 * sizeof(f16));
    size_t o_wtfHa  = carve(16384 * sizeof(f16));
    size_t o_wtfHb  = carve(16384 * sizeof(f16));
    size_t base_need = off;                                  // ~35 MB
    size_t o_ebuf   = carve((size_t)E * EMBD * sizeof(f16)); // +128 MB
    size_t need_staged = off;

    float* out_f = (float*)d_out;

    if (ws_size < base_need) {
        k_fill<<<(out_size + 255) / 256, 256, 0, stream>>>(out_f, 12345678.0f, out_size);
        return;
    }

    char* wsb = (char*)d_ws;
    float* stats  = (float*)(wsb + o_stats);
    float* trace  = (float*)(wsb + o_trace);
    int*   cnti   = (int*)(wsb + o_cnti);
    float* h_aggr = (float*)(wsb + o_haggr);
    float* x_aggr = (float*)(wsb + o_xaggr);
    float* t4     = (float*)(wsb + o_t4);
    int*   offs   = (int*)(wsb + o_offs);
    int*   cursor = (int*)(wsb + o_cursor);
    int*   bsum   = (int*)(wsb + o_bsum);
    int*   eidx   = (int*)(wsb + o_eidx);
    int*   srcp   = (int*)(wsb + o_srcp);
    int*   dstp   = (int*)(wsb + o_dstp);
    f16*   wtf2   = (f16*)(wsb + o_wtf2);
    f16*   wtf3   = (f16*)(wsb + o_wtf3);
    f16*   wtfU   = (f16*)(wsb + o_wtfU);
    f16*   wtfV   = (f16*)(wsb + o_wtfV);
    f16*   wtfHa  = (f16*)(wsb + o_wtfHa);
    f16*   wtfHb  = (f16*)(wsb + o_wtfHb);
    f16*   uv     = (f16*)d_out;   // N*256 fp16 = N*512B <= out bytes

    const bool staged = (ws_size >= need_staged);
    hipMemsetAsync(d_ws, 0, staged ? zero_small : zero_need, stream);

    const int gPE  = (E + 255) / 256;
    const int gE   = (E + TE - 1) / TE;
    const int gGM  = (E + 64 * ROWT - 1) / (64 * ROWT);
    const int gNM  = (N + 64 * ROWT - 1) / (64 * ROWT);
    const int gE64 = (E + 63) / 64;
    const int gS1  = (E + 127) / 128;
    const int gW   = (N + 3) / 4;
    const int gSC  = (N + 1023) / 1024;

    k_prep6<<<384, 256, 0, stream>>>(Wm2, Wp1, Wm1, Wu1,
                                     wtf2, wtf3, wtfU, wtfV, wtfHa, wtfHb,
                                     trace, 1.0f);
    k_uvm<<<gNM, 256, 0, stream>>>(h, wtfU, wtfV, uv, trace, 2.0f, N);
    k_count<<<gPE, 256, 0, stream>>>(dstI, cnti, trace, 4.0f, E, N);
    k_scan1<<<gSC, 1024, 0, stream>>>(cnti, offs, bsum, trace, 8.0f, N);
    k_scan2<<<1, 1024, 0, stream>>>(bsum, offs, trace, 16.0f, gSC, N);
    k_scan3<<<gSC, 1024, 0, stream>>>(offs, cursor, bsum, trace, 32.0f, N);
    k_scatter<<<gPE, 256, 0, stream>>>(srcI, dstI, cursor, eidx, srcp, dstp,
                                       trace, 64.0f, E, N);

    if (staged) {
        f16* eb = (f16*)(wsb + o_ebuf);
        k_t1<<<gE64, 256, 0, stream>>>(uv, pos, srcp, dstp, Wm1,
                                       stats, eb, trace, 128.0f, E, N);
        k_gm<<<gGM, 256, 0, stream>>>(eb, wtf2, gm1, bbm1,
                                      stats, stats + 256,
                                      eb, trace, 256.0f, E);
        k_aggr<<<gW, 256, 0, stream>>>(eb, offs, gm2, bbm2, stats + 256,
                                       h_aggr, trace, 512.0f, E, N);
        k_gm<<<gGM, 256, 0, stream>>>(eb, wtf3, gm2, bbm2,
                                      stats + 256, stats + 512,
                                      eb, trace, 1024.0f, E);
        k_dot<<<gE, 256, 0, stream>>>(eb, Wp2, gp1, bbp1,
                                      stats + 512, stats + 768, t4,
                                      trace, 2048.0f, E);
        k_pos_aggr<1><<<gW, 256, 0, stream>>>(t4, offs, eidx, srcp, srcI, pos,
                                              stats, gp2, bbp2, x_aggr,
                                              trace, 4096.0f, E, N);
        k_updm<<<gNM, 256, 0, stream>>>(h, h_aggr, wtfHa, wtfHb,
                                        stats + 1024, out_f, trace, 8192.0f, N);
        k_final<<<(N + 1) / 2, 256, 0, stream>>>(h, pos, stats + 1024, gu1, bbu1,
                                                 x_aggr, trace, out_f, N, 16383.0f);
    } else {
        k_stats1<<<gS1, 256, 0, stream>>>(uv, pos, srcp, dstp, Wm1,
                                          stats, trace, 128.0f, E, N);
        k_edge_rc<2><<<gE, 256, 0, stream>>>(uv, srcI, dstI, pos,
                                             Wm1, Wm2, Wp1, Wp2,
                                             gm1, bbm1, gm2, bbm2, gp1, bbp1,
                                             stats, stats + 256, h_aggr, t4,
                                             trace, 256.0f, E, N);
        k_edge_rc<3><<<gE, 256, 0, stream>>>(uv, srcI, dstI, pos,
                                             Wm1, Wm2, Wp1, Wp2,
                                             gm1, bbm1, gm2, bbm2, gp1, bbp1,
                                             stats, stats + 512, h_aggr, t4,
                                             trace, 512.0f, E, N);
        k_edge_rc<4><<<gE, 256, 0, stream>>>(uv, srcI, dstI, pos,
                                             Wm1, Wm2, Wp1, Wp2,
                                             gm1, bbm1, gm2, bbm2, gp1, bbp1,
                                             stats, stats + 768, h_aggr, t4,
                                             trace, 1024.0f, E, N);
        k_pos_aggr<0><<<gW, 256, 0, stream>>>(t4, offs, eidx, srcp, srcI, pos,
                                              stats, gp2, bbp2, x_aggr,
                                              trace, 2048.0f, E, N);
        k_updm<<<gNM, 256, 0, stream>>>(h, h_aggr, wtfHa, wtfHb,
                                        stats + 1024, out_f, trace, 4096.0f, N);
        k_final<<<(N + 1) / 2, 256, 0, stream>>>(h, pos, stats + 1024, gu1, bbu1,
                                                 x_aggr, trace, out_f, N, 8191.0f);
    }
}

// Round 12
// 528.830 us; speedup vs baseline: 1.4589x; 1.0348x over previous
//
#include <hip/hip_runtime.h>
#include <hip/hip_bf16.h>

// SpatialNCA, MI355X. R20: launch-count + fixed-overhead reduction. R19:
// k_gm x2 = 111us visible, ~180us unaccounted => launch gaps + per-block
// stats-fold overhead (k_dot 15625 blocks x 32KB replica reads = 500MB L2).
// Changes: (1) k_head fuses prep(4 wtf)+uvm(self-transposing W1)+count;
// (2) k_scan2 deleted (scan3 self-prefixes <=49 sums); (3) k_gm prefetches
// next sub-tile loads; (4) k_dot 128 rows/block; (5) k_aggr 16 nodes/block.
// Trace fail-closed: staged expect=2047, rc expect=1023.

#define EMBD 128
#define TE 32
#define KC 32
#define BN_EPS 1e-5f
#define SREP 32
#define SSTRIDE 1280
#define ROWT 4

typedef unsigned int u32;
typedef _Float16 f16;
typedef _Float16 hf8_t __attribute__((ext_vector_type(8)));
typedef float fx4_t __attribute__((ext_vector_type(4)));

__device__ __forceinline__ bool finitef(float f) {
    union { float f; u32 i; } v; v.f = f;
    return ((v.i >> 23) & 0xFFu) != 0xFFu;
}
__device__ __forceinline__ float sane(float f, float lim) {
    if (!finitef(f)) return 0.f;
    return fminf(fmaxf(f, -lim), lim);
}
__device__ __forceinline__ void trace_mark(float* tp, float bit) {
    if (blockIdx.x == 0 && threadIdx.x == 0) atomicAdd(tp, bit);
}

struct f16x4 { f16 a, b, c, d; };
struct alignas(4) f16x2 { f16 x, y; };
__device__ __forceinline__ float4 ld4h(const f16* p) {
    f16x4 t = *(const f16x4*)p;
    return make_float4((float)t.a, (float)t.b, (float)t.c, (float)t.d);
}

// ---------------------------------------------------------------- sentinel
__global__ __launch_bounds__(256) void k_fill(float* out, float val, int n) {
    int i = blockIdx.x * 256 + threadIdx.x;
    if (i < n) out[i] = val;
}

// ------------------------------------------------------------ shared macros
#define STAGE_W(WPTR, K0) { \
        const float* wp = (WPTR) + (size_t)((K0) + kw) * EMBD + cw; \
        float4 wa = *(const float4*)wp; \
        float4 wb = *(const float4*)(wp + 4); \
        float4 wc = *(const float4*)(wp + 8); \
        float4 wdv = *(const float4*)(wp + 12); \
        float* wd = &Ws[kw][cw]; \
        *(float4*)(wd + 0) = wa; *(float4*)(wd + 4) = wb; \
        *(float4*)(wd + 8) = wc; *(float4*)(wd + 12) = wdv; }

#define MMA32() { \
        _Pragma("unroll 8") \
        for (int kk = 0; kk < KC; ++kk) { \
            float4 xv4 = *(const float4*)&XsT[kk][e4]; \
            float4 wv4 = *(const float4*)&Ws[kk][c4]; \
            float xv[4] = {xv4.x, xv4.y, xv4.z, xv4.w}; \
            float wv[4] = {wv4.x, wv4.y, wv4.z, wv4.w}; \
            for (int i = 0; i < 4; ++i) \
                for (int j = 0; j < 4; ++j) acc[i][j] = fmaf(xv[i], wv[j], acc[i][j]); } }

#define STATS_TO(SOUT) { \
        __syncthreads(); \
        const int rep_ = (blockIdx.x & (SREP - 1)) * SSTRIDE; \
        for (int j = 0; j < 4; ++j) { \
            float s = 0.f, q = 0.f; \
            for (int i = 0; i < 4; ++i) \
                if (e4 + i < valid) { float a = acc[i][j]; s += a; q += a * a; } \
            part_s[grp][c4 + j] = s; part_q[grp][c4 + j] = q; \
        } \
        __syncthreads(); \
        if (tid < EMBD) { \
            float S = 0.f, Q = 0.f; \
            for (int g = 0; g < 8; ++g) { S += part_s[g][tid]; Q += part_q[g][tid]; } \
            atomicAdd(&(SOUT)[rep_ + tid], S); \
            atomicAdd(&(SOUT)[rep_ + EMBD + tid], Q); } }

#define LOAD_AFF(SRC, GG, BB, SS, CC, DEN) { \
        float sm_ = 0.f, sq_ = 0.f; \
        _Pragma("unroll 8") \
        for (int r_ = 0; r_ < SREP; ++r_) { \
            sm_ += (SRC)[r_ * SSTRIDE + tid]; \
            sq_ += (SRC)[r_ * SSTRIDE + EMBD + tid]; } \
        float m_ = sm_ * (DEN); \
        float v_ = fmaxf(sq_ * (DEN) - m_ * m_, 0.f); \
        float s_ = (GG)[tid] * rsqrtf(v_ + BN_EPS); \
        (SS)[tid] = s_; (CC)[tid] = (BB)[tid] - m_ * s_; }

// Rebuild post-BN1 a1 into XsT from UV (fp16) + dist.  (rc fallback only)
#define REBUILD_XST(K0) { \
        int k = (K0) + kl; \
        float4 u4 = ld4h(uv + (size_t)dst_s[e_st] * 256 + k); \
        float4 v4 = ld4h(uv + (size_t)src_s[e_st] * 256 + 128 + k); \
        float4 wd = *(const float4*)(W1 + (size_t)(2 * EMBD) * EMBD + k); \
        float dd_ = dist_s[e_st]; \
        float r0_ = fmaf(dd_, wd.x, u4.x + v4.x); \
        float r1_ = fmaf(dd_, wd.y, u4.y + v4.y); \
        float r2_ = fmaf(dd_, wd.z, u4.z + v4.z); \
        float r3_ = fmaf(dd_, wd.w, u4.w + v4.w); \
        XsT[kl + 0][e_st] = fmaxf(fmaf(r0_, sA_s[k + 0], sA_c[k + 0]), 0.f); \
        XsT[kl + 1][e_st] = fmaxf(fmaf(r1_, sA_s[k + 1], sA_c[k + 1]), 0.f); \
        XsT[kl + 2][e_st] = fmaxf(fmaf(r2_, sA_s[k + 2], sA_c[k + 2]), 0.f); \
        XsT[kl + 3][e_st] = fmaxf(fmaf(r3_, sA_s[k + 3], sA_c[k + 3]), 0.f); }

#define EDGE_META(WITH_SRC) { \
        if (tid < TE) { \
            int e = r0 + tid; if (e >= E) e = E - 1; \
            int dj = srcI[e], di = dstI[e]; \
            if ((u32)dj >= (u32)Nn) dj = 0; \
            if ((u32)di >= (u32)Nn) di = 0; \
            dst_s[tid] = di; \
            if (WITH_SRC) { \
                src_s[tid] = dj; \
                float2 pj = *(const float2*)(pos + (size_t)dj * 2); \
                float2 pi = *(const float2*)(pos + (size_t)di * 2); \
                float dx = pj.x - pi.x, dy = pj.y - pi.y; \
                dist_s[tid] = sqrtf(dx * dx + dy * dy); } } }

// ================================================================== k_head
// FUSED launch, block-role split:
//  b < 256            : prep role — transpose W2/Wp1/Wu1a/Wu1b to frag f16
//  256 <= b < 256+nUV : uvm role  — U,V = h @ W1 halves (self-staged), fp16
//  else               : count role — degree histogram for CSR
__global__ __launch_bounds__(256) void k_head(
    const float* __restrict__ h, const float* __restrict__ W1,
    const float* __restrict__ W2, const float* __restrict__ Wp1,
    const float* __restrict__ Wu1,
    f16* __restrict__ wtf2, f16* __restrict__ wtf3,
    f16* __restrict__ wtfHa, f16* __restrict__ wtfHb,
    f16* __restrict__ uv,
    const int* __restrict__ dstI, int* __restrict__ cnti,
    float* trace, float bit, int Nn, int E, int nUV)
{
    trace_mark(trace, bit);
    __shared__ __align__(16) f16 bsh[16384];
    __shared__ __align__(16) f16 otile[32][136];

    const int tid = threadIdx.x;
    const int b = blockIdx.x;

    if (b < 256) {                       // ---- prep role
        const int which = b >> 6;
        const int idx = (b & 63) * 256 + tid;
        const int k = idx >> 7, n = idx & 127;
        const size_t s = ((size_t)(k >> 3) * 128 + n) * 8 + (k & 7);
        switch (which) {
            case 0: wtf2[s]  = (f16)W2[(size_t)k * 128 + n]; break;
            case 1: wtf3[s]  = (f16)Wp1[(size_t)k * 128 + n]; break;
            case 2: wtfHa[s] = (f16)Wu1[(size_t)k * 128 + n]; break;
            case 3: wtfHb[s] = (f16)Wu1[(size_t)(128 + k) * 128 + n]; break;
        }
        return;
    }
    if (b >= 256 + nUV) {                // ---- count role
        int e = (b - 256 - nUV) * 256 + tid;
        if (e < E) {
            int di = dstI[e];
            if ((u32)di >= (u32)Nn) di = 0;
            atomicAdd(&cnti[di], 1);
        }
        return;
    }

    // ---- uvm role (MFMA, self-transposing W1 stage)
    const int base = (b - 256) * (64 * ROWT);
    const int wv = tid >> 6, lane = tid & 63;
    const int lm = lane & 15, lg = lane >> 4;
    const int rbl = wv * 16 + lg * 4;

    for (int pass = 0; pass < 2; ++pass) {
        const float* Wp = W1 + (size_t)pass * 128 * 128;
        __syncthreads();
        for (int i = 0; i < 16; ++i) {   // f32 -> f16 frag-order transpose
            int f4 = tid + i * 256;
            int k = f4 >> 5, n0 = (f4 & 31) * 4;
            float4 w = *(const float4*)(Wp + (size_t)k * 128 + n0);
            size_t s0 = ((size_t)(k >> 3) * 128) * 8 + (k & 7);
            bsh[s0 + (size_t)(n0 + 0) * 8] = (f16)w.x;
            bsh[s0 + (size_t)(n0 + 1) * 8] = (f16)w.y;
            bsh[s0 + (size_t)(n0 + 2) * 8] = (f16)w.z;
            bsh[s0 + (size_t)(n0 + 3) * 8] = (f16)w.w;
        }
        __syncthreads();

        for (int t = 0; t < ROWT; ++t) {
            const int r0 = base + t * 64;
            if (r0 >= Nn) break;
            int grA = r0 + wv * 16 + lm; if (grA >= Nn) grA = Nn - 1;

            fx4_t acc[8];
#pragma unroll
            for (int c = 0; c < 8; ++c) acc[c] = (fx4_t){0.f, 0.f, 0.f, 0.f};

#pragma unroll
            for (int ks = 0; ks < 4; ++ks) {
                const int k0 = ks * 32 + lg * 8;
                float4 xa = *(const float4*)(h + (size_t)grA * 128 + k0);
                float4 xb = *(const float4*)(h + (size_t)grA * 128 + k0 + 4);
                hf8_t af;
                af[0] = (f16)xa.x; af[1] = (f16)xa.y; af[2] = (f16)xa.z; af[3] = (f16)xa.w;
                af[4] = (f16)xb.x; af[5] = (f16)xb.y; af[6] = (f16)xb.z; af[7] = (f16)xb.w;
                const f16* bb = bsh + (size_t)(ks * 4 + lg) * 128 * 8;
#pragma unroll
                for (int c = 0; c < 8; ++c) {
                    hf8_t bf = *(const hf8_t*)(bb + (size_t)(c * 16 + lm) * 8);
                    acc[c] = __builtin_amdgcn_mfma_f32_16x16x32_f16(af, bf, acc[c], 0, 0, 0);
                }
            }

#pragma unroll
            for (int half = 0; half < 2; ++half) {
                __syncthreads();
                if ((rbl >> 5) == half) {
                    const int rloc = rbl & 31;
#pragma unroll
                    for (int c = 0; c < 8; ++c) {
                        int col = c * 16 + lm;
#pragma unroll
                        for (int r = 0; r < 4; ++r)
                            otile[rloc + r][col] = (f16)acc[c][r];
                    }
                }
                __syncthreads();
#pragma unroll
                for (int it = 0; it < 2; ++it) {
                    int rloc = it * 16 + (tid >> 4), ch = tid & 15;
                    int gr = r0 + half * 32 + rloc;
                    if (gr < Nn)
                        *(float4*)(uv + (size_t)gr * 256 + pass * 128 + ch * 8) =
                            *(const float4*)(&otile[rloc][ch * 8]);
                }
            }
        }
    }
}

// ================================================================= k_scan1
__global__ __launch_bounds__(1024) void k_scan1(
    const int* __restrict__ cnti, int* __restrict__ offs,
    int* __restrict__ bsum, float* trace, float bit, int Nn)
{
    trace_mark(trace, bit);
    __shared__ int buf[1024];
    const int tid = threadIdx.x;
    const int gid = blockIdx.x * 1024 + tid;
    int v = (gid < Nn) ? cnti[gid] : 0;
    buf[tid] = v;
    __syncthreads();
    for (int d = 1; d < 1024; d <<= 1) {
        int t = (tid >= d) ? buf[tid - d] : 0;
        __syncthreads();
        buf[tid] += t;
        __syncthreads();
    }
    if (gid < Nn) offs[gid] = buf[tid] - v;
    if (tid == 1023) bsum[blockIdx.x] = buf[1023];
}

// ================================================================= k_scan3
// Each block serially prefixes the <=1024 raw block sums itself (L2-hot,
// uniform -> scalarized). Replaces R19's k_scan2+k_scan3 pair.
__global__ __launch_bounds__(1024) void k_scan3(
    int* __restrict__ offs, int* __restrict__ cursor,
    const int* __restrict__ bsum, float* trace, float bit, int Nn)
{
    trace_mark(trace, bit);
    const int tid = threadIdx.x;
    const int gid = blockIdx.x * 1024 + tid;
    int pre = 0;
    for (int i = 0; i < (int)blockIdx.x; ++i) pre += bsum[i];
    if (gid < Nn) {
        int o = offs[gid] + pre;
        offs[gid] = o;
        cursor[gid] = o;
    }
    if (blockIdx.x == gridDim.x - 1 && tid == 1023)
        offs[Nn] = pre + bsum[blockIdx.x];
}

// =============================================================== k_scatter
__global__ __launch_bounds__(256) void k_scatter(
    const int* __restrict__ srcI, const int* __restrict__ dstI,
    int* __restrict__ cursor, int* __restrict__ eidx,
    int* __restrict__ srcp, int* __restrict__ dstp,
    float* trace, float bit, int E, int Nn)
{
    trace_mark(trace, bit);
    int e = blockIdx.x * 256 + threadIdx.x;
    if (e >= E) return;
    int di = dstI[e], sj = srcI[e];
    if ((u32)di >= (u32)Nn) di = 0;
    if ((u32)sj >= (u32)Nn) sj = 0;
    int p = atomicAdd(&cursor[di], 1);
    eidx[p] = e;
    srcp[p] = sj;
    dstp[p] = di;
}

// ================================================================== k_t1
#define TB 64
__global__ __launch_bounds__(256) void k_t1(
    const f16* __restrict__ uv, const float* __restrict__ pos,
    const int* __restrict__ srcp, const int* __restrict__ dstp,
    const float* __restrict__ W1, float* stats_out,
    f16* __restrict__ t1out, float* trace, float bit, int E, int Nn)
{
    trace_mark(trace, bit);
    __shared__ int ds[TB], ss[TB];
    __shared__ float dd[TB];
    __shared__ float ps[4][EMBD], pq[4][EMBD];

    const int tid = threadIdx.x;
    const int r0 = blockIdx.x * TB;

    if (tid < TB) {
        int e = r0 + tid; if (e >= E) e = E - 1;
        int dj = srcp[e], di = dstp[e];
        ds[tid] = di; ss[tid] = dj;
        float2 pj = *(const float2*)(pos + (size_t)dj * 2);
        float2 pi = *(const float2*)(pos + (size_t)di * 2);
        float dx = pj.x - pi.x, dy = pj.y - pi.y;
        dd[tid] = sqrtf(dx * dx + dy * dy);
    }
    __syncthreads();

    const int lane = tid & 63, wv = tid >> 6;
    const int c0 = lane * 2;
    const float w0 = W1[(size_t)(2 * EMBD) * EMBD + c0];
    const float w1 = W1[(size_t)(2 * EMBD) * EMBD + c0 + 1];

    float S0 = 0.f, Q0 = 0.f, S1 = 0.f, Q1 = 0.f;
#pragma unroll
    for (int i = 0; i < 16; ++i) {
        const int el = wv * 16 + i;
        const int e = r0 + el;
        f16x2 u2 = *(const f16x2*)(uv + (size_t)ds[el] * 256 + c0);
        f16x2 v2 = *(const f16x2*)(uv + (size_t)ss[el] * 256 + 128 + c0);
        float d = dd[el];
        float t0 = fmaf(d, w0, (float)u2.x + (float)v2.x);
        float t1v = fmaf(d, w1, (float)u2.y + (float)v2.y);
        if (e < E) {
            S0 += t0; Q0 += t0 * t0;
            S1 += t1v; Q1 += t1v * t1v;
            f16x2 o; o.x = (f16)t0; o.y = (f16)t1v;
            *(f16x2*)(t1out + (size_t)e * EMBD + c0) = o;
        }
    }
    ps[wv][c0] = S0; ps[wv][c0 + 1] = S1;
    pq[wv][c0] = Q0; pq[wv][c0 + 1] = Q1;
    __syncthreads();
    const int rep = (blockIdx.x & (SREP - 1)) * SSTRIDE;
    if (tid < EMBD) {
        atomicAdd(&stats_out[rep + tid], ps[0][tid] + ps[1][tid] + ps[2][tid] + ps[3][tid]);
        atomicAdd(&stats_out[rep + EMBD + tid], pq[0][tid] + pq[1][tid] + pq[2][tid] + pq[3][tid]);
    }
}
#undef TB

// =============================================================== k_stats1
// rc fallback only.
#define SB 128
__global__ __launch_bounds__(256) void k_stats1(
    const f16* __restrict__ uv, const float* __restrict__ pos,
    const int* __restrict__ srcp, const int* __restrict__ dstp,
    const float* __restrict__ W1, float* stats_out,
    float* trace, float bit, int E, int Nn)
{
    trace_mark(trace, bit);
    __shared__ int ds[SB], ss[SB];
    __shared__ float dd[SB];
    __shared__ float ps[2][EMBD], pq[2][EMBD];

    const int tid = threadIdx.x;
    const int r0 = blockIdx.x * SB;

    if (tid < SB) {
        int e = r0 + tid; if (e >= E) e = E - 1;
        int dj = srcp[e], di = dstp[e];
        ds[tid] = di; ss[tid] = dj;
        float2 pj = *(const float2*)(pos + (size_t)dj * 2);
        float2 pi = *(const float2*)(pos + (size_t)di * 2);
        float dx = pj.x - pi.x, dy = pj.y - pi.y;
        dd[tid] = sqrtf(dx * dx + dy * dy);
    }
    __syncthreads();

    const int c = tid & 127, hh = tid >> 7;
    const float w1d = W1[(size_t)(2 * EMBD) * EMBD + c];
    float S = 0.f, Q = 0.f;
#pragma unroll 4
    for (int i = 0; i < 64; ++i) {
        int el = hh * 64 + i;
        int e = r0 + el;
        if (e < E) {
            float u = (float)uv[(size_t)ds[el] * 256 + c];
            float v = (float)uv[(size_t)ss[el] * 256 + 128 + c];
            float t = fmaf(dd[el], w1d, u + v);
            S += t; Q += t * t;
        }
    }
    ps[hh][c] = S; pq[hh][c] = Q;
    __syncthreads();
    const int rep = (blockIdx.x & (SREP - 1)) * SSTRIDE;
    if (tid < EMBD) {
        atomicAdd(&stats_out[rep + tid], ps[0][tid] + ps[1][tid]);
        atomicAdd(&stats_out[rep + EMBD + tid], pq[0][tid] + pq[1][tid]);
    }
}
#undef SB

// ================================================================== k_gm
// Streaming MFMA mid GEMM, R20: next-tile load prefetch added to R18/R19
// structure. IN-PLACE safe (block-own disjoint row tiles).
__global__ __launch_bounds__(256) void k_gm(
    const f16* __restrict__ tin, const f16* __restrict__ wtf,
    const float* g, const float* b,
    const float* __restrict__ stats_in, float* stats_out,
    f16* __restrict__ tout, float* trace, float bit, int E)
{
    trace_mark(trace, bit);
    __shared__ __align__(16) f16 bsh[16384];
    __shared__ __align__(16) f16 otile[32][136];
    __shared__ float sB_s[EMBD], sB_c[EMBD];
    __shared__ f16 sB_h[EMBD], cB_h[EMBD];
    __shared__ float ps[4][EMBD], pq[4][EMBD];

    const int tid = threadIdx.x;
    const int base = blockIdx.x * (64 * ROWT);

    if (tid < EMBD) {
        const float invE = 1.f / (float)E;
        LOAD_AFF(stats_in, g, b, sB_s, sB_c, invE);
        sB_h[tid] = (f16)sB_s[tid];
        cB_h[tid] = (f16)sB_c[tid];
    }
    {
        const float4* s4 = (const float4*)wtf;
        float4* d4 = (float4*)bsh;
#pragma unroll
        for (int i = 0; i < 8; ++i) d4[i * 256 + tid] = s4[i * 256 + tid];
    }
    __syncthreads();

    const int wv = tid >> 6, lane = tid & 63;
    const int lm = lane & 15, lg = lane >> 4;
    const int rbl = wv * 16 + lg * 4;

    float sAcc[8], qAcc[8];
#pragma unroll
    for (int c = 0; c < 8; ++c) { sAcc[c] = 0.f; qAcc[c] = 0.f; }

    // prologue load for tile 0
    hf8_t xc[4];
    {
        int g0 = base + wv * 16 + lm; if (g0 >= E) g0 = E - 1;
#pragma unroll
        for (int ks = 0; ks < 4; ++ks)
            xc[ks] = *(const hf8_t*)(tin + (size_t)g0 * 128 + ks * 32 + lg * 8);
    }

    for (int t = 0; t < ROWT; ++t) {
        const int r0 = base + t * 64;
        if (r0 >= E) break;

        // prefetch next tile's loads (overlaps with MFMA + repack barriers)
        hf8_t xn[4];
        const int r1 = base + (t + 1) * 64;
        if (t + 1 < ROWT && r1 < E) {
            int g1 = r1 + wv * 16 + lm; if (g1 >= E) g1 = E - 1;
#pragma unroll
            for (int ks = 0; ks < 4; ++ks)
                xn[ks] = *(const hf8_t*)(tin + (size_t)g1 * 128 + ks * 32 + lg * 8);
        }

        fx4_t acc[8];
#pragma unroll
        for (int c = 0; c < 8; ++c) acc[c] = (fx4_t){0.f, 0.f, 0.f, 0.f};

#pragma unroll
        for (int ks = 0; ks < 4; ++ks) {
            const int k0 = ks * 32 + lg * 8;
            hf8_t s8 = *(const hf8_t*)&sB_h[k0];
            hf8_t c8 = *(const hf8_t*)&cB_h[k0];
            hf8_t af = xc[ks] * s8 + c8;              // v_pk_fma_f16
#pragma unroll
            for (int e = 0; e < 8; ++e)
                af[e] = (af[e] > (f16)0.f) ? af[e] : (f16)0.f;
            const f16* bb = bsh + (size_t)(ks * 4 + lg) * 128 * 8;
#pragma unroll
            for (int c = 0; c < 8; ++c) {
                hf8_t bf = *(const hf8_t*)(bb + (size_t)(c * 16 + lm) * 8);
                acc[c] = __builtin_amdgcn_mfma_f32_16x16x32_f16(af, bf, acc[c], 0, 0, 0);
            }
        }

#pragma unroll
        for (int c = 0; c < 8; ++c) {
#pragma unroll
            for (int r = 0; r < 4; ++r)
                if (r0 + rbl + r < E) {
                    float a = acc[c][r];
                    sAcc[c] += a; qAcc[c] += a * a;
                }
        }

#pragma unroll
        for (int half = 0; half < 2; ++half) {
            __syncthreads();
            if ((rbl >> 5) == half) {
                const int rloc = rbl & 31;
#pragma unroll
                for (int c = 0; c < 8; ++c) {
                    int col = c * 16 + lm;
#pragma unroll
                    for (int r = 0; r < 4; ++r)
                        otile[rloc + r][col] = (f16)acc[c][r];
                }
            }
            __syncthreads();
#pragma unroll
            for (int it = 0; it < 2; ++it) {
                int rloc = it * 16 + (tid >> 4), ch = tid & 15;
                int gr = r0 + half * 32 + rloc;
                if (gr < E)
                    *(float4*)(tout + (size_t)gr * 128 + ch * 8) =
                        *(const float4*)(&otile[rloc][ch * 8]);
            }
        }

#pragma unroll
        for (int ks = 0; ks < 4; ++ks) xc[ks] = xn[ks];
    }

#pragma unroll
    for (int c = 0; c < 8; ++c) {
        float s = sAcc[c], q = qAcc[c];
        s += __shfl_xor(s, 16, 64); q += __shfl_xor(q, 16, 64);
        s += __shfl_xor(s, 32, 64); q += __shfl_xor(q, 32, 64);
        if (lg == 0) { ps[wv][c * 16 + lm] = s; pq[wv][c * 16 + lm] = q; }
    }
    __syncthreads();
    const int rep = (blockIdx.x & (SREP - 1)) * SSTRIDE;
    if (tid < EMBD) {
        atomicAdd(&stats_out[rep + tid], ps[0][tid] + ps[1][tid] + ps[2][tid] + ps[3][tid]);
        atomicAdd(&stats_out[rep + EMBD + tid], pq[0][tid] + pq[1][tid] + pq[2][tid] + pq[3][tid]);
    }
}

// ================================================================== k_aggr
// Segment-sum over permuted t2; 16 nodes/block (one affine fold amortized).
__global__ __launch_bounds__(256) void k_aggr(
    const f16* __restrict__ t2, const int* __restrict__ offs,
    const float* g2, const float* b2, const float* __restrict__ stats_in,
    float* __restrict__ h_aggr, float* trace, float bit, int E, int Nn)
{
    trace_mark(trace, bit);
    __shared__ float sB_s[EMBD], sB_c[EMBD];
    const int tid = threadIdx.x;
    if (tid < EMBD) {
        const float invE = 1.f / (float)E;
        LOAD_AFF(stats_in, g2, b2, sB_s, sB_c, invE);
    }
    __syncthreads();

    const int lane = tid & 63, wv = tid >> 6;
    const int c0 = lane * 2;
    const float s0 = sB_s[c0], s1 = sB_s[c0 + 1];
    const float cc0 = sB_c[c0], cc1 = sB_c[c0 + 1];

    for (int g = 0; g < 4; ++g) {
        const int node = blockIdx.x * 16 + g * 4 + wv;
        if (node >= Nn) continue;
        const int o0 = offs[node], o1 = offs[node + 1];
        float a0 = 0.f, a1 = 0.f;
        for (int k = o0; k < o1; ++k) {
            f16x2 xv = *(const f16x2*)(t2 + (size_t)k * EMBD + c0);
            a0 += fmaxf(fmaf((float)xv.x, s0, cc0), 0.f);
            a1 += fmaxf(fmaf((float)xv.y, s1, cc1), 0.f);
        }
        *(float2*)(h_aggr + (size_t)node * EMBD + c0) = make_float2(a0, a1);
    }
}

// ================================================================== k_dot
// 128 rows/block (4 sub-tiles, affine folded once).
__global__ __launch_bounds__(256) void k_dot(
    const f16* __restrict__ t3, const float* __restrict__ Wp2,
    const float* g3, const float* b3,
    const float* __restrict__ stats_in, float* stats_out, float* t4,
    float* trace, float bit, int E)
{
    trace_mark(trace, bit);
    __shared__ float sC_s[EMBD], sC_c[EMBD];
    __shared__ float red[256];
    __shared__ float dotbuf[TE];

    const int tid = threadIdx.x;

    if (tid < EMBD) {
        const float invE = 1.f / (float)E;
        LOAD_AFF(stats_in, g3, b3, sC_s, sC_c, invE);
    }
    __syncthreads();

    const int row = tid >> 3, c0 = (tid & 7) << 4;
    float accS = 0.f, accQ = 0.f;

    for (int rt = 0; rt < 4; ++rt) {
        const int r0 = blockIdx.x * 128 + rt * 32;
        if (r0 >= E) break;
        int valid = E - r0; if (valid > TE) valid = TE;
        int e = r0 + row; if (e >= E) e = E - 1;
        const f16* tp = t3 + (size_t)e * EMBD + c0;

        float part = 0.f;
#pragma unroll
        for (int q = 0; q < 4; ++q) {
            float4 x = ld4h(tp + q * 4);
            float4 w = *(const float4*)(Wp2 + c0 + q * 4);
            int c = c0 + q * 4;
            part = fmaf(fmaxf(fmaf(x.x, sC_s[c + 0], sC_c[c + 0]), 0.f), w.x, part);
            part = fmaf(fmaxf(fmaf(x.y, sC_s[c + 1], sC_c[c + 1]), 0.f), w.y, part);
            part = fmaf(fmaxf(fmaf(x.z, sC_s[c + 2], sC_c[c + 2]), 0.f), w.z, part);
            part = fmaf(fmaxf(fmaf(x.w, sC_s[c + 3], sC_c[c + 3]), 0.f), w.w, part);
        }
        red[tid] = part;
        __syncthreads();
        if ((tid & 7) == 0) {
            float dot = red[tid] + red[tid+1] + red[tid+2] + red[tid+3]
                      + red[tid+4] + red[tid+5] + red[tid+6] + red[tid+7];
            dotbuf[row] = dot;
            if (row < valid) t4[r0 + row] = dot;
        }
        __syncthreads();
        if (tid == 0) {
            for (int r = 0; r < valid; ++r) {
                float d = dotbuf[r]; accS += d; accQ += d * d;
            }
        }
        __syncthreads();
    }
    if (tid == 0) {
        const int rep = (blockIdx.x & (SREP - 1)) * SSTRIDE;
        atomicAdd(&stats_out[rep + 768], accS);
        atomicAdd(&stats_out[rep + 768 + EMBD], accQ);
    }
}

// ============================================================= k_pos_aggr
template<int PERM>
__global__ __launch_bounds__(256) void k_pos_aggr(
    const float* __restrict__ t4, const int* __restrict__ offs,
    const int* __restrict__ eidx, const int* __restrict__ srcp,
    const int* __restrict__ srcI,
    const float* __restrict__ pos, const float* __restrict__ stats_base,
    const float* gp2, const float* bbp2,
    float* __restrict__ x_aggr, float* trace, float bit, int E, int Nn)
{
    trace_mark(trace, bit);
    const int tid = threadIdx.x;
    const int lane = tid & 63;
    const int node = blockIdx.x * 4 + (tid >> 6);
    if (node >= Nn) return;

    const float invE = 1.f / (float)E;
    float sm = 0.f, sq = 0.f;
#pragma unroll 8
    for (int r = 0; r < SREP; ++r) {
        sm += stats_base[r * SSTRIDE + 768];
        sq += stats_base[r * SSTRIDE + 768 + EMBD];
    }
    float m = sm * invE;
    float v = fmaxf(sq * invE - m * m, 0.f);
    float s3 = gp2[0] * rsqrtf(v + BN_EPS);
    float c3 = bbp2[0] - m * s3;

    const int o0 = offs[node], o1 = offs[node + 1];
    float2 pi = *(const float2*)(pos + (size_t)node * 2);
    float ax = 0.f, ay = 0.f;
    for (int k = o0 + lane; k < o1; k += 64) {
        float s; int j;
        if (PERM) {
            s = fmaxf(fmaf(t4[k], s3, c3), 0.f);
            j = srcp[k];
        } else {
            int e = eidx[k];
            s = fmaxf(fmaf(t4[e], s3, c3), 0.f);
            j = srcI[e];
            if ((u32)j >= (u32)Nn) j = 0;
        }
        float2 pj = *(const float2*)(pos + (size_t)j * 2);
        ax += (pj.x - pi.x) * s;
        ay += (pj.y - pi.y) * s;
    }
#pragma unroll
    for (int off = 32; off; off >>= 1) {
        ax += __shfl_down(ax, off, 64);
        ay += __shfl_down(ay, off, 64);
    }
    if (lane == 0) {
        float inv = 1.f / fmaxf((float)(o1 - o0), 1.f);
        *(float2*)(x_aggr + (size_t)node * 2) = make_float2(ax * inv, ay * inv);
    }
}

// ================================================================== k_updm
// MFMA node GEMM K=256 (R19 structure unchanged).
__global__ __launch_bounds__(256) void k_updm(
    const float* __restrict__ h, const float* __restrict__ h_aggr,
    const f16* __restrict__ wtfHa, const f16* __restrict__ wtfHb,
    float* stats_out, float* __restrict__ t5,
    float* trace, float bit, int Nn)
{
    trace_mark(trace, bit);
    __shared__ __align__(16) f16 bshA[16384];
    __shared__ __align__(16) f16 bshB[16384];
    __shared__ float otile[32][132];
    __shared__ float ps[4][EMBD], pq[4][EMBD];

    const int tid = threadIdx.x;
    const int base = blockIdx.x * (64 * ROWT);
    const int wv = tid >> 6, lane = tid & 63;
    const int lm = lane & 15, lg = lane >> 4;
    const int rbl = wv * 16 + lg * 4;

    {
        const float4* sa = (const float4*)wtfHa;
        const float4* sb = (const float4*)wtfHb;
        float4* da = (float4*)bshA;
        float4* db = (float4*)bshB;
#pragma unroll
        for (int i = 0; i < 8; ++i) {
            da[i * 256 + tid] = sa[i * 256 + tid];
            db[i * 256 + tid] = sb[i * 256 + tid];
        }
    }
    __syncthreads();

    float sAcc[8], qAcc[8];
#pragma unroll
    for (int c = 0; c < 8; ++c) { sAcc[c] = 0.f; qAcc[c] = 0.f; }

    for (int t = 0; t < ROWT; ++t) {
        const int r0 = base + t * 64;
        if (r0 >= Nn) break;
        int grA = r0 + wv * 16 + lm; if (grA >= Nn) grA = Nn - 1;

        fx4_t acc[8];
#pragma unroll
        for (int c = 0; c < 8; ++c) acc[c] = (fx4_t){0.f, 0.f, 0.f, 0.f};

#pragma unroll
        for (int ks = 0; ks < 8; ++ks) {
            const int k0 = (ks & 3) * 32 + lg * 8;
            const float* src = (ks < 4) ? (h + (size_t)grA * 128 + k0)
                                        : (h_aggr + (size_t)grA * 128 + k0);
            float4 xa = *(const float4*)src;
            float4 xb = *(const float4*)(src + 4);
            hf8_t af;
            af[0] = (f16)xa.x; af[1] = (f16)xa.y; af[2] = (f16)xa.z; af[3] = (f16)xa.w;
            af[4] = (f16)xb.x; af[5] = (f16)xb.y; af[6] = (f16)xb.z; af[7] = (f16)xb.w;
            const f16* bb = ((ks < 4) ? bshA : bshB) + (size_t)((ks & 3) * 4 + lg) * 128 * 8;
#pragma unroll
            for (int c = 0; c < 8; ++c) {
                hf8_t bf = *(const hf8_t*)(bb + (size_t)(c * 16 + lm) * 8);
                acc[c] = __builtin_amdgcn_mfma_f32_16x16x32_f16(af, bf, acc[c], 0, 0, 0);
            }
        }

#pragma unroll
        for (int c = 0; c < 8; ++c) {
#pragma unroll
            for (int r = 0; r < 4; ++r)
                if (r0 + rbl + r < Nn) {
                    float a = acc[c][r];
                    sAcc[c] += a; qAcc[c] += a * a;
                }
        }

#pragma unroll
        for (int half = 0; half < 2; ++half) {
            __syncthreads();
            if ((rbl >> 5) == half) {
                const int rloc = rbl & 31;
#pragma unroll
                for (int c = 0; c < 8; ++c) {
                    int col = c * 16 + lm;
#pragma unroll
                    for (int r = 0; r < 4; ++r)
                        otile[rloc + r][col] = acc[c][r];
                }
            }
            __syncthreads();
#pragma unroll
            for (int it = 0; it < 4; ++it) {
                int rloc = it * 8 + (tid >> 5), ch = tid & 31;
                int gr = r0 + half * 32 + rloc;
                if (gr < Nn)
                    *(float4*)(t5 + (size_t)gr * 128 + ch * 4) =
                        *(const float4*)(&otile[rloc][ch * 4]);
            }
        }
    }

#pragma unroll
    for (int c = 0; c < 8; ++c) {
        float s = sAcc[c], q = qAcc[c];
        s += __shfl_xor(s, 16, 64); q += __shfl_xor(q, 16, 64);
        s += __shfl_xor(s, 32, 64); q += __shfl_xor(q, 32, 64);
        if (lg == 0) { ps[wv][c * 16 + lm] = s; pq[wv][c * 16 + lm] = q; }
    }
    __syncthreads();
    const int rep = (blockIdx.x & (SREP - 1)) * SSTRIDE;
    if (tid < EMBD) {
        atomicAdd(&stats_out[rep + tid], ps[0][tid] + ps[1][tid] + ps[2][tid] + ps[3][tid]);
        atomicAdd(&stats_out[rep + EMBD + tid], pq[0][tid] + pq[1][tid] + pq[2][tid] + pq[3][tid]);
    }
}

// ============================================================== k_edge_rc
template<int DEPTH>
__global__ __launch_bounds__(256) void k_edge_rc(
    const f16* __restrict__ uv,
    const int* __restrict__ srcI, const int* __restrict__ dstI,
    const float* __restrict__ pos,
    const float* __restrict__ W1, const float* __restrict__ W2,
    const float* __restrict__ W3, const float* __restrict__ Wp2,
    const float* g1, const float* b1, const float* g2, const float* b2,
    const float* g3, const float* b3,
    const float* __restrict__ stats_base, float* stats_out,
    float* h_aggr, float* t4_out,
    float* trace, float bit, int E, int Nn)
{
    trace_mark(trace, bit);
    __shared__ float XsT[KC][TE];
    __shared__ float Ws[KC][EMBD];
    __shared__ float A[(DEPTH >= 3) ? TE : 1][EMBD + 4];
    __shared__ float part_s[8][EMBD];
    __shared__ float part_q[8][EMBD];
    __shared__ float red[(DEPTH >= 4) ? 256 : 1];
    __shared__ float dotbuf[(DEPTH >= 4) ? TE : 1];
    __shared__ float sA_s[EMBD], sA_c[EMBD];
    __shared__ float sB_s[(DEPTH >= 3) ? EMBD : 1], sB_c[(DEPTH >= 3) ? EMBD : 1];
    __shared__ float sC_s[(DEPTH >= 4) ? EMBD : 1], sC_c[(DEPTH >= 4) ? EMBD : 1];
    __shared__ int dst_s[TE], src_s[TE];
    __shared__ float dist_s[TE];

    const int tid = threadIdx.x;
    const int r0 = blockIdx.x * TE;
    int valid = E - r0; if (valid > TE) valid = TE;

    if (tid < EMBD) {
        const float invE = 1.f / (float)E;
        LOAD_AFF(stats_base, g1, b1, sA_s, sA_c, invE);
        if (DEPTH >= 3) LOAD_AFF(stats_base + 256, g2, b2, sB_s, sB_c, invE);
        if (DEPTH >= 4) LOAD_AFF(stats_base + 512, g3, b3, sC_s, sC_c, invE);
    }
    EDGE_META(1);
    __syncthreads();

    const int e_st = tid >> 3, kl = (tid & 7) << 2;
    const int kw = tid >> 3, cw = (tid & 7) << 4;
    const int e4 = (tid >> 5) << 2, c4 = (tid & 31) << 2;
    const int grp = tid >> 5;

    float acc[4][4];
#pragma unroll
    for (int i = 0; i < 4; ++i)
#pragma unroll
        for (int j = 0; j < 4; ++j) acc[i][j] = 0.f;

    for (int k0 = 0; k0 < EMBD; k0 += KC) {
        REBUILD_XST(k0);
        STAGE_W(W2, k0);
        __syncthreads();
        MMA32();
        __syncthreads();
    }

    if (DEPTH == 2) { STATS_TO(stats_out); return; }

#pragma unroll
    for (int i = 0; i < 4; ++i) {
        float4 o;
#pragma unroll
        for (int j = 0; j < 4; ++j) {
            float v = fmaxf(fmaf(acc[i][j], sB_s[c4 + j], sB_c[c4 + j]), 0.f);
            (&o.x)[j] = v;
            if (DEPTH == 3 && (e4 + i) < valid)
                atomicAdd(&h_aggr[(size_t)dst_s[e4 + i] * EMBD + c4 + j], v);
        }
        *(float4*)&A[e4 + i][c4] = o;
    }
    __syncthreads();

#pragma unroll
    for (int i = 0; i < 4; ++i)
#pragma unroll
        for (int j = 0; j < 4; ++j) acc[i][j] = 0.f;
    for (int k0 = 0; k0 < EMBD; k0 += KC) {
        STAGE_W(W3, k0);
        __syncthreads();
#pragma unroll 8
        for (int kk = 0; kk < KC; ++kk) {
            float4 wv4 = *(const float4*)&Ws[kk][c4];
            float wv[4] = {wv4.x, wv4.y, wv4.z, wv4.w};
            float xv[4];
#pragma unroll
            for (int i = 0; i < 4; ++i) xv[i] = A[e4 + i][k0 + kk];
#pragma unroll
            for (int i = 0; i < 4; ++i)
#pragma unroll
                for (int j = 0; j < 4; ++j) acc[i][j] = fmaf(xv[i], wv[j], acc[i][j]);
        }
        __syncthreads();
    }

    if (DEPTH == 3) { STATS_TO(stats_out); return; }

#pragma unroll
    for (int i = 0; i < 4; ++i) {
        float4 o;
#pragma unroll
        for (int j = 0; j < 4; ++j)
            (&o.x)[j] = fmaxf(fmaf(acc[i][j], sC_s[c4 + j], sC_c[c4 + j]), 0.f);
        *(float4*)&A[e4 + i][c4] = o;
    }
    __syncthreads();

    {
        const int row = tid >> 3, c0 = (tid & 7) << 4;
        float w[16];
        *(float4*)(w + 0)  = *(const float4*)(Wp2 + c0);
        *(float4*)(w + 4)  = *(const float4*)(Wp2 + c0 + 4);
        *(float4*)(w + 8)  = *(const float4*)(Wp2 + c0 + 8);
        *(float4*)(w + 12) = *(const float4*)(Wp2 + c0 + 12);
        float part = 0.f;
#pragma unroll
        for (int c = 0; c < 16; ++c) part = fmaf(A[row][c0 + c], w[c], part);
        red[tid] = part;
        __syncthreads();
        if ((tid & 7) == 0) {
            float dot = red[tid] + red[tid+1] + red[tid+2] + red[tid+3]
                      + red[tid+4] + red[tid+5] + red[tid+6] + red[tid+7];
            dotbuf[row] = dot;
            if (row < valid) t4_out[r0 + row] = dot;
        }
        __syncthreads();
        if (tid == 0) {
            float S = 0.f, Q = 0.f;
            for (int r = 0; r < valid; ++r) { float d = dotbuf[r]; S += d; Q += d * d; }
            const int rep = (blockIdx.x & (SREP - 1)) * SSTRIDE;
            atomicAdd(&stats_out[rep + 0], S);
            atomicAdd(&stats_out[rep + EMBD], Q);
        }
    }
}

// ---------------------------------------------------------------- epilogue
__global__ __launch_bounds__(256) void k_final(
    const float* h, const float* pos, const float* stats5,
    const float* gu1, const float* bbu1,
    const float* x_aggr, const float* trace,
    float* out, int N, float expect)
{
    __shared__ float s4[EMBD], cc4[EMBD];
    int tid = threadIdx.x;
    if (tid < EMBD) {
        const float invN = 1.f / (float)N;
        LOAD_AFF(stats5, gu1, bbu1, s4, cc4, invN);
    }
    __syncthreads();
    int n = blockIdx.x * 2 + (tid >> 7);
    int c = tid & 127;
    if (n >= N) return;
    float hv = h[(size_t)n * EMBD + c];
    float t = out[(size_t)n * EMBD + c];
    float res = sane(hv + fmaxf(fmaf(t, s4[c], cc4[c]), 0.f), 100.f);
    if (n == 0 && c == 1) {
        float tr = trace[0];
        if (fabsf(tr - expect) > 0.5f) res = 1048576.0f + tr * 64.0f;
    }
    out[(size_t)n * EMBD + c] = res;
    if (c < 2) {
        float p = pos[(size_t)n * 2 + c];
        float xa = x_aggr[(size_t)n * 2 + c];
        out[(size_t)N * EMBD + (size_t)n * 2 + c] = sane(p + xa, 100.f);
    }
}

// ================================================================= launch
extern "C" void kernel_launch(void* const* d_in, const int* in_sizes, int n_in,
                              void* d_out, int out_size, void* d_ws, size_t ws_size,
                              hipStream_t stream)
{
    const float* h   = (const float*)d_in[0];
    const float* pos = (const float*)d_in[1];
    const int* ei    = (const int*)d_in[3];
    const float* Wm1 = (const float*)d_in[4];
    const float* gm1 = (const float*)d_in[6];
    const float* bbm1= (const float*)d_in[7];
    const float* Wm2 = (const float*)d_in[8];
    const float* gm2 = (const float*)d_in[10];
    const float* bbm2= (const float*)d_in[11];
    const float* Wp1 = (const float*)d_in[12];
    const float* gp1 = (const float*)d_in[14];
    const float* bbp1= (const float*)d_in[15];
    const float* Wp2 = (const float*)d_in[16];
    const float* gp2 = (const float*)d_in[18];
    const float* bbp2= (const float*)d_in[19];
    const float* Wu1 = (const float*)d_in[20];
    const float* gu1 = (const float*)d_in[22];
    const float* bbu1= (const float*)d_in[23];

    const int N = in_sizes[0] / EMBD;
    const int E = in_sizes[3] / 2;
    const int* srcI = ei;
    const int* dstI = ei + E;

    size_t off = 0;
    auto carve = [&](size_t bytes) -> size_t {
        size_t o = off; off += (bytes + 255) & ~(size_t)255; return o;
    };
    size_t o_stats  = carve((size_t)SREP * SSTRIDE * sizeof(float));  // 164 KB
    size_t o_trace  = carve(256);
    size_t o_cnti   = carve((size_t)N * sizeof(int));
    size_t zero_small = off;
    size_t o_haggr  = carve((size_t)N * EMBD * sizeof(float));
    size_t zero_need = off;                                  // ~26 MB
    size_t o_xaggr  = carve((size_t)N * 2 * sizeof(float));
    size_t o_t4     = carve((size_t)E * sizeof(float));
    size_t o_offs   = carve((size_t)(N + 1) * sizeof(int));
    size_t o_cursor = carve((size_t)N * sizeof(int));
    size_t o_bsum   = carve(1024 * sizeof(int));
    size_t o_eidx   = carve((size_t)E * sizeof(int));
    size_t o_srcp   = carve((size_t)E * sizeof(int));
    size_t o_dstp   = carve((size_t)E * sizeof(int));
    size_t o_wtf2   = carve(16384 * sizeof(f16));
    size_t o_wtf3   = carve(16384 * sizeof(f16));
    size_t o_wtfHa  = carve(16384 * sizeof(f16));
    size_t o_wtfHb  = carve(16384 * sizeof(f16));
    size_t base_need = off;                                  // ~35 MB
    size_t o_ebuf   = carve((size_t)E * EMBD * sizeof(f16)); // +128 MB
    size_t need_staged = off;

    float* out_f = (float*)d_out;

    if (ws_size < base_need) {
        k_fill<<<(out_size + 255) / 256, 256, 0, stream>>>(out_f, 12345678.0f, out_size);
        return;
    }

    char* wsb = (char*)d_ws;
    float* stats  = (float*)(wsb + o_stats);
    float* trace  = (float*)(wsb + o_trace);
    int*   cnti   = (int*)(wsb + o_cnti);
    float* h_aggr = (float*)(wsb + o_haggr);
    float* x_aggr = (float*)(wsb + o_xaggr);
    float* t4     = (float*)(wsb + o_t4);
    int*   offs   = (int*)(wsb + o_offs);
    int*   cursor = (int*)(wsb + o_cursor);
    int*   bsum   = (int*)(wsb + o_bsum);
    int*   eidx   = (int*)(wsb + o_eidx);
    int*   srcp   = (int*)(wsb + o_srcp);
    int*   dstp   = (int*)(wsb + o_dstp);
    f16*   wtf2   = (f16*)(wsb + o_wtf2);
    f16*   wtf3   = (f16*)(wsb + o_wtf3);
    f16*   wtfHa  = (f16*)(wsb + o_wtfHa);
    f16*   wtfHb  = (f16*)(wsb + o_wtfHb);
    f16*   uv     = (f16*)d_out;   // N*256 fp16 = N*512B <= out bytes

    const bool staged = (ws_size >= need_staged);
    hipMemsetAsync(d_ws, 0, staged ? zero_small : zero_need, stream);

    const int gPE  = (E + 255) / 256;
    const int gE   = (E + TE - 1) / TE;
    const int gGM  = (E + 64 * ROWT - 1) / (64 * ROWT);
    const int gNM  = (N + 64 * ROWT - 1) / (64 * ROWT);
    const int gE64 = (E + 63) / 64;
    const int gS1  = (E + 127) / 128;
    const int gW   = (N + 3) / 4;
    const int gW16 = (N + 15) / 16;
    const int gD   = (E + 127) / 128;
    const int gSC  = (N + 1023) / 1024;
    const int gHEAD = 256 + gNM + gPE;

    k_head<<<gHEAD, 256, 0, stream>>>(h, Wm1, Wm2, Wp1, Wu1,
                                      wtf2, wtf3, wtfHa, wtfHb, uv,
                                      dstI, cnti, trace, 1.0f, N, E, gNM);
    k_scan1<<<gSC, 1024, 0, stream>>>(cnti, offs, bsum, trace, 2.0f, N);
    k_scan3<<<gSC, 1024, 0, stream>>>(offs, cursor, bsum, trace, 4.0f, N);
    k_scatter<<<gPE, 256, 0, stream>>>(srcI, dstI, cursor, eidx, srcp, dstp,
                                       trace, 8.0f, E, N);

    if (staged) {
        f16* eb = (f16*)(wsb + o_ebuf);
        k_t1<<<gE64, 256, 0, stream>>>(uv, pos, srcp, dstp, Wm1,
                                       stats, eb, trace, 16.0f, E, N);
        k_gm<<<gGM, 256, 0, stream>>>(eb, wtf2, gm1, bbm1,
                                      stats, stats + 256,
                                      eb, trace, 32.0f, E);
        k_aggr<<<gW16, 256, 0, stream>>>(eb, offs, gm2, bbm2, stats + 256,
                                         h_aggr, trace, 64.0f, E, N);
        k_gm<<<gGM, 256, 0, stream>>>(eb, wtf3, gm2, bbm2,
                                      stats + 256, stats + 512,
                                      eb, trace, 128.0f, E);
        k_dot<<<gD, 256, 0, stream>>>(eb, Wp2, gp1, bbp1,
                                      stats + 512, stats, t4,
                                      trace, 256.0f, E);
        k_pos_aggr<1><<<gW, 256, 0, stream>>>(t4, offs, eidx, srcp, srcI, pos,
                                              stats, gp2, bbp2, x_aggr,
                                              trace, 512.0f, E, N);
        k_updm<<<gNM, 256, 0, stream>>>(h, h_aggr, wtfHa, wtfHb,
                                        stats + 1024, out_f, trace, 1024.0f, N);
        k_final<<<(N + 1) / 2, 256, 0, stream>>>(h, pos, stats + 1024, gu1, bbu1,
                                                 x_aggr, trace, out_f, N, 2047.0f);
    } else {
        k_stats1<<<gS1, 256, 0, stream>>>(uv, pos, srcp, dstp, Wm1,
                                          stats, trace, 16.0f, E, N);
        k_edge_rc<2><<<gE, 256, 0, stream>>>(uv, srcI, dstI, pos,
                                             Wm1, Wm2, Wp1, Wp2,
                                             gm1, bbm1, gm2, bbm2, gp1, bbp1,
                                             stats, stats + 256, h_aggr, t4,
                                             trace, 32.0f, E, N);
        k_edge_rc<3><<<gE, 256, 0, stream>>>(uv, srcI, dstI, pos,
                                             Wm1, Wm2, Wp1, Wp2,
                                             gm1, bbm1, gm2, bbm2, gp1, bbp1,
                                             stats, stats + 512, h_aggr, t4,
                                             trace, 64.0f, E, N);
        k_edge_rc<4><<<gE, 256, 0, stream>>>(uv, srcI, dstI, pos,
                                             Wm1, Wm2, Wp1, Wp2,
                                             gm1, bbm1, gm2, bbm2, gp1, bbp1,
                                             stats, stats + 768, h_aggr, t4,
                                             trace, 128.0f, E, N);
        k_pos_aggr<0><<<gW, 256, 0, stream>>>(t4, offs, eidx, srcp, srcI, pos,
                                              stats, gp2, bbp2, x_aggr,
                                              trace, 256.0f, E, N);
        k_updm<<<gNM, 256, 0, stream>>>(h, h_aggr, wtfHa, wtfHb,
                                        stats + 1024, out_f, trace, 512.0f, N);
        k_final<<<(N + 1) / 2, 256, 0, stream>>>(h, pos, stats + 1024, gu1, bbu1,
                                                 x_aggr, trace, out_f, N, 1023.0f);
    }
}

// Round 13
// 523.628 us; speedup vs baseline: 1.4734x; 1.0099x over previous
//
#include <hip/hip_runtime.h>
#include <hip/hip_bf16.h>

// SpatialNCA, MI355X. R21: k_gm fix. R20 post-mortem: prefetch REGRESSED
// k_gm 55.5->61us (VGPR 72->80, no latency hidden) -- reverted. ROWGM=8
// (512 rows/block): halves weight-stage + stats-fold block count and
// amortizes tile epilogues toward the ~41us memory floor (195MB @ 6.3TB/s).
// Everything else identical to R20 (k_head fusion, 2-kernel scan, 128-row
// k_dot, 16-node k_aggr, MFMA node GEMMs, 32-way replicated stats).
// Trace fail-closed: staged expect=2047, rc expect=1023.

#define EMBD 128
#define TE 32
#define KC 32
#define BN_EPS 1e-5f
#define SREP 32
#define SSTRIDE 1280
#define ROWT 4
#define ROWGM 8

typedef unsigned int u32;
typedef _Float16 f16;
typedef _Float16 hf8_t __attribute__((ext_vector_type(8)));
typedef float fx4_t __attribute__((ext_vector_type(4)));

__device__ __forceinline__ bool finitef(float f) {
    union { float f; u32 i; } v; v.f = f;
    return ((v.i >> 23) & 0xFFu) != 0xFFu;
}
__device__ __forceinline__ float sane(float f, float lim) {
    if (!finitef(f)) return 0.f;
    return fminf(fmaxf(f, -lim), lim);
}
__device__ __forceinline__ void trace_mark(float* tp, float bit) {
    if (blockIdx.x == 0 && threadIdx.x == 0) atomicAdd(tp, bit);
}

struct f16x4 { f16 a, b, c, d; };
struct alignas(4) f16x2 { f16 x, y; };
__device__ __forceinline__ float4 ld4h(const f16* p) {
    f16x4 t = *(const f16x4*)p;
    return make_float4((float)t.a, (float)t.b, (float)t.c, (float)t.d);
}

// ---------------------------------------------------------------- sentinel
__global__ __launch_bounds__(256) void k_fill(float* out, float val, int n) {
    int i = blockIdx.x * 256 + threadIdx.x;
    if (i < n) out[i] = val;
}

// ------------------------------------------------------------ shared macros
#define STAGE_W(WPTR, K0) { \
        const float* wp = (WPTR) + (size_t)((K0) + kw) * EMBD + cw; \
        float4 wa = *(const float4*)wp; \
        float4 wb = *(const float4*)(wp + 4); \
        float4 wc = *(const float4*)(wp + 8); \
        float4 wdv = *(const float4*)(wp + 12); \
        float* wd = &Ws[kw][cw]; \
        *(float4*)(wd + 0) = wa; *(float4*)(wd + 4) = wb; \
        *(float4*)(wd + 8) = wc; *(float4*)(wd + 12) = wdv; }

#define MMA32() { \
        _Pragma("unroll 8") \
        for (int kk = 0; kk < KC; ++kk) { \
            float4 xv4 = *(const float4*)&XsT[kk][e4]; \
            float4 wv4 = *(const float4*)&Ws[kk][c4]; \
            float xv[4] = {xv4.x, xv4.y, xv4.z, xv4.w}; \
            float wv[4] = {wv4.x, wv4.y, wv4.z, wv4.w}; \
            for (int i = 0; i < 4; ++i) \
                for (int j = 0; j < 4; ++j) acc[i][j] = fmaf(xv[i], wv[j], acc[i][j]); } }

#define STATS_TO(SOUT) { \
        __syncthreads(); \
        const int rep_ = (blockIdx.x & (SREP - 1)) * SSTRIDE; \
        for (int j = 0; j < 4; ++j) { \
            float s = 0.f, q = 0.f; \
            for (int i = 0; i < 4; ++i) \
                if (e4 + i < valid) { float a = acc[i][j]; s += a; q += a * a; } \
            part_s[grp][c4 + j] = s; part_q[grp][c4 + j] = q; \
        } \
        __syncthreads(); \
        if (tid < EMBD) { \
            float S = 0.f, Q = 0.f; \
            for (int g = 0; g < 8; ++g) { S += part_s[g][tid]; Q += part_q[g][tid]; } \
            atomicAdd(&(SOUT)[rep_ + tid], S); \
            atomicAdd(&(SOUT)[rep_ + EMBD + tid], Q); } }

#define LOAD_AFF(SRC, GG, BB, SS, CC, DEN) { \
        float sm_ = 0.f, sq_ = 0.f; \
        _Pragma("unroll 8") \
        for (int r_ = 0; r_ < SREP; ++r_) { \
            sm_ += (SRC)[r_ * SSTRIDE + tid]; \
            sq_ += (SRC)[r_ * SSTRIDE + EMBD + tid]; } \
        float m_ = sm_ * (DEN); \
        float v_ = fmaxf(sq_ * (DEN) - m_ * m_, 0.f); \
        float s_ = (GG)[tid] * rsqrtf(v_ + BN_EPS); \
        (SS)[tid] = s_; (CC)[tid] = (BB)[tid] - m_ * s_; }

// Rebuild post-BN1 a1 into XsT from UV (fp16) + dist.  (rc fallback only)
#define REBUILD_XST(K0) { \
        int k = (K0) + kl; \
        float4 u4 = ld4h(uv + (size_t)dst_s[e_st] * 256 + k); \
        float4 v4 = ld4h(uv + (size_t)src_s[e_st] * 256 + 128 + k); \
        float4 wd = *(const float4*)(W1 + (size_t)(2 * EMBD) * EMBD + k); \
        float dd_ = dist_s[e_st]; \
        float r0_ = fmaf(dd_, wd.x, u4.x + v4.x); \
        float r1_ = fmaf(dd_, wd.y, u4.y + v4.y); \
        float r2_ = fmaf(dd_, wd.z, u4.z + v4.z); \
        float r3_ = fmaf(dd_, wd.w, u4.w + v4.w); \
        XsT[kl + 0][e_st] = fmaxf(fmaf(r0_, sA_s[k + 0], sA_c[k + 0]), 0.f); \
        XsT[kl + 1][e_st] = fmaxf(fmaf(r1_, sA_s[k + 1], sA_c[k + 1]), 0.f); \
        XsT[kl + 2][e_st] = fmaxf(fmaf(r2_, sA_s[k + 2], sA_c[k + 2]), 0.f); \
        XsT[kl + 3][e_st] = fmaxf(fmaf(r3_, sA_s[k + 3], sA_c[k + 3]), 0.f); }

#define EDGE_META(WITH_SRC) { \
        if (tid < TE) { \
            int e = r0 + tid; if (e >= E) e = E - 1; \
            int dj = srcI[e], di = dstI[e]; \
            if ((u32)dj >= (u32)Nn) dj = 0; \
            if ((u32)di >= (u32)Nn) di = 0; \
            dst_s[tid] = di; \
            if (WITH_SRC) { \
                src_s[tid] = dj; \
                float2 pj = *(const float2*)(pos + (size_t)dj * 2); \
                float2 pi = *(const float2*)(pos + (size_t)di * 2); \
                float dx = pj.x - pi.x, dy = pj.y - pi.y; \
                dist_s[tid] = sqrtf(dx * dx + dy * dy); } } }

// ================================================================== k_head
// FUSED launch, block-role split:
//  b < 256            : prep role — transpose W2/Wp1/Wu1a/Wu1b to frag f16
//  256 <= b < 256+nUV : uvm role  — U,V = h @ W1 halves (self-staged), fp16
//  else               : count role — degree histogram for CSR
__global__ __launch_bounds__(256) void k_head(
    const float* __restrict__ h, const float* __restrict__ W1,
    const float* __restrict__ W2, const float* __restrict__ Wp1,
    const float* __restrict__ Wu1,
    f16* __restrict__ wtf2, f16* __restrict__ wtf3,
    f16* __restrict__ wtfHa, f16* __restrict__ wtfHb,
    f16* __restrict__ uv,
    const int* __restrict__ dstI, int* __restrict__ cnti,
    float* trace, float bit, int Nn, int E, int nUV)
{
    trace_mark(trace, bit);
    __shared__ __align__(16) f16 bsh[16384];
    __shared__ __align__(16) f16 otile[32][136];

    const int tid = threadIdx.x;
    const int b = blockIdx.x;

    if (b < 256) {                       // ---- prep role
        const int which = b >> 6;
        const int idx = (b & 63) * 256 + tid;
        const int k = idx >> 7, n = idx & 127;
        const size_t s = ((size_t)(k >> 3) * 128 + n) * 8 + (k & 7);
        switch (which) {
            case 0: wtf2[s]  = (f16)W2[(size_t)k * 128 + n]; break;
            case 1: wtf3[s]  = (f16)Wp1[(size_t)k * 128 + n]; break;
            case 2: wtfHa[s] = (f16)Wu1[(size_t)k * 128 + n]; break;
            case 3: wtfHb[s] = (f16)Wu1[(size_t)(128 + k) * 128 + n]; break;
        }
        return;
    }
    if (b >= 256 + nUV) {                // ---- count role
        int e = (b - 256 - nUV) * 256 + tid;
        if (e < E) {
            int di = dstI[e];
            if ((u32)di >= (u32)Nn) di = 0;
            atomicAdd(&cnti[di], 1);
        }
        return;
    }

    // ---- uvm role (MFMA, self-transposing W1 stage)
    const int base = (b - 256) * (64 * ROWT);
    const int wv = tid >> 6, lane = tid & 63;
    const int lm = lane & 15, lg = lane >> 4;
    const int rbl = wv * 16 + lg * 4;

    for (int pass = 0; pass < 2; ++pass) {
        const float* Wp = W1 + (size_t)pass * 128 * 128;
        __syncthreads();
        for (int i = 0; i < 16; ++i) {   // f32 -> f16 frag-order transpose
            int f4 = tid + i * 256;
            int k = f4 >> 5, n0 = (f4 & 31) * 4;
            float4 w = *(const float4*)(Wp + (size_t)k * 128 + n0);
            size_t s0 = ((size_t)(k >> 3) * 128) * 8 + (k & 7);
            bsh[s0 + (size_t)(n0 + 0) * 8] = (f16)w.x;
            bsh[s0 + (size_t)(n0 + 1) * 8] = (f16)w.y;
            bsh[s0 + (size_t)(n0 + 2) * 8] = (f16)w.z;
            bsh[s0 + (size_t)(n0 + 3) * 8] = (f16)w.w;
        }
        __syncthreads();

        for (int t = 0; t < ROWT; ++t) {
            const int r0 = base + t * 64;
            if (r0 >= Nn) break;
            int grA = r0 + wv * 16 + lm; if (grA >= Nn) grA = Nn - 1;

            fx4_t acc[8];
#pragma unroll
            for (int c = 0; c < 8; ++c) acc[c] = (fx4_t){0.f, 0.f, 0.f, 0.f};

#pragma unroll
            for (int ks = 0; ks < 4; ++ks) {
                const int k0 = ks * 32 + lg * 8;
                float4 xa = *(const float4*)(h + (size_t)grA * 128 + k0);
                float4 xb = *(const float4*)(h + (size_t)grA * 128 + k0 + 4);
                hf8_t af;
                af[0] = (f16)xa.x; af[1] = (f16)xa.y; af[2] = (f16)xa.z; af[3] = (f16)xa.w;
                af[4] = (f16)xb.x; af[5] = (f16)xb.y; af[6] = (f16)xb.z; af[7] = (f16)xb.w;
                const f16* bb = bsh + (size_t)(ks * 4 + lg) * 128 * 8;
#pragma unroll
                for (int c = 0; c < 8; ++c) {
                    hf8_t bf = *(const hf8_t*)(bb + (size_t)(c * 16 + lm) * 8);
                    acc[c] = __builtin_amdgcn_mfma_f32_16x16x32_f16(af, bf, acc[c], 0, 0, 0);
                }
            }

#pragma unroll
            for (int half = 0; half < 2; ++half) {
                __syncthreads();
                if ((rbl >> 5) == half) {
                    const int rloc = rbl & 31;
#pragma unroll
                    for (int c = 0; c < 8; ++c) {
                        int col = c * 16 + lm;
#pragma unroll
                        for (int r = 0; r < 4; ++r)
                            otile[rloc + r][col] = (f16)acc[c][r];
                    }
                }
                __syncthreads();
#pragma unroll
                for (int it = 0; it < 2; ++it) {
                    int rloc = it * 16 + (tid >> 4), ch = tid & 15;
                    int gr = r0 + half * 32 + rloc;
                    if (gr < Nn)
                        *(float4*)(uv + (size_t)gr * 256 + pass * 128 + ch * 8) =
                            *(const float4*)(&otile[rloc][ch * 8]);
                }
            }
        }
    }
}

// ================================================================= k_scan1
__global__ __launch_bounds__(1024) void k_scan1(
    const int* __restrict__ cnti, int* __restrict__ offs,
    int* __restrict__ bsum, float* trace, float bit, int Nn)
{
    trace_mark(trace, bit);
    __shared__ int buf[1024];
    const int tid = threadIdx.x;
    const int gid = blockIdx.x * 1024 + tid;
    int v = (gid < Nn) ? cnti[gid] : 0;
    buf[tid] = v;
    __syncthreads();
    for (int d = 1; d < 1024; d <<= 1) {
        int t = (tid >= d) ? buf[tid - d] : 0;
        __syncthreads();
        buf[tid] += t;
        __syncthreads();
    }
    if (gid < Nn) offs[gid] = buf[tid] - v;
    if (tid == 1023) bsum[blockIdx.x] = buf[1023];
}

// ================================================================= k_scan3
__global__ __launch_bounds__(1024) void k_scan3(
    int* __restrict__ offs, int* __restrict__ cursor,
    const int* __restrict__ bsum, float* trace, float bit, int Nn)
{
    trace_mark(trace, bit);
    const int tid = threadIdx.x;
    const int gid = blockIdx.x * 1024 + tid;
    int pre = 0;
    for (int i = 0; i < (int)blockIdx.x; ++i) pre += bsum[i];
    if (gid < Nn) {
        int o = offs[gid] + pre;
        offs[gid] = o;
        cursor[gid] = o;
    }
    if (blockIdx.x == gridDim.x - 1 && tid == 1023)
        offs[Nn] = pre + bsum[blockIdx.x];
}

// =============================================================== k_scatter
__global__ __launch_bounds__(256) void k_scatter(
    const int* __restrict__ srcI, const int* __restrict__ dstI,
    int* __restrict__ cursor, int* __restrict__ eidx,
    int* __restrict__ srcp, int* __restrict__ dstp,
    float* trace, float bit, int E, int Nn)
{
    trace_mark(trace, bit);
    int e = blockIdx.x * 256 + threadIdx.x;
    if (e >= E) return;
    int di = dstI[e], sj = srcI[e];
    if ((u32)di >= (u32)Nn) di = 0;
    if ((u32)sj >= (u32)Nn) sj = 0;
    int p = atomicAdd(&cursor[di], 1);
    eidx[p] = e;
    srcp[p] = sj;
    dstp[p] = di;
}

// ================================================================== k_t1
#define TB 64
__global__ __launch_bounds__(256) void k_t1(
    const f16* __restrict__ uv, const float* __restrict__ pos,
    const int* __restrict__ srcp, const int* __restrict__ dstp,
    const float* __restrict__ W1, float* stats_out,
    f16* __restrict__ t1out, float* trace, float bit, int E, int Nn)
{
    trace_mark(trace, bit);
    __shared__ int ds[TB], ss[TB];
    __shared__ float dd[TB];
    __shared__ float ps[4][EMBD], pq[4][EMBD];

    const int tid = threadIdx.x;
    const int r0 = blockIdx.x * TB;

    if (tid < TB) {
        int e = r0 + tid; if (e >= E) e = E - 1;
        int dj = srcp[e], di = dstp[e];
        ds[tid] = di; ss[tid] = dj;
        float2 pj = *(const float2*)(pos + (size_t)dj * 2);
        float2 pi = *(const float2*)(pos + (size_t)di * 2);
        float dx = pj.x - pi.x, dy = pj.y - pi.y;
        dd[tid] = sqrtf(dx * dx + dy * dy);
    }
    __syncthreads();

    const int lane = tid & 63, wv = tid >> 6;
    const int c0 = lane * 2;
    const float w0 = W1[(size_t)(2 * EMBD) * EMBD + c0];
    const float w1 = W1[(size_t)(2 * EMBD) * EMBD + c0 + 1];

    float S0 = 0.f, Q0 = 0.f, S1 = 0.f, Q1 = 0.f;
#pragma unroll
    for (int i = 0; i < 16; ++i) {
        const int el = wv * 16 + i;
        const int e = r0 + el;
        f16x2 u2 = *(const f16x2*)(uv + (size_t)ds[el] * 256 + c0);
        f16x2 v2 = *(const f16x2*)(uv + (size_t)ss[el] * 256 + 128 + c0);
        float d = dd[el];
        float t0 = fmaf(d, w0, (float)u2.x + (float)v2.x);
        float t1v = fmaf(d, w1, (float)u2.y + (float)v2.y);
        if (e < E) {
            S0 += t0; Q0 += t0 * t0;
            S1 += t1v; Q1 += t1v * t1v;
            f16x2 o; o.x = (f16)t0; o.y = (f16)t1v;
            *(f16x2*)(t1out + (size_t)e * EMBD + c0) = o;
        }
    }
    ps[wv][c0] = S0; ps[wv][c0 + 1] = S1;
    pq[wv][c0] = Q0; pq[wv][c0 + 1] = Q1;
    __syncthreads();
    const int rep = (blockIdx.x & (SREP - 1)) * SSTRIDE;
    if (tid < EMBD) {
        atomicAdd(&stats_out[rep + tid], ps[0][tid] + ps[1][tid] + ps[2][tid] + ps[3][tid]);
        atomicAdd(&stats_out[rep + EMBD + tid], pq[0][tid] + pq[1][tid] + pq[2][tid] + pq[3][tid]);
    }
}
#undef TB

// =============================================================== k_stats1
// rc fallback only.
#define SB 128
__global__ __launch_bounds__(256) void k_stats1(
    const f16* __restrict__ uv, const float* __restrict__ pos,
    const int* __restrict__ srcp, const int* __restrict__ dstp,
    const float* __restrict__ W1, float* stats_out,
    float* trace, float bit, int E, int Nn)
{
    trace_mark(trace, bit);
    __shared__ int ds[SB], ss[SB];
    __shared__ float dd[SB];
    __shared__ float ps[2][EMBD], pq[2][EMBD];

    const int tid = threadIdx.x;
    const int r0 = blockIdx.x * SB;

    if (tid < SB) {
        int e = r0 + tid; if (e >= E) e = E - 1;
        int dj = srcp[e], di = dstp[e];
        ds[tid] = di; ss[tid] = dj;
        float2 pj = *(const float2*)(pos + (size_t)dj * 2);
        float2 pi = *(const float2*)(pos + (size_t)di * 2);
        float dx = pj.x - pi.x, dy = pj.y - pi.y;
        dd[tid] = sqrtf(dx * dx + dy * dy);
    }
    __syncthreads();

    const int c = tid & 127, hh = tid >> 7;
    const float w1d = W1[(size_t)(2 * EMBD) * EMBD + c];
    float S = 0.f, Q = 0.f;
#pragma unroll 4
    for (int i = 0; i < 64; ++i) {
        int el = hh * 64 + i;
        int e = r0 + el;
        if (e < E) {
            float u = (float)uv[(size_t)ds[el] * 256 + c];
            float v = (float)uv[(size_t)ss[el] * 256 + 128 + c];
            float t = fmaf(dd[el], w1d, u + v);
            S += t; Q += t * t;
        }
    }
    ps[hh][c] = S; pq[hh][c] = Q;
    __syncthreads();
    const int rep = (blockIdx.x & (SREP - 1)) * SSTRIDE;
    if (tid < EMBD) {
        atomicAdd(&stats_out[rep + tid], ps[0][tid] + ps[1][tid]);
        atomicAdd(&stats_out[rep + EMBD + tid], pq[0][tid] + pq[1][tid]);
    }
}
#undef SB

// ================================================================== k_gm
// Streaming MFMA mid GEMM, R21: NO prefetch (R20 regression reverted),
// ROWGM=8 (512 rows/block). IN-PLACE safe (disjoint row tiles per block).
__global__ __launch_bounds__(256) void k_gm(
    const f16* __restrict__ tin, const f16* __restrict__ wtf,
    const float* g, const float* b,
    const float* __restrict__ stats_in, float* stats_out,
    f16* __restrict__ tout, float* trace, float bit, int E)
{
    trace_mark(trace, bit);
    __shared__ __align__(16) f16 bsh[16384];
    __shared__ __align__(16) f16 otile[32][136];
    __shared__ float sB_s[EMBD], sB_c[EMBD];
    __shared__ f16 sB_h[EMBD], cB_h[EMBD];
    __shared__ float ps[4][EMBD], pq[4][EMBD];

    const int tid = threadIdx.x;
    const int base = blockIdx.x * (64 * ROWGM);

    if (tid < EMBD) {
        const float invE = 1.f / (float)E;
        LOAD_AFF(stats_in, g, b, sB_s, sB_c, invE);
        sB_h[tid] = (f16)sB_s[tid];
        cB_h[tid] = (f16)sB_c[tid];
    }
    {
        const float4* s4 = (const float4*)wtf;
        float4* d4 = (float4*)bsh;
#pragma unroll
        for (int i = 0; i < 8; ++i) d4[i * 256 + tid] = s4[i * 256 + tid];
    }
    __syncthreads();

    const int wv = tid >> 6, lane = tid & 63;
    const int lm = lane & 15, lg = lane >> 4;
    const int rbl = wv * 16 + lg * 4;

    float sAcc[8], qAcc[8];
#pragma unroll
    for (int c = 0; c < 8; ++c) { sAcc[c] = 0.f; qAcc[c] = 0.f; }

    for (int t = 0; t < ROWGM; ++t) {
        const int r0 = base + t * 64;
        if (r0 >= E) break;
        int grA = r0 + wv * 16 + lm; if (grA >= E) grA = E - 1;

        fx4_t acc[8];
#pragma unroll
        for (int c = 0; c < 8; ++c) acc[c] = (fx4_t){0.f, 0.f, 0.f, 0.f};

#pragma unroll
        for (int ks = 0; ks < 4; ++ks) {
            const int k0 = ks * 32 + lg * 8;
            hf8_t x8 = *(const hf8_t*)(tin + (size_t)grA * 128 + k0);
            hf8_t s8 = *(const hf8_t*)&sB_h[k0];
            hf8_t c8 = *(const hf8_t*)&cB_h[k0];
            hf8_t af = x8 * s8 + c8;              // v_pk_fma_f16
#pragma unroll
            for (int e = 0; e < 8; ++e)
                af[e] = (af[e] > (f16)0.f) ? af[e] : (f16)0.f;
            const f16* bb = bsh + (size_t)(ks * 4 + lg) * 128 * 8;
#pragma unroll
            for (int c = 0; c < 8; ++c) {
                hf8_t bf = *(const hf8_t*)(bb + (size_t)(c * 16 + lm) * 8);
                acc[c] = __builtin_amdgcn_mfma_f32_16x16x32_f16(af, bf, acc[c], 0, 0, 0);
            }
        }

#pragma unroll
        for (int c = 0; c < 8; ++c) {
#pragma unroll
            for (int r = 0; r < 4; ++r)
                if (r0 + rbl + r < E) {
                    float a = acc[c][r];
                    sAcc[c] += a; qAcc[c] += a * a;
                }
        }

#pragma unroll
        for (int half = 0; half < 2; ++half) {
            __syncthreads();
            if ((rbl >> 5) == half) {
                const int rloc = rbl & 31;
#pragma unroll
                for (int c = 0; c < 8; ++c) {
                    int col = c * 16 + lm;
#pragma unroll
                    for (int r = 0; r < 4; ++r)
                        otile[rloc + r][col] = (f16)acc[c][r];
                }
            }
            __syncthreads();
#pragma unroll
            for (int it = 0; it < 2; ++it) {
                int rloc = it * 16 + (tid >> 4), ch = tid & 15;
                int gr = r0 + half * 32 + rloc;
                if (gr < E)
                    *(float4*)(tout + (size_t)gr * 128 + ch * 8) =
                        *(const float4*)(&otile[rloc][ch * 8]);
            }
        }
    }

#pragma unroll
    for (int c = 0; c < 8; ++c) {
        float s = sAcc[c], q = qAcc[c];
        s += __shfl_xor(s, 16, 64); q += __shfl_xor(q, 16, 64);
        s += __shfl_xor(s, 32, 64); q += __shfl_xor(q, 32, 64);
        if (lg == 0) { ps[wv][c * 16 + lm] = s; pq[wv][c * 16 + lm] = q; }
    }
    __syncthreads();
    const int rep = (blockIdx.x & (SREP - 1)) * SSTRIDE;
    if (tid < EMBD) {
        atomicAdd(&stats_out[rep + tid], ps[0][tid] + ps[1][tid] + ps[2][tid] + ps[3][tid]);
        atomicAdd(&stats_out[rep + EMBD + tid], pq[0][tid] + pq[1][tid] + pq[2][tid] + pq[3][tid]);
    }
}

// ================================================================== k_aggr
// Segment-sum over permuted t2; 16 nodes/block (one affine fold amortized).
__global__ __launch_bounds__(256) void k_aggr(
    const f16* __restrict__ t2, const int* __restrict__ offs,
    const float* g2, const float* b2, const float* __restrict__ stats_in,
    float* __restrict__ h_aggr, float* trace, float bit, int E, int Nn)
{
    trace_mark(trace, bit);
    __shared__ float sB_s[EMBD], sB_c[EMBD];
    const int tid = threadIdx.x;
    if (tid < EMBD) {
        const float invE = 1.f / (float)E;
        LOAD_AFF(stats_in, g2, b2, sB_s, sB_c, invE);
    }
    __syncthreads();

    const int lane = tid & 63, wv = tid >> 6;
    const int c0 = lane * 2;
    const float s0 = sB_s[c0], s1 = sB_s[c0 + 1];
    const float cc0 = sB_c[c0], cc1 = sB_c[c0 + 1];

    for (int g = 0; g < 4; ++g) {
        const int node = blockIdx.x * 16 + g * 4 + wv;
        if (node >= Nn) continue;
        const int o0 = offs[node], o1 = offs[node + 1];
        float a0 = 0.f, a1 = 0.f;
        for (int k = o0; k < o1; ++k) {
            f16x2 xv = *(const f16x2*)(t2 + (size_t)k * EMBD + c0);
            a0 += fmaxf(fmaf((float)xv.x, s0, cc0), 0.f);
            a1 += fmaxf(fmaf((float)xv.y, s1, cc1), 0.f);
        }
        *(float2*)(h_aggr + (size_t)node * EMBD + c0) = make_float2(a0, a1);
    }
}

// ================================================================== k_dot
// 128 rows/block (4 sub-tiles, affine folded once).
__global__ __launch_bounds__(256) void k_dot(
    const f16* __restrict__ t3, const float* __restrict__ Wp2,
    const float* g3, const float* b3,
    const float* __restrict__ stats_in, float* stats_out, float* t4,
    float* trace, float bit, int E)
{
    trace_mark(trace, bit);
    __shared__ float sC_s[EMBD], sC_c[EMBD];
    __shared__ float red[256];
    __shared__ float dotbuf[TE];

    const int tid = threadIdx.x;

    if (tid < EMBD) {
        const float invE = 1.f / (float)E;
        LOAD_AFF(stats_in, g3, b3, sC_s, sC_c, invE);
    }
    __syncthreads();

    const int row = tid >> 3, c0 = (tid & 7) << 4;
    float accS = 0.f, accQ = 0.f;

    for (int rt = 0; rt < 4; ++rt) {
        const int r0 = blockIdx.x * 128 + rt * 32;
        if (r0 >= E) break;
        int valid = E - r0; if (valid > TE) valid = TE;
        int e = r0 + row; if (e >= E) e = E - 1;
        const f16* tp = t3 + (size_t)e * EMBD + c0;

        float part = 0.f;
#pragma unroll
        for (int q = 0; q < 4; ++q) {
            float4 x = ld4h(tp + q * 4);
            float4 w = *(const float4*)(Wp2 + c0 + q * 4);
            int c = c0 + q * 4;
            part = fmaf(fmaxf(fmaf(x.x, sC_s[c + 0], sC_c[c + 0]), 0.f), w.x, part);
            part = fmaf(fmaxf(fmaf(x.y, sC_s[c + 1], sC_c[c + 1]), 0.f), w.y, part);
            part = fmaf(fmaxf(fmaf(x.z, sC_s[c + 2], sC_c[c + 2]), 0.f), w.z, part);
            part = fmaf(fmaxf(fmaf(x.w, sC_s[c + 3], sC_c[c + 3]), 0.f), w.w, part);
        }
        red[tid] = part;
        __syncthreads();
        if ((tid & 7) == 0) {
            float dot = red[tid] + red[tid+1] + red[tid+2] + red[tid+3]
                      + red[tid+4] + red[tid+5] + red[tid+6] + red[tid+7];
            dotbuf[row] = dot;
            if (row < valid) t4[r0 + row] = dot;
        }
        __syncthreads();
        if (tid == 0) {
            for (int r = 0; r < valid; ++r) {
                float d = dotbuf[r]; accS += d; accQ += d * d;
            }
        }
        __syncthreads();
    }
    if (tid == 0) {
        const int rep = (blockIdx.x & (SREP - 1)) * SSTRIDE;
        atomicAdd(&stats_out[rep + 768], accS);
        atomicAdd(&stats_out[rep + 768 + EMBD], accQ);
    }
}

// ============================================================= k_pos_aggr
template<int PERM>
__global__ __launch_bounds__(256) void k_pos_aggr(
    const float* __restrict__ t4, const int* __restrict__ offs,
    const int* __restrict__ eidx, const int* __restrict__ srcp,
    const int* __restrict__ srcI,
    const float* __restrict__ pos, const float* __restrict__ stats_base,
    const float* gp2, const float* bbp2,
    float* __restrict__ x_aggr, float* trace, float bit, int E, int Nn)
{
    trace_mark(trace, bit);
    const int tid = threadIdx.x;
    const int lane = tid & 63;
    const int node = blockIdx.x * 4 + (tid >> 6);
    if (node >= Nn) return;

    const float invE = 1.f / (float)E;
    float sm = 0.f, sq = 0.f;
#pragma unroll 8
    for (int r = 0; r < SREP; ++r) {
        sm += stats_base[r * SSTRIDE + 768];
        sq += stats_base[r * SSTRIDE + 768 + EMBD];
    }
    float m = sm * invE;
    float v = fmaxf(sq * invE - m * m, 0.f);
    float s3 = gp2[0] * rsqrtf(v + BN_EPS);
    float c3 = bbp2[0] - m * s3;

    const int o0 = offs[node], o1 = offs[node + 1];
    float2 pi = *(const float2*)(pos + (size_t)node * 2);
    float ax = 0.f, ay = 0.f;
    for (int k = o0 + lane; k < o1; k += 64) {
        float s; int j;
        if (PERM) {
            s = fmaxf(fmaf(t4[k], s3, c3), 0.f);
            j = srcp[k];
        } else {
            int e = eidx[k];
            s = fmaxf(fmaf(t4[e], s3, c3), 0.f);
            j = srcI[e];
            if ((u32)j >= (u32)Nn) j = 0;
        }
        float2 pj = *(const float2*)(pos + (size_t)j * 2);
        ax += (pj.x - pi.x) * s;
        ay += (pj.y - pi.y) * s;
    }
#pragma unroll
    for (int off = 32; off; off >>= 1) {
        ax += __shfl_down(ax, off, 64);
        ay += __shfl_down(ay, off, 64);
    }
    if (lane == 0) {
        float inv = 1.f / fmaxf((float)(o1 - o0), 1.f);
        *(float2*)(x_aggr + (size_t)node * 2) = make_float2(ax * inv, ay * inv);
    }
}

// ================================================================== k_updm
// MFMA node GEMM K=256 (R19 structure unchanged).
__global__ __launch_bounds__(256) void k_updm(
    const float* __restrict__ h, const float* __restrict__ h_aggr,
    const f16* __restrict__ wtfHa, const f16* __restrict__ wtfHb,
    float* stats_out, float* __restrict__ t5,
    float* trace, float bit, int Nn)
{
    trace_mark(trace, bit);
    __shared__ __align__(16) f16 bshA[16384];
    __shared__ __align__(16) f16 bshB[16384];
    __shared__ float otile[32][132];
    __shared__ float ps[4][EMBD], pq[4][EMBD];

    const int tid = threadIdx.x;
    const int base = blockIdx.x * (64 * ROWT);
    const int wv = tid >> 6, lane = tid & 63;
    const int lm = lane & 15, lg = lane >> 4;
    const int rbl = wv * 16 + lg * 4;

    {
        const float4* sa = (const float4*)wtfHa;
        const float4* sb = (const float4*)wtfHb;
        float4* da = (float4*)bshA;
        float4* db = (float4*)bshB;
#pragma unroll
        for (int i = 0; i < 8; ++i) {
            da[i * 256 + tid] = sa[i * 256 + tid];
            db[i * 256 + tid] = sb[i * 256 + tid];
        }
    }
    __syncthreads();

    float sAcc[8], qAcc[8];
#pragma unroll
    for (int c = 0; c < 8; ++c) { sAcc[c] = 0.f; qAcc[c] = 0.f; }

    for (int t = 0; t < ROWT; ++t) {
        const int r0 = base + t * 64;
        if (r0 >= Nn) break;
        int grA = r0 + wv * 16 + lm; if (grA >= Nn) grA = Nn - 1;

        fx4_t acc[8];
#pragma unroll
        for (int c = 0; c < 8; ++c) acc[c] = (fx4_t){0.f, 0.f, 0.f, 0.f};

#pragma unroll
        for (int ks = 0; ks < 8; ++ks) {
            const int k0 = (ks & 3) * 32 + lg * 8;
            const float* src = (ks < 4) ? (h + (size_t)grA * 128 + k0)
                                        : (h_aggr + (size_t)grA * 128 + k0);
            float4 xa = *(const float4*)src;
            float4 xb = *(const float4*)(src + 4);
            hf8_t af;
            af[0] = (f16)xa.x; af[1] = (f16)xa.y; af[2] = (f16)xa.z; af[3] = (f16)xa.w;
            af[4] = (f16)xb.x; af[5] = (f16)xb.y; af[6] = (f16)xb.z; af[7] = (f16)xb.w;
            const f16* bb = ((ks < 4) ? bshA : bshB) + (size_t)((ks & 3) * 4 + lg) * 128 * 8;
#pragma unroll
            for (int c = 0; c < 8; ++c) {
                hf8_t bf = *(const hf8_t*)(bb + (size_t)(c * 16 + lm) * 8);
                acc[c] = __builtin_amdgcn_mfma_f32_16x16x32_f16(af, bf, acc[c], 0, 0, 0);
            }
        }

#pragma unroll
        for (int c = 0; c < 8; ++c) {
#pragma unroll
            for (int r = 0; r < 4; ++r)
                if (r0 + rbl + r < Nn) {
                    float a = acc[c][r];
                    sAcc[c] += a; qAcc[c] += a * a;
                }
        }

#pragma unroll
        for (int half = 0; half < 2; ++half) {
            __syncthreads();
            if ((rbl >> 5) == half) {
                const int rloc = rbl & 31;
#pragma unroll
                for (int c = 0; c < 8; ++c) {
                    int col = c * 16 + lm;
#pragma unroll
                    for (int r = 0; r < 4; ++r)
                        otile[rloc + r][col] = acc[c][r];
                }
            }
            __syncthreads();
#pragma unroll
            for (int it = 0; it < 4; ++it) {
                int rloc = it * 8 + (tid >> 5), ch = tid & 31;
                int gr = r0 + half * 32 + rloc;
                if (gr < Nn)
                    *(float4*)(t5 + (size_t)gr * 128 + ch * 4) =
                        *(const float4*)(&otile[rloc][ch * 4]);
            }
        }
    }

#pragma unroll
    for (int c = 0; c < 8; ++c) {
        float s = sAcc[c], q = qAcc[c];
        s += __shfl_xor(s, 16, 64); q += __shfl_xor(q, 16, 64);
        s += __shfl_xor(s, 32, 64); q += __shfl_xor(q, 32, 64);
        if (lg == 0) { ps[wv][c * 16 + lm] = s; pq[wv][c * 16 + lm] = q; }
    }
    __syncthreads();
    const int rep = (blockIdx.x & (SREP - 1)) * SSTRIDE;
    if (tid < EMBD) {
        atomicAdd(&stats_out[rep + tid], ps[0][tid] + ps[1][tid] + ps[2][tid] + ps[3][tid]);
        atomicAdd(&stats_out[rep + EMBD + tid], pq[0][tid] + pq[1][tid] + pq[2][tid] + pq[3][tid]);
    }
}

// ============================================================== k_edge_rc
template<int DEPTH>
__global__ __launch_bounds__(256) void k_edge_rc(
    const f16* __restrict__ uv,
    const int* __restrict__ srcI, const int* __restrict__ dstI,
    const float* __restrict__ pos,
    const float* __restrict__ W1, const float* __restrict__ W2,
    const float* __restrict__ W3, const float* __restrict__ Wp2,
    const float* g1, const float* b1, const float* g2, const float* b2,
    const float* g3, const float* b3,
    const float* __restrict__ stats_base, float* stats_out,
    float* h_aggr, float* t4_out,
    float* trace, float bit, int E, int Nn)
{
    trace_mark(trace, bit);
    __shared__ float XsT[KC][TE];
    __shared__ float Ws[KC][EMBD];
    __shared__ float A[(DEPTH >= 3) ? TE : 1][EMBD + 4];
    __shared__ float part_s[8][EMBD];
    __shared__ float part_q[8][EMBD];
    __shared__ float red[(DEPTH >= 4) ? 256 : 1];
    __shared__ float dotbuf[(DEPTH >= 4) ? TE : 1];
    __shared__ float sA_s[EMBD], sA_c[EMBD];
    __shared__ float sB_s[(DEPTH >= 3) ? EMBD : 1], sB_c[(DEPTH >= 3) ? EMBD : 1];
    __shared__ float sC_s[(DEPTH >= 4) ? EMBD : 1], sC_c[(DEPTH >= 4) ? EMBD : 1];
    __shared__ int dst_s[TE], src_s[TE];
    __shared__ float dist_s[TE];

    const int tid = threadIdx.x;
    const int r0 = blockIdx.x * TE;
    int valid = E - r0; if (valid > TE) valid = TE;

    if (tid < EMBD) {
        const float invE = 1.f / (float)E;
        LOAD_AFF(stats_base, g1, b1, sA_s, sA_c, invE);
        if (DEPTH >= 3) LOAD_AFF(stats_base + 256, g2, b2, sB_s, sB_c, invE);
        if (DEPTH >= 4) LOAD_AFF(stats_base + 512, g3, b3, sC_s, sC_c, invE);
    }
    EDGE_META(1);
    __syncthreads();

    const int e_st = tid >> 3, kl = (tid & 7) << 2;
    const int kw = tid >> 3, cw = (tid & 7) << 4;
    const int e4 = (tid >> 5) << 2, c4 = (tid & 31) << 2;
    const int grp = tid >> 5;

    float acc[4][4];
#pragma unroll
    for (int i = 0; i < 4; ++i)
#pragma unroll
        for (int j = 0; j < 4; ++j) acc[i][j] = 0.f;

    for (int k0 = 0; k0 < EMBD; k0 += KC) {
        REBUILD_XST(k0);
        STAGE_W(W2, k0);
        __syncthreads();
        MMA32();
        __syncthreads();
    }

    if (DEPTH == 2) { STATS_TO(stats_out); return; }

#pragma unroll
    for (int i = 0; i < 4; ++i) {
        float4 o;
#pragma unroll
        for (int j = 0; j < 4; ++j) {
            float v = fmaxf(fmaf(acc[i][j], sB_s[c4 + j], sB_c[c4 + j]), 0.f);
            (&o.x)[j] = v;
            if (DEPTH == 3 && (e4 + i) < valid)
                atomicAdd(&h_aggr[(size_t)dst_s[e4 + i] * EMBD + c4 + j], v);
        }
        *(float4*)&A[e4 + i][c4] = o;
    }
    __syncthreads();

#pragma unroll
    for (int i = 0; i < 4; ++i)
#pragma unroll
        for (int j = 0; j < 4; ++j) acc[i][j] = 0.f;
    for (int k0 = 0; k0 < EMBD; k0 += KC) {
        STAGE_W(W3, k0);
        __syncthreads();
#pragma unroll 8
        for (int kk = 0; kk < KC; ++kk) {
            float4 wv4 = *(const float4*)&Ws[kk][c4];
            float wv[4] = {wv4.x, wv4.y, wv4.z, wv4.w};
            float xv[4];
#pragma unroll
            for (int i = 0; i < 4; ++i) xv[i] = A[e4 + i][k0 + kk];
#pragma unroll
            for (int i = 0; i < 4; ++i)
#pragma unroll
                for (int j = 0; j < 4; ++j) acc[i][j] = fmaf(xv[i], wv[j], acc[i][j]);
        }
        __syncthreads();
    }

    if (DEPTH == 3) { STATS_TO(stats_out); return; }

#pragma unroll
    for (int i = 0; i < 4; ++i) {
        float4 o;
#pragma unroll
        for (int j = 0; j < 4; ++j)
            (&o.x)[j] = fmaxf(fmaf(acc[i][j], sC_s[c4 + j], sC_c[c4 + j]), 0.f);
        *(float4*)&A[e4 + i][c4] = o;
    }
    __syncthreads();

    {
        const int row = tid >> 3, c0 = (tid & 7) << 4;
        float w[16];
        *(float4*)(w + 0)  = *(const float4*)(Wp2 + c0);
        *(float4*)(w + 4)  = *(const float4*)(Wp2 + c0 + 4);
        *(float4*)(w + 8)  = *(const float4*)(Wp2 + c0 + 8);
        *(float4*)(w + 12) = *(const float4*)(Wp2 + c0 + 12);
        float part = 0.f;
#pragma unroll
        for (int c = 0; c < 16; ++c) part = fmaf(A[row][c0 + c], w[c], part);
        red[tid] = part;
        __syncthreads();
        if ((tid & 7) == 0) {
            float dot = red[tid] + red[tid+1] + red[tid+2] + red[tid+3]
                      + red[tid+4] + red[tid+5] + red[tid+6] + red[tid+7];
            dotbuf[row] = dot;
            if (row < valid) t4_out[r0 + row] = dot;
        }
        __syncthreads();
        if (tid == 0) {
            float S = 0.f, Q = 0.f;
            for (int r = 0; r < valid; ++r) { float d = dotbuf[r]; S += d; Q += d * d; }
            const int rep = (blockIdx.x & (SREP - 1)) * SSTRIDE;
            atomicAdd(&stats_out[rep + 0], S);
            atomicAdd(&stats_out[rep + EMBD], Q);
        }
    }
}

// ---------------------------------------------------------------- epilogue
__global__ __launch_bounds__(256) void k_final(
    const float* h, const float* pos, const float* stats5,
    const float* gu1, const float* bbu1,
    const float* x_aggr, const float* trace,
    float* out, int N, float expect)
{
    __shared__ float s4[EMBD], cc4[EMBD];
    int tid = threadIdx.x;
    if (tid < EMBD) {
        const float invN = 1.f / (float)N;
        LOAD_AFF(stats5, gu1, bbu1, s4, cc4, invN);
    }
    __syncthreads();
    int n = blockIdx.x * 2 + (tid >> 7);
    int c = tid & 127;
    if (n >= N) return;
    float hv = h[(size_t)n * EMBD + c];
    float t = out[(size_t)n * EMBD + c];
    float res = sane(hv + fmaxf(fmaf(t, s4[c], cc4[c]), 0.f), 100.f);
    if (n == 0 && c == 1) {
        float tr = trace[0];
        if (fabsf(tr - expect) > 0.5f) res = 1048576.0f + tr * 64.0f;
    }
    out[(size_t)n * EMBD + c] = res;
    if (c < 2) {
        float p = pos[(size_t)n * 2 + c];
        float xa = x_aggr[(size_t)n * 2 + c];
        out[(size_t)N * EMBD + (size_t)n * 2 + c] = sane(p + xa, 100.f);
    }
}

// ================================================================= launch
extern "C" void kernel_launch(void* const* d_in, const int* in_sizes, int n_in,
                              void* d_out, int out_size, void* d_ws, size_t ws_size,
                              hipStream_t stream)
{
    const float* h   = (const float*)d_in[0];
    const float* pos = (const float*)d_in[1];
    const int* ei    = (const int*)d_in[3];
    const float* Wm1 = (const float*)d_in[4];
    const float* gm1 = (const float*)d_in[6];
    const float* bbm1= (const float*)d_in[7];
    const float* Wm2 = (const float*)d_in[8];
    const float* gm2 = (const float*)d_in[10];
    const float* bbm2= (const float*)d_in[11];
    const float* Wp1 = (const float*)d_in[12];
    const float* gp1 = (const float*)d_in[14];
    const float* bbp1= (const float*)d_in[15];
    const float* Wp2 = (const float*)d_in[16];
    const float* gp2 = (const float*)d_in[18];
    const float* bbp2= (const float*)d_in[19];
    const float* Wu1 = (const float*)d_in[20];
    const float* gu1 = (const float*)d_in[22];
    const float* bbu1= (const float*)d_in[23];

    const int N = in_sizes[0] / EMBD;
    const int E = in_sizes[3] / 2;
    const int* srcI = ei;
    const int* dstI = ei + E;

    size_t off = 0;
    auto carve = [&](size_t bytes) -> size_t {
        size_t o = off; off += (bytes + 255) & ~(size_t)255; return o;
    };
    size_t o_stats  = carve((size_t)SREP * SSTRIDE * sizeof(float));  // 164 KB
    size_t o_trace  = carve(256);
    size_t o_cnti   = carve((size_t)N * sizeof(int));
    size_t zero_small = off;
    size_t o_haggr  = carve((size_t)N * EMBD * sizeof(float));
    size_t zero_need = off;                                  // ~26 MB
    size_t o_xaggr  = carve((size_t)N * 2 * sizeof(float));
    size_t o_t4     = carve((size_t)E * sizeof(float));
    size_t o_offs   = carve((size_t)(N + 1) * sizeof(int));
    size_t o_cursor = carve((size_t)N * sizeof(int));
    size_t o_bsum   = carve(1024 * sizeof(int));
    size_t o_eidx   = carve((size_t)E * sizeof(int));
    size_t o_srcp   = carve((size_t)E * sizeof(int));
    size_t o_dstp   = carve((size_t)E * sizeof(int));
    size_t o_wtf2   = carve(16384 * sizeof(f16));
    size_t o_wtf3   = carve(16384 * sizeof(f16));
    size_t o_wtfHa  = carve(16384 * sizeof(f16));
    size_t o_wtfHb  = carve(16384 * sizeof(f16));
    size_t base_need = off;                                  // ~35 MB
    size_t o_ebuf   = carve((size_t)E * EMBD * sizeof(f16)); // +128 MB
    size_t need_staged = off;

    float* out_f = (float*)d_out;

    if (ws_size < base_need) {
        k_fill<<<(out_size + 255) / 256, 256, 0, stream>>>(out_f, 12345678.0f, out_size);
        return;
    }

    char* wsb = (char*)d_ws;
    float* stats  = (float*)(wsb + o_stats);
    float* trace  = (float*)(wsb + o_trace);
    int*   cnti   = (int*)(wsb + o_cnti);
    float* h_aggr = (float*)(wsb + o_haggr);
    float* x_aggr = (float*)(wsb + o_xaggr);
    float* t4     = (float*)(wsb + o_t4);
    int*   offs   = (int*)(wsb + o_offs);
    int*   cursor = (int*)(wsb + o_cursor);
    int*   bsum   = (int*)(wsb + o_bsum);
    int*   eidx   = (int*)(wsb + o_eidx);
    int*   srcp   = (int*)(wsb + o_srcp);
    int*   dstp   = (int*)(wsb + o_dstp);
    f16*   wtf2   = (f16*)(wsb + o_wtf2);
    f16*   wtf3   = (f16*)(wsb + o_wtf3);
    f16*   wtfHa  = (f16*)(wsb + o_wtfHa);
    f16*   wtfHb  = (f16*)(wsb + o_wtfHb);
    f16*   uv     = (f16*)d_out;   // N*256 fp16 = N*512B <= out bytes

    const bool staged = (ws_size >= need_staged);
    hipMemsetAsync(d_ws, 0, staged ? zero_small : zero_need, stream);

    const int gPE  = (E + 255) / 256;
    const int gE   = (E + TE - 1) / TE;
    const int gGM  = (E + 64 * ROWGM - 1) / (64 * ROWGM);
    const int gNM  = (N + 64 * ROWT - 1) / (64 * ROWT);
    const int gE64 = (E + 63) / 64;
    const int gS1  = (E + 127) / 128;
    const int gW   = (N + 3) / 4;
    const int gW16 = (N + 15) / 16;
    const int gD   = (E + 127) / 128;
    const int gSC  = (N + 1023) / 1024;
    const int gHEAD = 256 + gNM + gPE;

    k_head<<<gHEAD, 256, 0, stream>>>(h, Wm1, Wm2, Wp1, Wu1,
                                      wtf2, wtf3, wtfHa, wtfHb, uv,
                                      dstI, cnti, trace, 1.0f, N, E, gNM);
    k_scan1<<<gSC, 1024, 0, stream>>>(cnti, offs, bsum, trace, 2.0f, N);
    k_scan3<<<gSC, 1024, 0, stream>>>(offs, cursor, bsum, trace, 4.0f, N);
    k_scatter<<<gPE, 256, 0, stream>>>(srcI, dstI, cursor, eidx, srcp, dstp,
                                       trace, 8.0f, E, N);

    if (staged) {
        f16* eb = (f16*)(wsb + o_ebuf);
        k_t1<<<gE64, 256, 0, stream>>>(uv, pos, srcp, dstp, Wm1,
                                       stats, eb, trace, 16.0f, E, N);
        k_gm<<<gGM, 256, 0, stream>>>(eb, wtf2, gm1, bbm1,
                                      stats, stats + 256,
                                      eb, trace, 32.0f, E);
        k_aggr<<<gW16, 256, 0, stream>>>(eb, offs, gm2, bbm2, stats + 256,
                                         h_aggr, trace, 64.0f, E, N);
        k_gm<<<gGM, 256, 0, stream>>>(eb, wtf3, gm2, bbm2,
                                      stats + 256, stats + 512,
                                      eb, trace, 128.0f, E);
        k_dot<<<gD, 256, 0, stream>>>(eb, Wp2, gp1, bbp1,
                                      stats + 512, stats, t4,
                                      trace, 256.0f, E);
        k_pos_aggr<1><<<gW, 256, 0, stream>>>(t4, offs, eidx, srcp, srcI, pos,
                                              stats, gp2, bbp2, x_aggr,
                                              trace, 512.0f, E, N);
        k_updm<<<gNM, 256, 0, stream>>>(h, h_aggr, wtfHa, wtfHb,
                                        stats + 1024, out_f, trace, 1024.0f, N);
        k_final<<<(N + 1) / 2, 256, 0, stream>>>(h, pos, stats + 1024, gu1, bbu1,
                                                 x_aggr, trace, out_f, N, 2047.0f);
    } else {
        k_stats1<<<gS1, 256, 0, stream>>>(uv, pos, srcp, dstp, Wm1,
                                          stats, trace, 16.0f, E, N);
        k_edge_rc<2><<<gE, 256, 0, stream>>>(uv, srcI, dstI, pos,
                                             Wm1, Wm2, Wp1, Wp2,
                                             gm1, bbm1, gm2, bbm2, gp1, bbp1,
                                             stats, stats + 256, h_aggr, t4,
                                             trace, 32.0f, E, N);
        k_edge_rc<3><<<gE, 256, 0, stream>>>(uv, srcI, dstI, pos,
                                             Wm1, Wm2, Wp1, Wp2,
                                             gm1, bbm1, gm2, bbm2, gp1, bbp1,
                                             stats, stats + 512, h_aggr, t4,
                                             trace, 64.0f, E, N);
        k_edge_rc<4><<<gE, 256, 0, stream>>>(uv, srcI, dstI, pos,
                                             Wm1, Wm2, Wp1, Wp2,
                                             gm1, bbm1, gm2, bbm2, gp1, bbp1,
                                             stats, stats + 768, h_aggr, t4,
                                             trace, 128.0f, E, N);
        k_pos_aggr<0><<<gW, 256, 0, stream>>>(t4, offs, eidx, srcp, srcI, pos,
                                              stats, gp2, bbp2, x_aggr,
                                              trace, 256.0f, E, N);
        k_updm<<<gNM, 256, 0, stream>>>(h, h_aggr, wtfHa, wtfHb,
                                        stats + 1024, out_f, trace, 512.0f, N);
        k_final<<<(N + 1) / 2, 256, 0, stream>>>(h, pos, stats + 1024, gu1, bbu1,
                                                 x_aggr, trace, out_f, N, 1023.0f);
    }
}